// Round 10
// baseline (4635.471 us; speedup 1.0000x reference)
//
#include <hip/hip_runtime.h>
#include <cstdint>

// ---------------------------------------------------------------------------
// ForwardBackwardGNN — R10.
//   LSTM: R6 structure (64 edges/block, 4 es, 8 waves, cst in VGPR) +
//         Pg32 fp32 C-in direct loads (removes unpack temps -> VGPR ~80) +
//         launch_bounds(512,3): 170-reg cap fits 80 VGPR + 64 AGPR with
//         ZERO spill at 3 waves/SIMD (37.5% occupancy).
//   GAT:  per-node argmax + CSR + fused node kernel (R9).
//   N=50000, E=400000, L=16, V=64, EMB=32, H=128, D=373, SID=53.
// ---------------------------------------------------------------------------

#define D_DIM   373
#define SID_N   53
#define IN_COL  161
#define OUT_COL 320
#define HS_STRIDE 136   // u16/row
#define EDGES_T 64      // edges per tile/block
#define N_ES    4       // edge sub-tiles of 16

typedef short bf16x8 __attribute__((ext_vector_type(8)));
typedef float f32x4  __attribute__((ext_vector_type(4)));

#define LOG2E_F 1.4426950408889634f
#define TWO_LOG2E_F 2.8853900817779268f

__device__ __forceinline__ float fast_exp2(float x) {
#if __has_builtin(__builtin_amdgcn_exp2f)
  return __builtin_amdgcn_exp2f(x);
#else
  return exp2f(x);
#endif
}
__device__ __forceinline__ float fast_rcp(float x) {
#if __has_builtin(__builtin_amdgcn_rcpf)
  return __builtin_amdgcn_rcpf(x);
#else
  return 1.0f / x;
#endif
}
__device__ __forceinline__ float sig_ref(float x)  { return 1.0f / (1.0f + __expf(-x)); }
__device__ __forceinline__ float tanh_ref(float x) { return 2.0f / (1.0f + __expf(-2.0f * x)) - 1.0f; }

__device__ __forceinline__ unsigned short f2bf(float f) {
  unsigned u = __float_as_uint(f);
  unsigned r = (u + 0x7fffu + ((u >> 16) & 1u)) >> 16;
  return (unsigned short)r;
}
__device__ __forceinline__ unsigned cvt_pk_bf16(float lo, float hi) {
  unsigned r;
  asm("v_cvt_pk_bf16_f32 %0, %1, %2" : "=v"(r) : "v"(lo), "v"(hi));
  return r;
}
// sig(a)*tanh(b) with A=2^{-a*log2e} (pre-scaled), B=2^{+2b*log2e} (pre-scaled)
__device__ __forceinline__ float pair_sig_tanh(float A, float B) {
  return (B - 1.0f) * fast_rcp((1.0f + A) * (1.0f + B));
}

// ---------------- generic fill ----------------
__global__ void fill_u32_kernel(unsigned* __restrict__ p, unsigned v, size_t n) {
  size_t i = (size_t)blockIdx.x * blockDim.x + threadIdx.x;
  size_t stride = (size_t)gridDim.x * blockDim.x;
  for (; i < n; i += stride) p[i] = v;
}

// ---------------- precompute: Pg32 / FB / MFMA fragments ----------------
// grid = 64, block = 512. Pg32/BfragW carry folded scales (i,f,o:-log2e; g:+2log2e).
__global__ void precompute_kernel(
    const float* __restrict__ embed, const float* __restrict__ Wih_f,
    const float* __restrict__ Whh_f,
    const float* __restrict__ bih_f, const float* __restrict__ bhh_f,
    const float* __restrict__ Wih_r,
    const float* __restrict__ bih_r, const float* __restrict__ bhh_r,
    const float* __restrict__ W1, const float* __restrict__ b1,
    float* __restrict__ Pg32, unsigned short* __restrict__ BfragW,
    unsigned short* __restrict__ Bfrag1, float* __restrict__ FB)
{
  __shared__ float gb[512];
  __shared__ float hb[128];
  int v = blockIdx.x;
  int j = threadIdx.x;          // j = gate*128 + h

  float s = 0.0f;
  if (v != 0) {
    #pragma unroll
    for (int k = 0; k < 32; ++k) s += embed[v * 32 + k] * Wih_f[j * 32 + k];
  }
  s += bih_f[j] + bhh_f[j];

  float gr = bih_r[j] + bhh_r[j];
  if (v != 0) {
    #pragma unroll
    for (int k = 0; k < 32; ++k) gr += embed[v * 32 + k] * Wih_r[j * 32 + k];
  }
  gb[j] = gr;
  __syncthreads();
  if (j < 128) {
    float c = sig_ref(gb[j]) * tanh_ref(gb[256 + j]);
    hb[j] = sig_ref(gb[384 + j]) * tanh_ref(c);
  }
  __syncthreads();

  // Pg32[v][gate][h] = scale(gate) * P[v][gate*128+h]
  { int gate = j >> 7;
    float sc = (gate == 2) ? TWO_LOG2E_F : -LOG2E_F;
    Pg32[(size_t)v * 512 + j] = s * sc; }

  if (j < 32) {
    float s2 = b1[j];
    for (int m = 0; m < 128; ++m) s2 += hb[m] * W1[(128 + m) * 32 + j];
    FB[v * 32 + j] = s2;
  }

  if (v == 0) {
    // BfragW flat = ((nt*4+ks)*64 + lane)*8 + e ; val = scale * Whh_f[n][k]
    for (int f = j; f < 65536; f += 512) {
      int e = f & 7, l = (f >> 3) & 63, ks = (f >> 9) & 3, nt = f >> 11;
      int n = nt * 16 + (l & 15);
      int k = ks * 32 + (l >> 4) * 8 + e;
      float sc = ((nt >> 3) == 2) ? TWO_LOG2E_F : -LOG2E_F;
      BfragW[f] = f2bf(Whh_f[(size_t)n * 128 + k] * sc);
    }
  }
  if (v == 1) {
    // Bfrag1 flat = ((n2*4+ks)*64 + lane)*8 + e ; B[k][q] = W1[k][q] (k<128)
    for (int f = j; f < 4096; f += 512) {
      int e = f & 7, l = (f >> 3) & 63, ks = (f >> 9) & 3, n2 = f >> 11;
      int q = n2 * 16 + (l & 15);
      int k = ks * 32 + (l >> 4) * 8 + e;
      Bfrag1[f] = f2bf(W1[(size_t)k * 32 + q]);
    }
  }
}

// ---------------- MFMA LSTM: 64 edges/block, 8 waves, 1 barrier/step --------
// mfma(A=W-frag, B=H-frag) -> D: col=lane&15=edge(sub), row=(lane>>4)*4+r=hcol.
// Wave wv2 owns hcols [wv2*16,+16) x 4 gates for all 4 edge sub-tiles.
// launch_bounds(512,3): 170-reg cap -> 80 VGPR + 64 AGPR, no spill.
__global__ __launch_bounds__(512, 3) void lstm_mfma_kernel(
    const int*   __restrict__ tokens,   // [E][16]
    const float* __restrict__ Pg32,     // [64][4][128] f32 (scaled)
    const unsigned short* __restrict__ BfragW,  // [32][4][64][8] bf16 (scaled)
    const unsigned short* __restrict__ Bfrag1,  // [2][4][64][8] bf16
    const float* __restrict__ FB,       // [64][32]
    const float* __restrict__ W2,       // [32]
    const float* __restrict__ b2,
    float* __restrict__ ea, int E, int nTiles)
{
  __shared__ unsigned short Hs[2][EDGES_T * HS_STRIDE];  // 34,816 B
  __shared__ int toks[16][EDGES_T];                      //  4,096 B

  int tid  = threadIdx.x;
  int lane = tid & 63;
  int wv2  = tid >> 6;                  // 0..7
  int l15  = lane & 15;
  int lg   = lane >> 4;                 // 0..3
  int hbase = wv2 * 16 + lg * 4;        // this lane's 4 hcols
  const float* PgL = Pg32 + hbase;      // per-lane base

  // persistent A-frags (W): BW[gate][ks] — 64 regs (AGPR)
  bf16x8 BW[4][4];
  #pragma unroll
  for (int gate = 0; gate < 4; ++gate)
    #pragma unroll
    for (int ks = 0; ks < 4; ++ks)
      BW[gate][ks] = *(const bf16x8*)(BfragW +
          ((size_t)((gate * 8 + wv2) * 4 + ks) * 64 + lane) * 8);
  float4 w2lo = *(const float4*)(W2 + lg * 4);
  float4 w2hi = *(const float4*)(W2 + 16 + lg * 4);
  float b2v = b2[0];

  for (int tile = blockIdx.x; tile < nTiles; tile += gridDim.x) {
    int e0 = tile * EDGES_T;
    for (int i = tid; i < 16 * EDGES_T; i += 512) {   // stage tokens [t][m]
      int m = i >> 4, t = i & 15;
      int ee = e0 + m; if (ee >= E) ee = E - 1;
      toks[t][m] = tokens[(size_t)ee * 16 + t];
    }
    __syncthreads();

    f32x4 cst[N_ES];   // statically indexed (es fully unrolled)
    // ---- step 0: gates = P only (h0=c0=0, f-term vanishes)
    #pragma unroll
    for (int es = 0; es < N_ES; ++es) {
      int eL = es * 16 + l15;
      const float* pb = PgL + (unsigned)toks[0][eL] * 512u;
      f32x4 ai = *(const f32x4*)(pb);         // i (scaled)
      f32x4 ag = *(const f32x4*)(pb + 256);   // g
      f32x4 ao = *(const f32x4*)(pb + 384);   // o
      float h[4];
      #pragma unroll
      for (int r = 0; r < 4; ++r) {
        float A = fast_exp2(ai[r]);
        float B = fast_exp2(ag[r]);
        float O = fast_exp2(ao[r]);
        float cn = pair_sig_tanh(A, B);     // i*g
        cst[es][r] = cn;
        float C = fast_exp2(TWO_LOG2E_F * cn);
        h[r] = pair_sig_tanh(O, C);         // o*tanh(c)
      }
      uint2 hp = make_uint2(cvt_pk_bf16(h[0], h[1]), cvt_pk_bf16(h[2], h[3]));
      *(uint2*)(&Hs[0][eL * HS_STRIDE + hbase]) = hp;
    }
    __syncthreads();

    int cur = 0;
    #pragma unroll 1
    for (int t = 1; t < 16; ++t) {
      #pragma unroll
      for (int es = 0; es < N_ES; ++es) {
        int eL = es * 16 + l15;
        const float* pb = PgL + (unsigned)toks[t][eL] * 512u;
        f32x4 acc[4];
        acc[0] = *(const f32x4*)(pb);         // i
        acc[1] = *(const f32x4*)(pb + 128);   // f
        acc[2] = *(const f32x4*)(pb + 256);   // g
        acc[3] = *(const f32x4*)(pb + 384);   // o

        #pragma unroll
        for (int ks = 0; ks < 4; ++ks) {
          bf16x8 Hf = *(const bf16x8*)(&Hs[cur][eL * HS_STRIDE + ks * 32 + lg * 8]);
          #pragma unroll
          for (int gate = 0; gate < 4; ++gate)
            acc[gate] = __builtin_amdgcn_mfma_f32_16x16x32_bf16(
                BW[gate][ks], Hf, acc[gate], 0, 0, 0);
        }

        float h[4];
        #pragma unroll
        for (int r = 0; r < 4; ++r) {
          float A = fast_exp2(acc[0][r]);
          float F = fast_exp2(acc[1][r]);
          float B = fast_exp2(acc[2][r]);
          float O = fast_exp2(acc[3][r]);
          float ig = pair_sig_tanh(A, B);
          float f  = fast_rcp(1.0f + F);
          float cn = fmaf(f, cst[es][r], ig);
          cst[es][r] = cn;
          float C = fast_exp2(TWO_LOG2E_F * cn);
          h[r] = pair_sig_tanh(O, C);
        }
        uint2 hp = make_uint2(cvt_pk_bf16(h[0], h[1]), cvt_pk_bf16(h[2], h[3]));
        *(uint2*)(&Hs[cur ^ 1][eL * HS_STRIDE + hbase]) = hp;
      }
      cur ^= 1;
      __syncthreads();
    }

    // ---- tail: waves 0..3 each handle edge sub-tile es=wv2
    if (wv2 < N_ES) {
      int eL = wv2 * 16 + l15;
      bf16x8 Hf[4];
      #pragma unroll
      for (int ks = 0; ks < 4; ++ks)
        Hf[ks] = *(const bf16x8*)(&Hs[cur][eL * HS_STRIDE + ks * 32 + lg * 8]);
      f32x4 a2[2];
      a2[0] = (f32x4){0.f, 0.f, 0.f, 0.f};
      a2[1] = (f32x4){0.f, 0.f, 0.f, 0.f};
      #pragma unroll
      for (int ks = 0; ks < 4; ++ks)
        #pragma unroll
        for (int n2 = 0; n2 < 2; ++n2)
          a2[n2] = __builtin_amdgcn_mfma_f32_16x16x32_bf16(
              *(const bf16x8*)(Bfrag1 + ((size_t)(n2 * 4 + ks) * 64 + lane) * 8),
              Hf[ks], a2[n2], 0, 0, 0);
      int v15 = toks[15][eL];
      float4 fb0 = *(const float4*)(FB + v15 * 32 + lg * 4);
      float4 fb1 = *(const float4*)(FB + v15 * 32 + 16 + lg * 4);
      float pr = fmaxf(a2[0][0] + fb0.x, 0.f) * w2lo.x
               + fmaxf(a2[0][1] + fb0.y, 0.f) * w2lo.y
               + fmaxf(a2[0][2] + fb0.z, 0.f) * w2lo.z
               + fmaxf(a2[0][3] + fb0.w, 0.f) * w2lo.w
               + fmaxf(a2[1][0] + fb1.x, 0.f) * w2hi.x
               + fmaxf(a2[1][1] + fb1.y, 0.f) * w2hi.y
               + fmaxf(a2[1][2] + fb1.z, 0.f) * w2hi.z
               + fmaxf(a2[1][3] + fb1.w, 0.f) * w2hi.w;
      pr += __shfl_xor(pr, 16);
      pr += __shfl_xor(pr, 32);
      int eidx = e0 + eL;
      if (lane < 16 && eidx < E) ea[eidx] = fmaxf(pr + b2v, 0.0f);
    }
    __syncthreads();   // before next tile reuses toks/Hs
  }
}

// ---------------- per-node argmax over x[:, :53] (wave per node) -----------
__global__ __launch_bounds__(256) void node_argmax_kernel(
    const float* __restrict__ x, int* __restrict__ nid, int N)
{
  int n = (blockIdx.x * 256 + threadIdx.x) >> 6;
  int lane = threadIdx.x & 63;
  if (n >= N) return;
  float v = (lane < SID_N) ? x[(size_t)n * D_DIM + lane] : -3.4e38f;
  int idx = lane;
  #pragma unroll
  for (int o = 32; o > 0; o >>= 1) {
    float ov = __shfl_down(v, o);
    int   oi = __shfl_down(idx, o);
    if (ov > v || (ov == v && oi < idx)) { v = ov; idx = oi; }
  }
  if (lane == 0) nid[n] = idx;
}

// ---------------- edge winner (last edge wins) + resolve -------------------
__global__ void edge_winner_kernel(
    const int* __restrict__ ei, const int* __restrict__ nid,
    int* __restrict__ win_in, int* __restrict__ win_out, int E)
{
  int e = blockIdx.x * 256 + threadIdx.x;
  if (e >= E) return;
  int s = ei[e];
  int t = ei[E + e];
  atomicMax(&win_in[(size_t)t * SID_N + nid[s]], e);
  atomicMax(&win_out[(size_t)s * SID_N + nid[t]], e);
}

__global__ void scatter_resolve_kernel(
    const int* __restrict__ ei, const int* __restrict__ nid,
    const float* __restrict__ ea,
    const int* __restrict__ win_in, const int* __restrict__ win_out,
    float* __restrict__ x_mod, int E)
{
  int e = blockIdx.x * 256 + threadIdx.x;
  if (e >= E) return;
  int s = ei[e];
  int t = ei[E + e];
  int sid = nid[s], tix = nid[t];
  if (win_in[(size_t)t * SID_N + sid] == e)
    x_mod[(size_t)t * D_DIM + IN_COL + sid] = ea[e];
  if (win_out[(size_t)s * SID_N + tix] == e)
    x_mod[(size_t)s * D_DIM + OUT_COL + tix] = ea[e];
}

// ---------------- pack Wl||Wr into MFMA fragment order ----------------
__global__ void pack_w_kernel(const float* __restrict__ Wl,
                              const float* __restrict__ Wr,
                              unsigned short* __restrict__ Wfrag)
{
  int f = blockIdx.x * 256 + threadIdx.x;
  if (f >= 48 * 12 * 64 * 8) return;
  int e = f & 7, l = (f >> 3) & 63;
  int rest = f >> 9;
  int ks = rest % 12, nt = rest / 12;
  int nl = nt * 16 + (l & 15);
  int k  = ks * 32 + (l >> 4) * 8 + e;
  float val = 0.0f;
  if (k < D_DIM) {
    if (nl < D_DIM)                      val = Wl[(size_t)k * D_DIM + nl];
    else if (nl >= 384 && nl < 384 + D_DIM) val = Wr[(size_t)k * D_DIM + (nl - 384)];
  }
  Wfrag[f] = f2bf(val);
}

// ---------------- fused bf16 MFMA GEMM: [xl||xr] = xmod @ [Wl||Wr] + bias ----
__global__ __launch_bounds__(256, 2) void gemm_mfma_kernel(
    const float* __restrict__ A,               // xmod [N][373] fp32
    const unsigned short* __restrict__ Wfrag,  // [48][12][64][8] bf16
    const float* __restrict__ bl, const float* __restrict__ br,
    float* __restrict__ xl, float* __restrict__ xr, int N)
{
  __shared__ unsigned short As[64][40];
  int tid  = threadIdx.x;
  int lane = tid & 63;
  int wv   = tid >> 6;
  int l15  = lane & 15, lg = lane >> 4;
  int m0   = blockIdx.x * 64;
  int nt   = blockIdx.y * 4 + wv;

  f32x4 acc[4];
  #pragma unroll
  for (int i = 0; i < 4; ++i) acc[i] = (f32x4){0.f, 0.f, 0.f, 0.f};

  int srow = tid >> 2, seg = tid & 3;
  int gr = m0 + srow; if (gr >= N) gr = N - 1;
  const float* arow = A + (size_t)gr * D_DIM;

  for (int ks = 0; ks < 12; ++ks) {
    int c0 = ks * 32 + seg * 8;
    float v[8];
    #pragma unroll
    for (int j = 0; j < 8; ++j) v[j] = (c0 + j < D_DIM) ? arow[c0 + j] : 0.0f;
    unsigned pk0 = cvt_pk_bf16(v[0], v[1]);
    unsigned pk1 = cvt_pk_bf16(v[2], v[3]);
    unsigned pk2 = cvt_pk_bf16(v[4], v[5]);
    unsigned pk3 = cvt_pk_bf16(v[6], v[7]);
    __syncthreads();
    *(uint4*)(&As[srow][seg * 8]) = make_uint4(pk0, pk1, pk2, pk3);
    __syncthreads();

    bf16x8 Bf = *(const bf16x8*)(Wfrag + ((size_t)(nt * 12 + ks) * 64 + lane) * 8);
    #pragma unroll
    for (int msub = 0; msub < 4; ++msub) {
      bf16x8 Af = *(const bf16x8*)(&As[msub * 16 + l15][lg * 8]);
      acc[msub] = __builtin_amdgcn_mfma_f32_16x16x32_bf16(Af, Bf, acc[msub], 0, 0, 0);
    }
  }

  int nl = nt * 16 + l15;
  float* dst = nullptr; int col = 0; const float* bias_ = nullptr;
  if (nl < D_DIM)                         { dst = xl; col = nl;       bias_ = bl; }
  else if (nl >= 384 && nl < 384 + D_DIM) { dst = xr; col = nl - 384; bias_ = br; }
  if (dst) {
    float bv = bias_[col];
    #pragma unroll
    for (int msub = 0; msub < 4; ++msub) {
      #pragma unroll
      for (int r = 0; r < 4; ++r) {
        int m = m0 + msub * 16 + lg * 4 + r;
        if (m < N) dst[(size_t)m * D_DIM + col] = acc[msub][r] + bv;
      }
    }
  }
}

// ---------------- GAT: attention logits (no atomics) ----------------
__global__ __launch_bounds__(256) void edge_e_kernel(
    const float* __restrict__ xl, const float* __restrict__ xr,
    const float* __restrict__ att, const int* __restrict__ ei,
    float* __restrict__ e_buf, int E)
{
  int widx = (blockIdx.x * 256 + threadIdx.x) >> 6;
  int lane = threadIdx.x & 63;
  if (widx >= E) return;
  int s = ei[widx], t = ei[E + widx];
  const float* pl = xl + (size_t)s * D_DIM;
  const float* pr = xr + (size_t)t * D_DIM;
  float acc = 0.0f;
  for (int d = lane; d < D_DIM; d += 64) {
    float m = pl[d] + pr[d];
    m = (m > 0.0f) ? m : 0.2f * m;
    acc += m * att[d];
  }
  #pragma unroll
  for (int o = 32; o > 0; o >>= 1) acc += __shfl_down(acc, o);
  if (lane == 0) e_buf[widx] = acc;
}

// ---------------- CSR build: histogram / scan / placement ----------------
__global__ void hist_kernel(const int* __restrict__ ei, unsigned* __restrict__ deg,
                            int E) {
  int e = blockIdx.x * 256 + threadIdx.x;
  if (e >= E) return;
  atomicAdd(&deg[ei[E + e]], 1u);
}

__global__ void scan1_kernel(const unsigned* __restrict__ deg,
                             unsigned* __restrict__ excl,
                             unsigned* __restrict__ bsum, int n) {
  __shared__ unsigned s[256];
  int t = threadIdx.x;
  int i = blockIdx.x * 256 + t;
  unsigned v = (i < n) ? deg[i] : 0u;
  s[t] = v; __syncthreads();
  #pragma unroll
  for (int o = 1; o < 256; o <<= 1) {
    unsigned u = (t >= o) ? s[t - o] : 0u;
    __syncthreads();
    s[t] += u;
    __syncthreads();
  }
  if (i < n) excl[i] = s[t] - v;
  if (t == 255) bsum[blockIdx.x] = s[255];
}

__global__ void scan2_kernel(unsigned* __restrict__ bsum, int nb) {
  __shared__ unsigned s[256];
  int t = threadIdx.x;
  unsigned v = (t < nb) ? bsum[t] : 0u;
  s[t] = v; __syncthreads();
  #pragma unroll
  for (int o = 1; o < 256; o <<= 1) {
    unsigned u = (t >= o) ? s[t - o] : 0u;
    __syncthreads();
    s[t] += u;
    __syncthreads();
  }
  if (t < nb) bsum[t] = s[t] - v;   // exclusive
}

__global__ void scan3_kernel(unsigned* __restrict__ excl,
                             const unsigned* __restrict__ bsum, int n) {
  int i = blockIdx.x * 256 + threadIdx.x;
  if (i < n) excl[i] += bsum[i >> 8];
}

__global__ void place_kernel(const int* __restrict__ ei,
                             unsigned* __restrict__ offs,
                             int* __restrict__ csr_eid, int E) {
  int e = blockIdx.x * 256 + threadIdx.x;
  if (e >= E) return;
  unsigned j = atomicAdd(&offs[ei[E + e]], 1u);
  csr_eid[j] = e;
}

// ---------------- fused per-node: softmax + aggregate + finalize ----------
__global__ __launch_bounds__(256) void node_gat_kernel(
    const int* __restrict__ ei, const int* __restrict__ csr_eid,
    const unsigned* __restrict__ offs, const unsigned* __restrict__ deg,
    float* __restrict__ ebuf, const float* __restrict__ xl,
    const float* __restrict__ xmod, const float* __restrict__ bias,
    float* __restrict__ out, int N, int E, int goff)
{
  int n = (blockIdx.x * 256 + threadIdx.x) >> 6;
  int lane = threadIdx.x & 63;
  if (n >= N) return;
  unsigned end = offs[n], d = deg[n], start = end - d;

  float mx = -3.4e38f;
  for (unsigned j = start; j < end; ++j)
    mx = fmaxf(mx, ebuf[csr_eid[j]]);
  float den = 0.0f;
  for (unsigned j = start; j < end; ++j) {
    int eid = csr_eid[j];
    float ex = __expf(ebuf[eid] - mx);
    ebuf[eid] = ex;               // reuse in agg pass (exclusive to this wave)
    den += ex;
  }
  float inv = 1.0f / (den + 1e-16f);

  float o0 = 0, o1 = 0, o2 = 0, o3 = 0, o4 = 0, o5 = 0;
  for (unsigned j = start; j < end; ++j) {
    int eid = csr_eid[j];
    float w = ebuf[eid] * inv;
    const float* row = xl + (size_t)ei[eid] * D_DIM;
    o0 = fmaf(w, row[lane], o0);
    o1 = fmaf(w, row[64 + lane], o1);
    o2 = fmaf(w, row[128 + lane], o2);
    o3 = fmaf(w, row[192 + lane], o3);
    o4 = fmaf(w, row[256 + lane], o4);
    if (lane < 53) o5 = fmaf(w, row[320 + lane], o5);
  }

  const float* xm = xmod + (size_t)n * D_DIM;
  float* op = out + (size_t)n * (2 * D_DIM) + goff;
  op[lane]       = fmaxf(o0 + bias[lane]       + xm[lane],       0.0f);
  op[64 + lane]  = fmaxf(o1 + bias[64 + lane]  + xm[64 + lane],  0.0f);
  op[128 + lane] = fmaxf(o2 + bias[128 + lane] + xm[128 + lane], 0.0f);
  op[192 + lane] = fmaxf(o3 + bias[192 + lane] + xm[192 + lane], 0.0f);
  op[256 + lane] = fmaxf(o4 + bias[256 + lane] + xm[256 + lane], 0.0f);
  if (lane < 53)
    op[320 + lane] = fmaxf(o5 + bias[320 + lane] + xm[320 + lane], 0.0f);
}

// ---------------------------------------------------------------------------
extern "C" void kernel_launch(void* const* d_in, const int* in_sizes, int n_in,
                              void* d_out, int out_size, void* d_ws, size_t ws_size,
                              hipStream_t stream)
{
  const float* fx     = (const float*)d_in[0];
  const float* bx     = (const float*)d_in[1];
  const int*   fei    = (const int*)d_in[2];
  const int*   bei    = (const int*)d_in[3];
  const int*   ftk    = (const int*)d_in[4];
  const int*   btk    = (const int*)d_in[5];
  const float* embed  = (const float*)d_in[6];
  const float* Wih_f  = (const float*)d_in[7];
  const float* Whh_f  = (const float*)d_in[8];
  const float* bih_f  = (const float*)d_in[9];
  const float* bhh_f  = (const float*)d_in[10];
  const float* Wih_r  = (const float*)d_in[11];
  // d_in[12] = Whh_r : unused (reverse cell consumes zero state)
  const float* bih_r  = (const float*)d_in[13];
  const float* bhh_r  = (const float*)d_in[14];
  const float* W1     = (const float*)d_in[15];
  const float* b1     = (const float*)d_in[16];
  const float* W2     = (const float*)d_in[17];
  const float* b2     = (const float*)d_in[18];

  const float* Wl_g[2]   = {(const float*)d_in[19], (const float*)d_in[25]};
  const float* bl_g[2]   = {(const float*)d_in[20], (const float*)d_in[26]};
  const float* Wr_g[2]   = {(const float*)d_in[21], (const float*)d_in[27]};
  const float* br_g[2]   = {(const float*)d_in[22], (const float*)d_in[28]};
  const float* att_g[2]  = {(const float*)d_in[23], (const float*)d_in[29]};
  const float* bias_g[2] = {(const float*)d_in[24], (const float*)d_in[30]};
  const float* x_g[2]    = {fx, bx};
  const int*   ei_g[2]   = {fei, bei};
  const int*   tk_g[2]   = {ftk, btk};

  const int E = in_sizes[2] / 2;          // 400000
  const int N = in_sizes[0] / D_DIM;      // 50000

  // ---- workspace layout (byte-based, 256B aligned chunks) ----
  char* wsb = (char*)d_ws;
  size_t off = 0;
  auto alloc = [&](size_t bytes) -> void* {
    void* p = wsb + off; off += (bytes + 255) & ~(size_t)255; return p;
  };
  float* Pg32            = (float*)alloc((size_t)64 * 512 * 4);
  unsigned short* BfragW = (unsigned short*)alloc((size_t)65536 * 2);
  unsigned short* Bfrag1 = (unsigned short*)alloc((size_t)4096 * 2);
  unsigned short* Wfrag2 = (unsigned short*)alloc((size_t)2 * 294912 * 2);
  float* FB    = (float*)alloc((size_t)64 * 32 * 4);
  float* ea    = (float*)alloc((size_t)E * 4);
  float* ebuf  = (float*)alloc((size_t)E * 4);
  int*   nid   = (int*)alloc((size_t)N * 4);
  int*   csr_eid = (int*)alloc((size_t)E * 4);
  unsigned* deg  = (unsigned*)alloc((size_t)N * 4);
  unsigned* offs = (unsigned*)alloc((size_t)N * 4);
  unsigned* bsum = (unsigned*)alloc((size_t)256 * 4);
  int* win_in  = (int*)alloc((size_t)N * SID_N * 4);
  int* win_out = (int*)alloc((size_t)N * SID_N * 4);
  float* xmod  = (float*)alloc((size_t)N * D_DIM * 4);
  float* xl    = (float*)alloc((size_t)N * D_DIM * 4);
  float* xr    = (float*)alloc((size_t)N * D_DIM * 4);
  (void)ws_size; (void)n_in; (void)out_size;

  const size_t win_u32 = (size_t)((char*)win_out - (char*)win_in) / 4
                         + (size_t)N * SID_N;

  float* out = (float*)d_out;

  precompute_kernel<<<64, 512, 0, stream>>>(
      embed, Wih_f, Whh_f, bih_f, bhh_f, Wih_r, bih_r, bhh_r, W1, b1,
      Pg32, BfragW, Bfrag1, FB);
  pack_w_kernel<<<(294912 + 255) / 256, 256, 0, stream>>>(
      Wl_g[0], Wr_g[0], Wfrag2);
  pack_w_kernel<<<(294912 + 255) / 256, 256, 0, stream>>>(
      Wl_g[1], Wr_g[1], Wfrag2 + 294912);

  const int nTiles  = (E + EDGES_T - 1) / EDGES_T;   // 6250
  const int gridL   = nTiles < 2048 ? nTiles : 2048;
  const int gridE   = (E + 255) / 256;
  const int gridEW  = (E + 3) / 4;
  const int nScanB  = (N + 255) / 256;
  const int gridNd  = (N * 64 + 255) / 256;
  dim3 gridG((N + 63) / 64, 12);

  for (int g = 0; g < 2; ++g) {
    const float* x  = x_g[g];
    const int*   ei = ei_g[g];

    // (1) edge scalar via MFMA LSTM
    lstm_mfma_kernel<<<gridL, 512, 0, stream>>>(tk_g[g], Pg32, BfragW, Bfrag1,
                                                FB, W2, b2, ea, E, nTiles);

    // (2) x_mod = copy(x); per-node argmax; last-edge-wins scatter writes
    hipMemcpyAsync(xmod, x, (size_t)N * D_DIM * sizeof(float),
                   hipMemcpyDeviceToDevice, stream);
    node_argmax_kernel<<<gridNd, 256, 0, stream>>>(x, nid, N);
    fill_u32_kernel<<<2048, 256, 0, stream>>>((unsigned*)win_in, 0xFFFFFFFFu,
                                              win_u32);
    edge_winner_kernel<<<gridE, 256, 0, stream>>>(ei, nid, win_in, win_out, E);
    scatter_resolve_kernel<<<gridE, 256, 0, stream>>>(ei, nid, ea,
                                                      win_in, win_out, xmod, E);

    // (3) [xl||xr] = xmod @ [Wl||Wr] + bias  (bf16 MFMA)
    gemm_mfma_kernel<<<gridG, 256, 0, stream>>>(xmod, Wfrag2 + (size_t)g * 294912,
                                                bl_g[g], br_g[g], xl, xr, N);

    // (4) CSR by dst
    fill_u32_kernel<<<512, 256, 0, stream>>>(deg, 0u, (size_t)N);
    hist_kernel<<<gridE, 256, 0, stream>>>(ei, deg, E);
    scan1_kernel<<<nScanB, 256, 0, stream>>>(deg, offs, bsum, N);
    scan2_kernel<<<1, 256, 0, stream>>>(bsum, nScanB);
    scan3_kernel<<<nScanB, 256, 0, stream>>>(offs, bsum, N);
    place_kernel<<<gridE, 256, 0, stream>>>(ei, offs, csr_eid, E);

    // (5) attention logits, then fused softmax+aggregate+finalize
    edge_e_kernel<<<gridEW, 256, 0, stream>>>(xl, xr, att_g[g], ei, ebuf, E);
    node_gat_kernel<<<gridNd, 256, 0, stream>>>(ei, csr_eid, offs, deg, ebuf,
                                                xl, xmod, bias_g[g], out,
                                                N, E, g * D_DIM);
  }
}

// Round 11
// 4319.133 us; speedup vs baseline: 1.0732x; 1.0732x over previous
//
#include <hip/hip_runtime.h>
#include <cstdint>

// ---------------------------------------------------------------------------
// ForwardBackwardGNN — R11.
//   LSTM: R6 shape (64 edges/block, 4 es, launch_bounds(512,4), cst in VGPR,
//         4 waves/SIMD) + Pg32 fp32 C-in direct loads (removes the unpack
//         temps that caused R6's 84MB spill). HW occupancy quantum is
//         {<=64:8, <=128:4, <=256:2} waves/SIMD (R8/R10 evidence) -> must
//         keep total VGPR+AGPR <= 128.
//   GAT:  per-node argmax + CSR + fused node kernel (R9/R10).
//   N=50000, E=400000, L=16, V=64, EMB=32, H=128, D=373, SID=53.
// ---------------------------------------------------------------------------

#define D_DIM   373
#define SID_N   53
#define IN_COL  161
#define OUT_COL 320
#define HS_STRIDE 136   // u16/row
#define EDGES_T 64      // edges per tile/block
#define N_ES    4       // edge sub-tiles of 16

typedef short bf16x8 __attribute__((ext_vector_type(8)));
typedef float f32x4  __attribute__((ext_vector_type(4)));

#define LOG2E_F 1.4426950408889634f
#define TWO_LOG2E_F 2.8853900817779268f

__device__ __forceinline__ float fast_exp2(float x) {
#if __has_builtin(__builtin_amdgcn_exp2f)
  return __builtin_amdgcn_exp2f(x);
#else
  return exp2f(x);
#endif
}
__device__ __forceinline__ float fast_rcp(float x) {
#if __has_builtin(__builtin_amdgcn_rcpf)
  return __builtin_amdgcn_rcpf(x);
#else
  return 1.0f / x;
#endif
}
__device__ __forceinline__ float sig_ref(float x)  { return 1.0f / (1.0f + __expf(-x)); }
__device__ __forceinline__ float tanh_ref(float x) { return 2.0f / (1.0f + __expf(-2.0f * x)) - 1.0f; }

__device__ __forceinline__ unsigned short f2bf(float f) {
  unsigned u = __float_as_uint(f);
  unsigned r = (u + 0x7fffu + ((u >> 16) & 1u)) >> 16;
  return (unsigned short)r;
}
__device__ __forceinline__ unsigned cvt_pk_bf16(float lo, float hi) {
  unsigned r;
  asm("v_cvt_pk_bf16_f32 %0, %1, %2" : "=v"(r) : "v"(lo), "v"(hi));
  return r;
}
// sig(a)*tanh(b) with A=2^{-a*log2e} (pre-scaled), B=2^{+2b*log2e} (pre-scaled)
__device__ __forceinline__ float pair_sig_tanh(float A, float B) {
  return (B - 1.0f) * fast_rcp((1.0f + A) * (1.0f + B));
}

// ---------------- generic fill ----------------
__global__ void fill_u32_kernel(unsigned* __restrict__ p, unsigned v, size_t n) {
  size_t i = (size_t)blockIdx.x * blockDim.x + threadIdx.x;
  size_t stride = (size_t)gridDim.x * blockDim.x;
  for (; i < n; i += stride) p[i] = v;
}

// ---------------- precompute: Pg32 / FB / MFMA fragments ----------------
// grid = 64, block = 512. Pg32/BfragW carry folded scales (i,f,o:-log2e; g:+2log2e).
__global__ void precompute_kernel(
    const float* __restrict__ embed, const float* __restrict__ Wih_f,
    const float* __restrict__ Whh_f,
    const float* __restrict__ bih_f, const float* __restrict__ bhh_f,
    const float* __restrict__ Wih_r,
    const float* __restrict__ bih_r, const float* __restrict__ bhh_r,
    const float* __restrict__ W1, const float* __restrict__ b1,
    float* __restrict__ Pg32, unsigned short* __restrict__ BfragW,
    unsigned short* __restrict__ Bfrag1, float* __restrict__ FB)
{
  __shared__ float gb[512];
  __shared__ float hb[128];
  int v = blockIdx.x;
  int j = threadIdx.x;          // j = gate*128 + h

  float s = 0.0f;
  if (v != 0) {
    #pragma unroll
    for (int k = 0; k < 32; ++k) s += embed[v * 32 + k] * Wih_f[j * 32 + k];
  }
  s += bih_f[j] + bhh_f[j];

  float gr = bih_r[j] + bhh_r[j];
  if (v != 0) {
    #pragma unroll
    for (int k = 0; k < 32; ++k) gr += embed[v * 32 + k] * Wih_r[j * 32 + k];
  }
  gb[j] = gr;
  __syncthreads();
  if (j < 128) {
    float c = sig_ref(gb[j]) * tanh_ref(gb[256 + j]);
    hb[j] = sig_ref(gb[384 + j]) * tanh_ref(c);
  }
  __syncthreads();

  // Pg32[v][gate][h] = scale(gate) * P[v][gate*128+h]
  { int gate = j >> 7;
    float sc = (gate == 2) ? TWO_LOG2E_F : -LOG2E_F;
    Pg32[(size_t)v * 512 + j] = s * sc; }

  if (j < 32) {
    float s2 = b1[j];
    for (int m = 0; m < 128; ++m) s2 += hb[m] * W1[(128 + m) * 32 + j];
    FB[v * 32 + j] = s2;
  }

  if (v == 0) {
    // BfragW flat = ((nt*4+ks)*64 + lane)*8 + e ; val = scale * Whh_f[n][k]
    for (int f = j; f < 65536; f += 512) {
      int e = f & 7, l = (f >> 3) & 63, ks = (f >> 9) & 3, nt = f >> 11;
      int n = nt * 16 + (l & 15);
      int k = ks * 32 + (l >> 4) * 8 + e;
      float sc = ((nt >> 3) == 2) ? TWO_LOG2E_F : -LOG2E_F;
      BfragW[f] = f2bf(Whh_f[(size_t)n * 128 + k] * sc);
    }
  }
  if (v == 1) {
    // Bfrag1 flat = ((n2*4+ks)*64 + lane)*8 + e ; B[k][q] = W1[k][q] (k<128)
    for (int f = j; f < 4096; f += 512) {
      int e = f & 7, l = (f >> 3) & 63, ks = (f >> 9) & 3, n2 = f >> 11;
      int q = n2 * 16 + (l & 15);
      int k = ks * 32 + (l >> 4) * 8 + e;
      Bfrag1[f] = f2bf(W1[(size_t)k * 32 + q]);
    }
  }
}

// ---------------- MFMA LSTM: 64 edges/block, 8 waves, 1 barrier/step --------
// mfma(A=W-frag, B=H-frag) -> D: col=lane&15=edge(sub), row=(lane>>4)*4+r=hcol.
// Wave wv2 owns hcols [wv2*16,+16) x 4 gates for all 4 edge sub-tiles.
// launch_bounds(512,4): total 128-reg cap -> 4 waves/SIMD.
__global__ __launch_bounds__(512, 4) void lstm_mfma_kernel(
    const int*   __restrict__ tokens,   // [E][16]
    const float* __restrict__ Pg32,     // [64][4][128] f32 (scaled)
    const unsigned short* __restrict__ BfragW,  // [32][4][64][8] bf16 (scaled)
    const unsigned short* __restrict__ Bfrag1,  // [2][4][64][8] bf16
    const float* __restrict__ FB,       // [64][32]
    const float* __restrict__ W2,       // [32]
    const float* __restrict__ b2,
    float* __restrict__ ea, int E, int nTiles)
{
  __shared__ unsigned short Hs[2][EDGES_T * HS_STRIDE];  // 34,816 B
  __shared__ int toks[16][EDGES_T];                      //  4,096 B

  int tid  = threadIdx.x;
  int lane = tid & 63;
  int wv2  = tid >> 6;                  // 0..7
  int l15  = lane & 15;
  int lg   = lane >> 4;                 // 0..3
  int hbase = wv2 * 16 + lg * 4;        // this lane's 4 hcols
  const float* PgL = Pg32 + hbase;      // per-lane base

  // persistent A-frags (W): BW[gate][ks] — 64 regs (AGPR)
  bf16x8 BW[4][4];
  #pragma unroll
  for (int gate = 0; gate < 4; ++gate)
    #pragma unroll
    for (int ks = 0; ks < 4; ++ks)
      BW[gate][ks] = *(const bf16x8*)(BfragW +
          ((size_t)((gate * 8 + wv2) * 4 + ks) * 64 + lane) * 8);
  float4 w2lo = *(const float4*)(W2 + lg * 4);
  float4 w2hi = *(const float4*)(W2 + 16 + lg * 4);
  float b2v = b2[0];

  for (int tile = blockIdx.x; tile < nTiles; tile += gridDim.x) {
    int e0 = tile * EDGES_T;
    for (int i = tid; i < 16 * EDGES_T; i += 512) {   // stage tokens [t][m]
      int m = i >> 4, t = i & 15;
      int ee = e0 + m; if (ee >= E) ee = E - 1;
      toks[t][m] = tokens[(size_t)ee * 16 + t];
    }
    __syncthreads();

    f32x4 cst[N_ES];   // statically indexed (es fully unrolled)
    // ---- step 0: gates = P only (h0=c0=0, f-term vanishes)
    #pragma unroll
    for (int es = 0; es < N_ES; ++es) {
      int eL = es * 16 + l15;
      const float* pb = PgL + (unsigned)toks[0][eL] * 512u;
      f32x4 ai = *(const f32x4*)(pb);         // i (scaled)
      f32x4 ag = *(const f32x4*)(pb + 256);   // g
      f32x4 ao = *(const f32x4*)(pb + 384);   // o
      float h[4];
      #pragma unroll
      for (int r = 0; r < 4; ++r) {
        float A = fast_exp2(ai[r]);
        float B = fast_exp2(ag[r]);
        float O = fast_exp2(ao[r]);
        float cn = pair_sig_tanh(A, B);     // i*g
        cst[es][r] = cn;
        float C = fast_exp2(TWO_LOG2E_F * cn);
        h[r] = pair_sig_tanh(O, C);         // o*tanh(c)
      }
      uint2 hp = make_uint2(cvt_pk_bf16(h[0], h[1]), cvt_pk_bf16(h[2], h[3]));
      *(uint2*)(&Hs[0][eL * HS_STRIDE + hbase]) = hp;
    }
    __syncthreads();

    int cur = 0;
    #pragma unroll 1
    for (int t = 1; t < 16; ++t) {
      #pragma unroll
      for (int es = 0; es < N_ES; ++es) {
        int eL = es * 16 + l15;
        const float* pb = PgL + (unsigned)toks[t][eL] * 512u;
        f32x4 acc[4];
        acc[0] = *(const f32x4*)(pb);         // i
        acc[1] = *(const f32x4*)(pb + 128);   // f
        acc[2] = *(const f32x4*)(pb + 256);   // g
        acc[3] = *(const f32x4*)(pb + 384);   // o

        #pragma unroll
        for (int ks = 0; ks < 4; ++ks) {
          bf16x8 Hf = *(const bf16x8*)(&Hs[cur][eL * HS_STRIDE + ks * 32 + lg * 8]);
          #pragma unroll
          for (int gate = 0; gate < 4; ++gate)
            acc[gate] = __builtin_amdgcn_mfma_f32_16x16x32_bf16(
                BW[gate][ks], Hf, acc[gate], 0, 0, 0);
        }

        float h[4];
        #pragma unroll
        for (int r = 0; r < 4; ++r) {
          float A = fast_exp2(acc[0][r]);
          float F = fast_exp2(acc[1][r]);
          float B = fast_exp2(acc[2][r]);
          float O = fast_exp2(acc[3][r]);
          float ig = pair_sig_tanh(A, B);
          float f  = fast_rcp(1.0f + F);
          float cn = fmaf(f, cst[es][r], ig);
          cst[es][r] = cn;
          float C = fast_exp2(TWO_LOG2E_F * cn);
          h[r] = pair_sig_tanh(O, C);
        }
        uint2 hp = make_uint2(cvt_pk_bf16(h[0], h[1]), cvt_pk_bf16(h[2], h[3]));
        *(uint2*)(&Hs[cur ^ 1][eL * HS_STRIDE + hbase]) = hp;
      }
      cur ^= 1;
      __syncthreads();
    }

    // ---- tail: waves 0..3 each handle edge sub-tile es=wv2
    if (wv2 < N_ES) {
      int eL = wv2 * 16 + l15;
      bf16x8 Hf[4];
      #pragma unroll
      for (int ks = 0; ks < 4; ++ks)
        Hf[ks] = *(const bf16x8*)(&Hs[cur][eL * HS_STRIDE + ks * 32 + lg * 8]);
      f32x4 a2[2];
      a2[0] = (f32x4){0.f, 0.f, 0.f, 0.f};
      a2[1] = (f32x4){0.f, 0.f, 0.f, 0.f};
      #pragma unroll
      for (int ks = 0; ks < 4; ++ks)
        #pragma unroll
        for (int n2 = 0; n2 < 2; ++n2)
          a2[n2] = __builtin_amdgcn_mfma_f32_16x16x32_bf16(
              *(const bf16x8*)(Bfrag1 + ((size_t)(n2 * 4 + ks) * 64 + lane) * 8),
              Hf[ks], a2[n2], 0, 0, 0);
      int v15 = toks[15][eL];
      float4 fb0 = *(const float4*)(FB + v15 * 32 + lg * 4);
      float4 fb1 = *(const float4*)(FB + v15 * 32 + 16 + lg * 4);
      float pr = fmaxf(a2[0][0] + fb0.x, 0.f) * w2lo.x
               + fmaxf(a2[0][1] + fb0.y, 0.f) * w2lo.y
               + fmaxf(a2[0][2] + fb0.z, 0.f) * w2lo.z
               + fmaxf(a2[0][3] + fb0.w, 0.f) * w2lo.w
               + fmaxf(a2[1][0] + fb1.x, 0.f) * w2hi.x
               + fmaxf(a2[1][1] + fb1.y, 0.f) * w2hi.y
               + fmaxf(a2[1][2] + fb1.z, 0.f) * w2hi.z
               + fmaxf(a2[1][3] + fb1.w, 0.f) * w2hi.w;
      pr += __shfl_xor(pr, 16);
      pr += __shfl_xor(pr, 32);
      int eidx = e0 + eL;
      if (lane < 16 && eidx < E) ea[eidx] = fmaxf(pr + b2v, 0.0f);
    }
    __syncthreads();   // before next tile reuses toks/Hs
  }
}

// ---------------- per-node argmax over x[:, :53] (wave per node) -----------
__global__ __launch_bounds__(256) void node_argmax_kernel(
    const float* __restrict__ x, int* __restrict__ nid, int N)
{
  int n = (blockIdx.x * 256 + threadIdx.x) >> 6;
  int lane = threadIdx.x & 63;
  if (n >= N) return;
  float v = (lane < SID_N) ? x[(size_t)n * D_DIM + lane] : -3.4e38f;
  int idx = lane;
  #pragma unroll
  for (int o = 32; o > 0; o >>= 1) {
    float ov = __shfl_down(v, o);
    int   oi = __shfl_down(idx, o);
    if (ov > v || (ov == v && oi < idx)) { v = ov; idx = oi; }
  }
  if (lane == 0) nid[n] = idx;
}

// ---------------- edge winner (last edge wins) + resolve -------------------
__global__ void edge_winner_kernel(
    const int* __restrict__ ei, const int* __restrict__ nid,
    int* __restrict__ win_in, int* __restrict__ win_out, int E)
{
  int e = blockIdx.x * 256 + threadIdx.x;
  if (e >= E) return;
  int s = ei[e];
  int t = ei[E + e];
  atomicMax(&win_in[(size_t)t * SID_N + nid[s]], e);
  atomicMax(&win_out[(size_t)s * SID_N + nid[t]], e);
}

__global__ void scatter_resolve_kernel(
    const int* __restrict__ ei, const int* __restrict__ nid,
    const float* __restrict__ ea,
    const int* __restrict__ win_in, const int* __restrict__ win_out,
    float* __restrict__ x_mod, int E)
{
  int e = blockIdx.x * 256 + threadIdx.x;
  if (e >= E) return;
  int s = ei[e];
  int t = ei[E + e];
  int sid = nid[s], tix = nid[t];
  if (win_in[(size_t)t * SID_N + sid] == e)
    x_mod[(size_t)t * D_DIM + IN_COL + sid] = ea[e];
  if (win_out[(size_t)s * SID_N + tix] == e)
    x_mod[(size_t)s * D_DIM + OUT_COL + tix] = ea[e];
}

// ---------------- pack Wl||Wr into MFMA fragment order ----------------
__global__ void pack_w_kernel(const float* __restrict__ Wl,
                              const float* __restrict__ Wr,
                              unsigned short* __restrict__ Wfrag)
{
  int f = blockIdx.x * 256 + threadIdx.x;
  if (f >= 48 * 12 * 64 * 8) return;
  int e = f & 7, l = (f >> 3) & 63;
  int rest = f >> 9;
  int ks = rest % 12, nt = rest / 12;
  int nl = nt * 16 + (l & 15);
  int k  = ks * 32 + (l >> 4) * 8 + e;
  float val = 0.0f;
  if (k < D_DIM) {
    if (nl < D_DIM)                      val = Wl[(size_t)k * D_DIM + nl];
    else if (nl >= 384 && nl < 384 + D_DIM) val = Wr[(size_t)k * D_DIM + (nl - 384)];
  }
  Wfrag[f] = f2bf(val);
}

// ---------------- fused bf16 MFMA GEMM: [xl||xr] = xmod @ [Wl||Wr] + bias ----
__global__ __launch_bounds__(256, 2) void gemm_mfma_kernel(
    const float* __restrict__ A,               // xmod [N][373] fp32
    const unsigned short* __restrict__ Wfrag,  // [48][12][64][8] bf16
    const float* __restrict__ bl, const float* __restrict__ br,
    float* __restrict__ xl, float* __restrict__ xr, int N)
{
  __shared__ unsigned short As[64][40];
  int tid  = threadIdx.x;
  int lane = tid & 63;
  int wv   = tid >> 6;
  int l15  = lane & 15, lg = lane >> 4;
  int m0   = blockIdx.x * 64;
  int nt   = blockIdx.y * 4 + wv;

  f32x4 acc[4];
  #pragma unroll
  for (int i = 0; i < 4; ++i) acc[i] = (f32x4){0.f, 0.f, 0.f, 0.f};

  int srow = tid >> 2, seg = tid & 3;
  int gr = m0 + srow; if (gr >= N) gr = N - 1;
  const float* arow = A + (size_t)gr * D_DIM;

  for (int ks = 0; ks < 12; ++ks) {
    int c0 = ks * 32 + seg * 8;
    float v[8];
    #pragma unroll
    for (int j = 0; j < 8; ++j) v[j] = (c0 + j < D_DIM) ? arow[c0 + j] : 0.0f;
    unsigned pk0 = cvt_pk_bf16(v[0], v[1]);
    unsigned pk1 = cvt_pk_bf16(v[2], v[3]);
    unsigned pk2 = cvt_pk_bf16(v[4], v[5]);
    unsigned pk3 = cvt_pk_bf16(v[6], v[7]);
    __syncthreads();
    *(uint4*)(&As[srow][seg * 8]) = make_uint4(pk0, pk1, pk2, pk3);
    __syncthreads();

    bf16x8 Bf = *(const bf16x8*)(Wfrag + ((size_t)(nt * 12 + ks) * 64 + lane) * 8);
    #pragma unroll
    for (int msub = 0; msub < 4; ++msub) {
      bf16x8 Af = *(const bf16x8*)(&As[msub * 16 + l15][lg * 8]);
      acc[msub] = __builtin_amdgcn_mfma_f32_16x16x32_bf16(Af, Bf, acc[msub], 0, 0, 0);
    }
  }

  int nl = nt * 16 + l15;
  float* dst = nullptr; int col = 0; const float* bias_ = nullptr;
  if (nl < D_DIM)                         { dst = xl; col = nl;       bias_ = bl; }
  else if (nl >= 384 && nl < 384 + D_DIM) { dst = xr; col = nl - 384; bias_ = br; }
  if (dst) {
    float bv = bias_[col];
    #pragma unroll
    for (int msub = 0; msub < 4; ++msub) {
      #pragma unroll
      for (int r = 0; r < 4; ++r) {
        int m = m0 + msub * 16 + lg * 4 + r;
        if (m < N) dst[(size_t)m * D_DIM + col] = acc[msub][r] + bv;
      }
    }
  }
}

// ---------------- GAT: attention logits (no atomics) ----------------
__global__ __launch_bounds__(256) void edge_e_kernel(
    const float* __restrict__ xl, const float* __restrict__ xr,
    const float* __restrict__ att, const int* __restrict__ ei,
    float* __restrict__ e_buf, int E)
{
  int widx = (blockIdx.x * 256 + threadIdx.x) >> 6;
  int lane = threadIdx.x & 63;
  if (widx >= E) return;
  int s = ei[widx], t = ei[E + widx];
  const float* pl = xl + (size_t)s * D_DIM;
  const float* pr = xr + (size_t)t * D_DIM;
  float acc = 0.0f;
  for (int d = lane; d < D_DIM; d += 64) {
    float m = pl[d] + pr[d];
    m = (m > 0.0f) ? m : 0.2f * m;
    acc += m * att[d];
  }
  #pragma unroll
  for (int o = 32; o > 0; o >>= 1) acc += __shfl_down(acc, o);
  if (lane == 0) e_buf[widx] = acc;
}

// ---------------- CSR build: histogram / scan / placement ----------------
__global__ void hist_kernel(const int* __restrict__ ei, unsigned* __restrict__ deg,
                            int E) {
  int e = blockIdx.x * 256 + threadIdx.x;
  if (e >= E) return;
  atomicAdd(&deg[ei[E + e]], 1u);
}

__global__ void scan1_kernel(const unsigned* __restrict__ deg,
                             unsigned* __restrict__ excl,
                             unsigned* __restrict__ bsum, int n) {
  __shared__ unsigned s[256];
  int t = threadIdx.x;
  int i = blockIdx.x * 256 + t;
  unsigned v = (i < n) ? deg[i] : 0u;
  s[t] = v; __syncthreads();
  #pragma unroll
  for (int o = 1; o < 256; o <<= 1) {
    unsigned u = (t >= o) ? s[t - o] : 0u;
    __syncthreads();
    s[t] += u;
    __syncthreads();
  }
  if (i < n) excl[i] = s[t] - v;
  if (t == 255) bsum[blockIdx.x] = s[255];
}

__global__ void scan2_kernel(unsigned* __restrict__ bsum, int nb) {
  __shared__ unsigned s[256];
  int t = threadIdx.x;
  unsigned v = (t < nb) ? bsum[t] : 0u;
  s[t] = v; __syncthreads();
  #pragma unroll
  for (int o = 1; o < 256; o <<= 1) {
    unsigned u = (t >= o) ? s[t - o] : 0u;
    __syncthreads();
    s[t] += u;
    __syncthreads();
  }
  if (t < nb) bsum[t] = s[t] - v;   // exclusive
}

__global__ void scan3_kernel(unsigned* __restrict__ excl,
                             const unsigned* __restrict__ bsum, int n) {
  int i = blockIdx.x * 256 + threadIdx.x;
  if (i < n) excl[i] += bsum[i >> 8];
}

__global__ void place_kernel(const int* __restrict__ ei,
                             unsigned* __restrict__ offs,
                             int* __restrict__ csr_eid, int E) {
  int e = blockIdx.x * 256 + threadIdx.x;
  if (e >= E) return;
  unsigned j = atomicAdd(&offs[ei[E + e]], 1u);
  csr_eid[j] = e;
}

// ---------------- fused per-node: softmax + aggregate + finalize ----------
__global__ __launch_bounds__(256) void node_gat_kernel(
    const int* __restrict__ ei, const int* __restrict__ csr_eid,
    const unsigned* __restrict__ offs, const unsigned* __restrict__ deg,
    float* __restrict__ ebuf, const float* __restrict__ xl,
    const float* __restrict__ xmod, const float* __restrict__ bias,
    float* __restrict__ out, int N, int E, int goff)
{
  int n = (blockIdx.x * 256 + threadIdx.x) >> 6;
  int lane = threadIdx.x & 63;
  if (n >= N) return;
  unsigned end = offs[n], d = deg[n], start = end - d;

  float mx = -3.4e38f;
  for (unsigned j = start; j < end; ++j)
    mx = fmaxf(mx, ebuf[csr_eid[j]]);
  float den = 0.0f;
  for (unsigned j = start; j < end; ++j) {
    int eid = csr_eid[j];
    float ex = __expf(ebuf[eid] - mx);
    ebuf[eid] = ex;               // reuse in agg pass (exclusive to this wave)
    den += ex;
  }
  float inv = 1.0f / (den + 1e-16f);

  float o0 = 0, o1 = 0, o2 = 0, o3 = 0, o4 = 0, o5 = 0;
  for (unsigned j = start; j < end; ++j) {
    int eid = csr_eid[j];
    float w = ebuf[eid] * inv;
    const float* row = xl + (size_t)ei[eid] * D_DIM;
    o0 = fmaf(w, row[lane], o0);
    o1 = fmaf(w, row[64 + lane], o1);
    o2 = fmaf(w, row[128 + lane], o2);
    o3 = fmaf(w, row[192 + lane], o3);
    o4 = fmaf(w, row[256 + lane], o4);
    if (lane < 53) o5 = fmaf(w, row[320 + lane], o5);
  }

  const float* xm = xmod + (size_t)n * D_DIM;
  float* op = out + (size_t)n * (2 * D_DIM) + goff;
  op[lane]       = fmaxf(o0 + bias[lane]       + xm[lane],       0.0f);
  op[64 + lane]  = fmaxf(o1 + bias[64 + lane]  + xm[64 + lane],  0.0f);
  op[128 + lane] = fmaxf(o2 + bias[128 + lane] + xm[128 + lane], 0.0f);
  op[192 + lane] = fmaxf(o3 + bias[192 + lane] + xm[192 + lane], 0.0f);
  op[256 + lane] = fmaxf(o4 + bias[256 + lane] + xm[256 + lane], 0.0f);
  if (lane < 53)
    op[320 + lane] = fmaxf(o5 + bias[320 + lane] + xm[320 + lane], 0.0f);
}

// ---------------------------------------------------------------------------
extern "C" void kernel_launch(void* const* d_in, const int* in_sizes, int n_in,
                              void* d_out, int out_size, void* d_ws, size_t ws_size,
                              hipStream_t stream)
{
  const float* fx     = (const float*)d_in[0];
  const float* bx     = (const float*)d_in[1];
  const int*   fei    = (const int*)d_in[2];
  const int*   bei    = (const int*)d_in[3];
  const int*   ftk    = (const int*)d_in[4];
  const int*   btk    = (const int*)d_in[5];
  const float* embed  = (const float*)d_in[6];
  const float* Wih_f  = (const float*)d_in[7];
  const float* Whh_f  = (const float*)d_in[8];
  const float* bih_f  = (const float*)d_in[9];
  const float* bhh_f  = (const float*)d_in[10];
  const float* Wih_r  = (const float*)d_in[11];
  // d_in[12] = Whh_r : unused (reverse cell consumes zero state)
  const float* bih_r  = (const float*)d_in[13];
  const float* bhh_r  = (const float*)d_in[14];
  const float* W1     = (const float*)d_in[15];
  const float* b1     = (const float*)d_in[16];
  const float* W2     = (const float*)d_in[17];
  const float* b2     = (const float*)d_in[18];

  const float* Wl_g[2]   = {(const float*)d_in[19], (const float*)d_in[25]};
  const float* bl_g[2]   = {(const float*)d_in[20], (const float*)d_in[26]};
  const float* Wr_g[2]   = {(const float*)d_in[21], (const float*)d_in[27]};
  const float* br_g[2]   = {(const float*)d_in[22], (const float*)d_in[28]};
  const float* att_g[2]  = {(const float*)d_in[23], (const float*)d_in[29]};
  const float* bias_g[2] = {(const float*)d_in[24], (const float*)d_in[30]};
  const float* x_g[2]    = {fx, bx};
  const int*   ei_g[2]   = {fei, bei};
  const int*   tk_g[2]   = {ftk, btk};

  const int E = in_sizes[2] / 2;          // 400000
  const int N = in_sizes[0] / D_DIM;      // 50000

  // ---- workspace layout (byte-based, 256B aligned chunks) ----
  char* wsb = (char*)d_ws;
  size_t off = 0;
  auto alloc = [&](size_t bytes) -> void* {
    void* p = wsb + off; off += (bytes + 255) & ~(size_t)255; return p;
  };
  float* Pg32            = (float*)alloc((size_t)64 * 512 * 4);
  unsigned short* BfragW = (unsigned short*)alloc((size_t)65536 * 2);
  unsigned short* Bfrag1 = (unsigned short*)alloc((size_t)4096 * 2);
  unsigned short* Wfrag2 = (unsigned short*)alloc((size_t)2 * 294912 * 2);
  float* FB    = (float*)alloc((size_t)64 * 32 * 4);
  float* ea    = (float*)alloc((size_t)E * 4);
  float* ebuf  = (float*)alloc((size_t)E * 4);
  int*   nid   = (int*)alloc((size_t)N * 4);
  int*   csr_eid = (int*)alloc((size_t)E * 4);
  unsigned* deg  = (unsigned*)alloc((size_t)N * 4);
  unsigned* offs = (unsigned*)alloc((size_t)N * 4);
  unsigned* bsum = (unsigned*)alloc((size_t)256 * 4);
  int* win_in  = (int*)alloc((size_t)N * SID_N * 4);
  int* win_out = (int*)alloc((size_t)N * SID_N * 4);
  float* xmod  = (float*)alloc((size_t)N * D_DIM * 4);
  float* xl    = (float*)alloc((size_t)N * D_DIM * 4);
  float* xr    = (float*)alloc((size_t)N * D_DIM * 4);
  (void)ws_size; (void)n_in; (void)out_size;

  const size_t win_u32 = (size_t)((char*)win_out - (char*)win_in) / 4
                         + (size_t)N * SID_N;

  float* out = (float*)d_out;

  precompute_kernel<<<64, 512, 0, stream>>>(
      embed, Wih_f, Whh_f, bih_f, bhh_f, Wih_r, bih_r, bhh_r, W1, b1,
      Pg32, BfragW, Bfrag1, FB);
  pack_w_kernel<<<(294912 + 255) / 256, 256, 0, stream>>>(
      Wl_g[0], Wr_g[0], Wfrag2);
  pack_w_kernel<<<(294912 + 255) / 256, 256, 0, stream>>>(
      Wl_g[1], Wr_g[1], Wfrag2 + 294912);

  const int nTiles  = (E + EDGES_T - 1) / EDGES_T;   // 6250
  const int gridL   = nTiles < 2048 ? nTiles : 2048;
  const int gridE   = (E + 255) / 256;
  const int gridEW  = (E + 3) / 4;
  const int nScanB  = (N + 255) / 256;
  const int gridNd  = (N * 64 + 255) / 256;
  dim3 gridG((N + 63) / 64, 12);

  for (int g = 0; g < 2; ++g) {
    const float* x  = x_g[g];
    const int*   ei = ei_g[g];

    // (1) edge scalar via MFMA LSTM
    lstm_mfma_kernel<<<gridL, 512, 0, stream>>>(tk_g[g], Pg32, BfragW, Bfrag1,
                                                FB, W2, b2, ea, E, nTiles);

    // (2) x_mod = copy(x); per-node argmax; last-edge-wins scatter writes
    hipMemcpyAsync(xmod, x, (size_t)N * D_DIM * sizeof(float),
                   hipMemcpyDeviceToDevice, stream);
    node_argmax_kernel<<<gridNd, 256, 0, stream>>>(x, nid, N);
    fill_u32_kernel<<<2048, 256, 0, stream>>>((unsigned*)win_in, 0xFFFFFFFFu,
                                              win_u32);
    edge_winner_kernel<<<gridE, 256, 0, stream>>>(ei, nid, win_in, win_out, E);
    scatter_resolve_kernel<<<gridE, 256, 0, stream>>>(ei, nid, ea,
                                                      win_in, win_out, xmod, E);

    // (3) [xl||xr] = xmod @ [Wl||Wr] + bias  (bf16 MFMA)
    gemm_mfma_kernel<<<gridG, 256, 0, stream>>>(xmod, Wfrag2 + (size_t)g * 294912,
                                                bl_g[g], br_g[g], xl, xr, N);

    // (4) CSR by dst
    fill_u32_kernel<<<512, 256, 0, stream>>>(deg, 0u, (size_t)N);
    hist_kernel<<<gridE, 256, 0, stream>>>(ei, deg, E);
    scan1_kernel<<<nScanB, 256, 0, stream>>>(deg, offs, bsum, N);
    scan2_kernel<<<1, 256, 0, stream>>>(bsum, nScanB);
    scan3_kernel<<<nScanB, 256, 0, stream>>>(offs, bsum, N);
    place_kernel<<<gridE, 256, 0, stream>>>(ei, offs, csr_eid, E);

    // (5) attention logits, then fused softmax+aggregate+finalize
    edge_e_kernel<<<gridEW, 256, 0, stream>>>(xl, xr, att_g[g], ei, ebuf, E);
    node_gat_kernel<<<gridNd, 256, 0, stream>>>(ei, csr_eid, offs, deg, ebuf,
                                                xl, xmod, bias_g[g], out,
                                                N, E, g * D_DIM);
  }
}

// Round 12
// 3595.584 us; speedup vs baseline: 1.2892x; 1.2012x over previous
//
#include <hip/hip_runtime.h>
#include <cstdint>

// ---------------------------------------------------------------------------
// ForwardBackwardGNN — R12: best-of reassembly.
//   LSTM: R6's winning config exactly (64 edges/block, 4 es, bf16 Pg unpack,
//         cst in VGPR, launch_bounds(512,4) -> 4 waves/SIMD, spill-tolerant)
//         + w2/b2 reloaded in tail (-9 persistent VGPRs -> less spill).
//   GAT:  R10 tail (node-argmax precompute + CSR + fused node kernel).
//   N=50000, E=400000, L=16, V=64, EMB=32, H=128, D=373, SID=53.
// ---------------------------------------------------------------------------

#define D_DIM   373
#define SID_N   53
#define IN_COL  161
#define OUT_COL 320
#define HS_STRIDE 136   // u16/row
#define EDGES_T 64      // edges per tile/block
#define N_ES    4       // edge sub-tiles of 16

typedef short bf16x8 __attribute__((ext_vector_type(8)));
typedef float f32x4  __attribute__((ext_vector_type(4)));

#define LOG2E_F 1.4426950408889634f
#define TWO_LOG2E_F 2.8853900817779268f

__device__ __forceinline__ float fast_exp2(float x) {
#if __has_builtin(__builtin_amdgcn_exp2f)
  return __builtin_amdgcn_exp2f(x);
#else
  return exp2f(x);
#endif
}
__device__ __forceinline__ float fast_rcp(float x) {
#if __has_builtin(__builtin_amdgcn_rcpf)
  return __builtin_amdgcn_rcpf(x);
#else
  return 1.0f / x;
#endif
}
__device__ __forceinline__ float sig_ref(float x)  { return 1.0f / (1.0f + __expf(-x)); }
__device__ __forceinline__ float tanh_ref(float x) { return 2.0f / (1.0f + __expf(-2.0f * x)) - 1.0f; }

__device__ __forceinline__ unsigned short f2bf(float f) {
  unsigned u = __float_as_uint(f);
  unsigned r = (u + 0x7fffu + ((u >> 16) & 1u)) >> 16;
  return (unsigned short)r;
}
__device__ __forceinline__ float bflo2f(unsigned u) { return __uint_as_float(u << 16); }
__device__ __forceinline__ float bfhi2f(unsigned u) { return __uint_as_float(u & 0xffff0000u); }
__device__ __forceinline__ unsigned cvt_pk_bf16(float lo, float hi) {
  unsigned r;
  asm("v_cvt_pk_bf16_f32 %0, %1, %2" : "=v"(r) : "v"(lo), "v"(hi));
  return r;
}
// sig(a)*tanh(b) with A=2^{-a*log2e} (pre-scaled), B=2^{+2b*log2e} (pre-scaled)
__device__ __forceinline__ float pair_sig_tanh(float A, float B) {
  return (B - 1.0f) * fast_rcp((1.0f + A) * (1.0f + B));
}

// ---------------- generic fill ----------------
__global__ void fill_u32_kernel(unsigned* __restrict__ p, unsigned v, size_t n) {
  size_t i = (size_t)blockIdx.x * blockDim.x + threadIdx.x;
  size_t stride = (size_t)gridDim.x * blockDim.x;
  for (; i < n; i += stride) p[i] = v;
}

// ---------------- precompute: Pg (bf16, gate-interleaved) / FB / fragments --
// grid = 64, block = 512. Pg/BfragW carry folded scales (i,f,o:-log2e; g:+2log2e).
__global__ void precompute_kernel(
    const float* __restrict__ embed, const float* __restrict__ Wih_f,
    const float* __restrict__ Whh_f,
    const float* __restrict__ bih_f, const float* __restrict__ bhh_f,
    const float* __restrict__ Wih_r,
    const float* __restrict__ bih_r, const float* __restrict__ bhh_r,
    const float* __restrict__ W1, const float* __restrict__ b1,
    unsigned short* __restrict__ Pg, unsigned short* __restrict__ BfragW,
    unsigned short* __restrict__ Bfrag1, float* __restrict__ FB)
{
  __shared__ float ps[512];
  __shared__ float gb[512];
  __shared__ float hb[128];
  int v = blockIdx.x;
  int j = threadIdx.x;

  float s = 0.0f;
  if (v != 0) {
    #pragma unroll
    for (int k = 0; k < 32; ++k) s += embed[v * 32 + k] * Wih_f[j * 32 + k];
  }
  ps[j] = s + bih_f[j] + bhh_f[j];

  float gr = bih_r[j] + bhh_r[j];
  if (v != 0) {
    #pragma unroll
    for (int k = 0; k < 32; ++k) gr += embed[v * 32 + k] * Wih_r[j * 32 + k];
  }
  gb[j] = gr;
  __syncthreads();
  if (j < 128) {
    float c = sig_ref(gb[j]) * tanh_ref(gb[256 + j]);
    hb[j] = sig_ref(gb[384 + j]) * tanh_ref(c);
  }
  __syncthreads();

  // Pg[v][h][g] = bf16(scale(g) * P[v][g*128+h])
  { int h = j >> 2, g = j & 3;
    float sc = (g == 2) ? TWO_LOG2E_F : -LOG2E_F;
    Pg[((size_t)v * 128 + h) * 4 + g] = f2bf(ps[g * 128 + h] * sc); }

  if (j < 32) {
    float s2 = b1[j];
    for (int m = 0; m < 128; ++m) s2 += hb[m] * W1[(128 + m) * 32 + j];
    FB[v * 32 + j] = s2;
  }

  if (v == 0) {
    // BfragW flat = ((nt*4+ks)*64 + lane)*8 + e ; val = scale * Whh_f[n][k]
    for (int f = j; f < 65536; f += 512) {
      int e = f & 7, l = (f >> 3) & 63, ks = (f >> 9) & 3, nt = f >> 11;
      int n = nt * 16 + (l & 15);
      int k = ks * 32 + (l >> 4) * 8 + e;
      float sc = ((nt >> 3) == 2) ? TWO_LOG2E_F : -LOG2E_F;
      BfragW[f] = f2bf(Whh_f[(size_t)n * 128 + k] * sc);
    }
  }
  if (v == 1) {
    // Bfrag1 flat = ((n2*4+ks)*64 + lane)*8 + e ; B[k][q] = W1[k][q] (k<128)
    for (int f = j; f < 4096; f += 512) {
      int e = f & 7, l = (f >> 3) & 63, ks = (f >> 9) & 3, n2 = f >> 11;
      int q = n2 * 16 + (l & 15);
      int k = ks * 32 + (l >> 4) * 8 + e;
      Bfrag1[f] = f2bf(W1[(size_t)k * 32 + q]);
    }
  }
}

// ---------------- MFMA LSTM: 64 edges/block, 8 waves, 1 barrier/step --------
// mfma(A=W-frag, B=H-frag) -> D: col=lane&15=edge(sub), row=(lane>>4)*4+r=hcol.
// Wave wv2 owns hcols [wv2*16,+16) x 4 gates for all 4 edge sub-tiles.
__global__ __launch_bounds__(512, 4) void lstm_mfma_kernel(
    const int*   __restrict__ tokens,   // [E][16]
    const unsigned short* __restrict__ Pg,      // [64][128][4] bf16 (scaled)
    const unsigned short* __restrict__ BfragW,  // [32][4][64][8] bf16 (scaled)
    const unsigned short* __restrict__ Bfrag1,  // [2][4][64][8] bf16
    const float* __restrict__ FB,       // [64][32]
    const float* __restrict__ W2,       // [32]
    const float* __restrict__ b2,
    float* __restrict__ ea, int E, int nTiles)
{
  __shared__ unsigned short Hs[2][EDGES_T * HS_STRIDE];  // 34,816 B
  __shared__ int toks[16][EDGES_T];                      //  4,096 B

  int tid  = threadIdx.x;
  int lane = tid & 63;
  int wv2  = tid >> 6;                  // 0..7
  int l15  = lane & 15;
  int lg   = lane >> 4;                 // 0..3
  int hbase = wv2 * 16 + lg * 4;        // this lane's 4 hcols

  // persistent A-frags (W): BW[gate][ks] — 64 regs (AGPR)
  bf16x8 BW[4][4];
  #pragma unroll
  for (int gate = 0; gate < 4; ++gate)
    #pragma unroll
    for (int ks = 0; ks < 4; ++ks)
      BW[gate][ks] = *(const bf16x8*)(BfragW +
          ((size_t)((gate * 8 + wv2) * 4 + ks) * 64 + lane) * 8);

  for (int tile = blockIdx.x; tile < nTiles; tile += gridDim.x) {
    int e0 = tile * EDGES_T;
    for (int i = tid; i < 16 * EDGES_T; i += 512) {   // stage tokens [t][m]
      int m = i >> 4, t = i & 15;
      int ee = e0 + m; if (ee >= E) ee = E - 1;
      toks[t][m] = tokens[(size_t)ee * 16 + t];
    }
    __syncthreads();

    f32x4 cst[N_ES];   // statically indexed (es fully unrolled)
    // ---- step 0: gates = P only (h0=c0=0, f-term vanishes)
    #pragma unroll
    for (int es = 0; es < N_ES; ++es) {
      int eL = es * 16 + l15;
      int v0 = toks[0][eL];
      const uint4* pp = (const uint4*)(Pg + ((size_t)v0 * 128 + hbase) * 4);
      uint4 pa = pp[0], pb = pp[1];
      float pi[4] = {bflo2f(pa.x), bflo2f(pa.z), bflo2f(pb.x), bflo2f(pb.z)};
      float pg[4] = {bflo2f(pa.y), bflo2f(pa.w), bflo2f(pb.y), bflo2f(pb.w)};
      float po[4] = {bfhi2f(pa.y), bfhi2f(pa.w), bfhi2f(pb.y), bfhi2f(pb.w)};
      float h[4];
      #pragma unroll
      for (int r = 0; r < 4; ++r) {
        float A = fast_exp2(pi[r]);
        float B = fast_exp2(pg[r]);
        float O = fast_exp2(po[r]);
        float cn = pair_sig_tanh(A, B);     // i*g
        cst[es][r] = cn;
        float C = fast_exp2(TWO_LOG2E_F * cn);
        h[r] = pair_sig_tanh(O, C);         // o*tanh(c)
      }
      uint2 hp = make_uint2(cvt_pk_bf16(h[0], h[1]), cvt_pk_bf16(h[2], h[3]));
      *(uint2*)(&Hs[0][eL * HS_STRIDE + hbase]) = hp;
    }
    __syncthreads();

    int cur = 0;
    #pragma unroll 1
    for (int t = 1; t < 16; ++t) {
      #pragma unroll
      for (int es = 0; es < N_ES; ++es) {
        int eL = es * 16 + l15;
        int vt = toks[t][eL];
        const uint4* pp = (const uint4*)(Pg + ((size_t)vt * 128 + hbase) * 4);
        uint4 pa = pp[0], pb = pp[1];
        f32x4 acc[4];
        acc[0] = (f32x4){bflo2f(pa.x), bflo2f(pa.z), bflo2f(pb.x), bflo2f(pb.z)}; // i
        acc[1] = (f32x4){bfhi2f(pa.x), bfhi2f(pa.z), bfhi2f(pb.x), bfhi2f(pb.z)}; // f
        acc[2] = (f32x4){bflo2f(pa.y), bflo2f(pa.w), bflo2f(pb.y), bflo2f(pb.w)}; // g
        acc[3] = (f32x4){bfhi2f(pa.y), bfhi2f(pa.w), bfhi2f(pb.y), bfhi2f(pb.w)}; // o

        #pragma unroll
        for (int ks = 0; ks < 4; ++ks) {
          bf16x8 Hf = *(const bf16x8*)(&Hs[cur][eL * HS_STRIDE + ks * 32 + lg * 8]);
          #pragma unroll
          for (int gate = 0; gate < 4; ++gate)
            acc[gate] = __builtin_amdgcn_mfma_f32_16x16x32_bf16(
                BW[gate][ks], Hf, acc[gate], 0, 0, 0);
        }

        float h[4];
        #pragma unroll
        for (int r = 0; r < 4; ++r) {
          float A = fast_exp2(acc[0][r]);
          float F = fast_exp2(acc[1][r]);
          float B = fast_exp2(acc[2][r]);
          float O = fast_exp2(acc[3][r]);
          float ig = pair_sig_tanh(A, B);
          float f  = fast_rcp(1.0f + F);
          float cn = fmaf(f, cst[es][r], ig);
          cst[es][r] = cn;
          float C = fast_exp2(TWO_LOG2E_F * cn);
          h[r] = pair_sig_tanh(O, C);
        }
        uint2 hp = make_uint2(cvt_pk_bf16(h[0], h[1]), cvt_pk_bf16(h[2], h[3]));
        *(uint2*)(&Hs[cur ^ 1][eL * HS_STRIDE + hbase]) = hp;
      }
      cur ^= 1;
      __syncthreads();
    }

    // ---- tail: waves 0..3 each handle edge sub-tile es=wv2.
    //      W2/b2 loaded HERE (not persistent) to cut live registers.
    if (wv2 < N_ES) {
      int eL = wv2 * 16 + l15;
      bf16x8 Hf[4];
      #pragma unroll
      for (int ks = 0; ks < 4; ++ks)
        Hf[ks] = *(const bf16x8*)(&Hs[cur][eL * HS_STRIDE + ks * 32 + lg * 8]);
      f32x4 a2[2];
      a2[0] = (f32x4){0.f, 0.f, 0.f, 0.f};
      a2[1] = (f32x4){0.f, 0.f, 0.f, 0.f};
      #pragma unroll
      for (int ks = 0; ks < 4; ++ks)
        #pragma unroll
        for (int n2 = 0; n2 < 2; ++n2)
          a2[n2] = __builtin_amdgcn_mfma_f32_16x16x32_bf16(
              *(const bf16x8*)(Bfrag1 + ((size_t)(n2 * 4 + ks) * 64 + lane) * 8),
              Hf[ks], a2[n2], 0, 0, 0);
      float4 w2lo = *(const float4*)(W2 + lg * 4);
      float4 w2hi = *(const float4*)(W2 + 16 + lg * 4);
      float b2v = b2[0];
      int v15 = toks[15][eL];
      float4 fb0 = *(const float4*)(FB + v15 * 32 + lg * 4);
      float4 fb1 = *(const float4*)(FB + v15 * 32 + 16 + lg * 4);
      float pr = fmaxf(a2[0][0] + fb0.x, 0.f) * w2lo.x
               + fmaxf(a2[0][1] + fb0.y, 0.f) * w2lo.y
               + fmaxf(a2[0][2] + fb0.z, 0.f) * w2lo.z
               + fmaxf(a2[0][3] + fb0.w, 0.f) * w2lo.w
               + fmaxf(a2[1][0] + fb1.x, 0.f) * w2hi.x
               + fmaxf(a2[1][1] + fb1.y, 0.f) * w2hi.y
               + fmaxf(a2[1][2] + fb1.z, 0.f) * w2hi.z
               + fmaxf(a2[1][3] + fb1.w, 0.f) * w2hi.w;
      pr += __shfl_xor(pr, 16);
      pr += __shfl_xor(pr, 32);
      int eidx = e0 + eL;
      if (lane < 16 && eidx < E) ea[eidx] = fmaxf(pr + b2v, 0.0f);
    }
    __syncthreads();   // before next tile reuses toks/Hs
  }
}

// ---------------- per-node argmax over x[:, :53] (wave per node) -----------
__global__ __launch_bounds__(256) void node_argmax_kernel(
    const float* __restrict__ x, int* __restrict__ nid, int N)
{
  int n = (blockIdx.x * 256 + threadIdx.x) >> 6;
  int lane = threadIdx.x & 63;
  if (n >= N) return;
  float v = (lane < SID_N) ? x[(size_t)n * D_DIM + lane] : -3.4e38f;
  int idx = lane;
  #pragma unroll
  for (int o = 32; o > 0; o >>= 1) {
    float ov = __shfl_down(v, o);
    int   oi = __shfl_down(idx, o);
    if (ov > v || (ov == v && oi < idx)) { v = ov; idx = oi; }
  }
  if (lane == 0) nid[n] = idx;
}

// ---------------- edge winner (last edge wins) + resolve -------------------
__global__ void edge_winner_kernel(
    const int* __restrict__ ei, const int* __restrict__ nid,
    int* __restrict__ win_in, int* __restrict__ win_out, int E)
{
  int e = blockIdx.x * 256 + threadIdx.x;
  if (e >= E) return;
  int s = ei[e];
  int t = ei[E + e];
  atomicMax(&win_in[(size_t)t * SID_N + nid[s]], e);
  atomicMax(&win_out[(size_t)s * SID_N + nid[t]], e);
}

__global__ void scatter_resolve_kernel(
    const int* __restrict__ ei, const int* __restrict__ nid,
    const float* __restrict__ ea,
    const int* __restrict__ win_in, const int* __restrict__ win_out,
    float* __restrict__ x_mod, int E)
{
  int e = blockIdx.x * 256 + threadIdx.x;
  if (e >= E) return;
  int s = ei[e];
  int t = ei[E + e];
  int sid = nid[s], tix = nid[t];
  if (win_in[(size_t)t * SID_N + sid] == e)
    x_mod[(size_t)t * D_DIM + IN_COL + sid] = ea[e];
  if (win_out[(size_t)s * SID_N + tix] == e)
    x_mod[(size_t)s * D_DIM + OUT_COL + tix] = ea[e];
}

// ---------------- pack Wl||Wr into MFMA fragment order ----------------
__global__ void pack_w_kernel(const float* __restrict__ Wl,
                              const float* __restrict__ Wr,
                              unsigned short* __restrict__ Wfrag)
{
  int f = blockIdx.x * 256 + threadIdx.x;
  if (f >= 48 * 12 * 64 * 8) return;
  int e = f & 7, l = (f >> 3) & 63;
  int rest = f >> 9;
  int ks = rest % 12, nt = rest / 12;
  int nl = nt * 16 + (l & 15);
  int k  = ks * 32 + (l >> 4) * 8 + e;
  float val = 0.0f;
  if (k < D_DIM) {
    if (nl < D_DIM)                      val = Wl[(size_t)k * D_DIM + nl];
    else if (nl >= 384 && nl < 384 + D_DIM) val = Wr[(size_t)k * D_DIM + (nl - 384)];
  }
  Wfrag[f] = f2bf(val);
}

// ---------------- fused bf16 MFMA GEMM: [xl||xr] = xmod @ [Wl||Wr] + bias ----
__global__ __launch_bounds__(256, 2) void gemm_mfma_kernel(
    const float* __restrict__ A,               // xmod [N][373] fp32
    const unsigned short* __restrict__ Wfrag,  // [48][12][64][8] bf16
    const float* __restrict__ bl, const float* __restrict__ br,
    float* __restrict__ xl, float* __restrict__ xr, int N)
{
  __shared__ unsigned short As[64][40];
  int tid  = threadIdx.x;
  int lane = tid & 63;
  int wv   = tid >> 6;
  int l15  = lane & 15, lg = lane >> 4;
  int m0   = blockIdx.x * 64;
  int nt   = blockIdx.y * 4 + wv;

  f32x4 acc[4];
  #pragma unroll
  for (int i = 0; i < 4; ++i) acc[i] = (f32x4){0.f, 0.f, 0.f, 0.f};

  int srow = tid >> 2, seg = tid & 3;
  int gr = m0 + srow; if (gr >= N) gr = N - 1;
  const float* arow = A + (size_t)gr * D_DIM;

  for (int ks = 0; ks < 12; ++ks) {
    int c0 = ks * 32 + seg * 8;
    float v[8];
    #pragma unroll
    for (int j = 0; j < 8; ++j) v[j] = (c0 + j < D_DIM) ? arow[c0 + j] : 0.0f;
    unsigned pk0 = cvt_pk_bf16(v[0], v[1]);
    unsigned pk1 = cvt_pk_bf16(v[2], v[3]);
    unsigned pk2 = cvt_pk_bf16(v[4], v[5]);
    unsigned pk3 = cvt_pk_bf16(v[6], v[7]);
    __syncthreads();
    *(uint4*)(&As[srow][seg * 8]) = make_uint4(pk0, pk1, pk2, pk3);
    __syncthreads();

    bf16x8 Bf = *(const bf16x8*)(Wfrag + ((size_t)(nt * 12 + ks) * 64 + lane) * 8);
    #pragma unroll
    for (int msub = 0; msub < 4; ++msub) {
      bf16x8 Af = *(const bf16x8*)(&As[msub * 16 + l15][lg * 8]);
      acc[msub] = __builtin_amdgcn_mfma_f32_16x16x32_bf16(Af, Bf, acc[msub], 0, 0, 0);
    }
  }

  int nl = nt * 16 + l15;
  float* dst = nullptr; int col = 0; const float* bias_ = nullptr;
  if (nl < D_DIM)                         { dst = xl; col = nl;       bias_ = bl; }
  else if (nl >= 384 && nl < 384 + D_DIM) { dst = xr; col = nl - 384; bias_ = br; }
  if (dst) {
    float bv = bias_[col];
    #pragma unroll
    for (int msub = 0; msub < 4; ++msub) {
      #pragma unroll
      for (int r = 0; r < 4; ++r) {
        int m = m0 + msub * 16 + lg * 4 + r;
        if (m < N) dst[(size_t)m * D_DIM + col] = acc[msub][r] + bv;
      }
    }
  }
}

// ---------------- GAT: attention logits (no atomics) ----------------
__global__ __launch_bounds__(256) void edge_e_kernel(
    const float* __restrict__ xl, const float* __restrict__ xr,
    const float* __restrict__ att, const int* __restrict__ ei,
    float* __restrict__ e_buf, int E)
{
  int widx = (blockIdx.x * 256 + threadIdx.x) >> 6;
  int lane = threadIdx.x & 63;
  if (widx >= E) return;
  int s = ei[widx], t = ei[E + widx];
  const float* pl = xl + (size_t)s * D_DIM;
  const float* pr = xr + (size_t)t * D_DIM;
  float acc = 0.0f;
  for (int d = lane; d < D_DIM; d += 64) {
    float m = pl[d] + pr[d];
    m = (m > 0.0f) ? m : 0.2f * m;
    acc += m * att[d];
  }
  #pragma unroll
  for (int o = 32; o > 0; o >>= 1) acc += __shfl_down(acc, o);
  if (lane == 0) e_buf[widx] = acc;
}

// ---------------- CSR build: histogram / scan / placement ----------------
__global__ void hist_kernel(const int* __restrict__ ei, unsigned* __restrict__ deg,
                            int E) {
  int e = blockIdx.x * 256 + threadIdx.x;
  if (e >= E) return;
  atomicAdd(&deg[ei[E + e]], 1u);
}

__global__ void scan1_kernel(const unsigned* __restrict__ deg,
                             unsigned* __restrict__ excl,
                             unsigned* __restrict__ bsum, int n) {
  __shared__ unsigned s[256];
  int t = threadIdx.x;
  int i = blockIdx.x * 256 + t;
  unsigned v = (i < n) ? deg[i] : 0u;
  s[t] = v; __syncthreads();
  #pragma unroll
  for (int o = 1; o < 256; o <<= 1) {
    unsigned u = (t >= o) ? s[t - o] : 0u;
    __syncthreads();
    s[t] += u;
    __syncthreads();
  }
  if (i < n) excl[i] = s[t] - v;
  if (t == 255) bsum[blockIdx.x] = s[255];
}

__global__ void scan2_kernel(unsigned* __restrict__ bsum, int nb) {
  __shared__ unsigned s[256];
  int t = threadIdx.x;
  unsigned v = (t < nb) ? bsum[t] : 0u;
  s[t] = v; __syncthreads();
  #pragma unroll
  for (int o = 1; o < 256; o <<= 1) {
    unsigned u = (t >= o) ? s[t - o] : 0u;
    __syncthreads();
    s[t] += u;
    __syncthreads();
  }
  if (t < nb) bsum[t] = s[t] - v;   // exclusive
}

__global__ void scan3_kernel(unsigned* __restrict__ excl,
                             const unsigned* __restrict__ bsum, int n) {
  int i = blockIdx.x * 256 + threadIdx.x;
  if (i < n) excl[i] += bsum[i >> 8];
}

__global__ void place_kernel(const int* __restrict__ ei,
                             unsigned* __restrict__ offs,
                             int* __restrict__ csr_eid, int E) {
  int e = blockIdx.x * 256 + threadIdx.x;
  if (e >= E) return;
  unsigned j = atomicAdd(&offs[ei[E + e]], 1u);
  csr_eid[j] = e;
}

// ---------------- fused per-node: softmax + aggregate + finalize ----------
__global__ __launch_bounds__(256) void node_gat_kernel(
    const int* __restrict__ ei, const int* __restrict__ csr_eid,
    const unsigned* __restrict__ offs, const unsigned* __restrict__ deg,
    float* __restrict__ ebuf, const float* __restrict__ xl,
    const float* __restrict__ xmod, const float* __restrict__ bias,
    float* __restrict__ out, int N, int E, int goff)
{
  int n = (blockIdx.x * 256 + threadIdx.x) >> 6;
  int lane = threadIdx.x & 63;
  if (n >= N) return;
  unsigned end = offs[n], d = deg[n], start = end - d;

  float mx = -3.4e38f;
  for (unsigned j = start; j < end; ++j)
    mx = fmaxf(mx, ebuf[csr_eid[j]]);
  float den = 0.0f;
  for (unsigned j = start; j < end; ++j) {
    int eid = csr_eid[j];
    float ex = __expf(ebuf[eid] - mx);
    ebuf[eid] = ex;               // reuse in agg pass (exclusive to this wave)
    den += ex;
  }
  float inv = 1.0f / (den + 1e-16f);

  float o0 = 0, o1 = 0, o2 = 0, o3 = 0, o4 = 0, o5 = 0;
  for (unsigned j = start; j < end; ++j) {
    int eid = csr_eid[j];
    float w = ebuf[eid] * inv;
    const float* row = xl + (size_t)ei[eid] * D_DIM;
    o0 = fmaf(w, row[lane], o0);
    o1 = fmaf(w, row[64 + lane], o1);
    o2 = fmaf(w, row[128 + lane], o2);
    o3 = fmaf(w, row[192 + lane], o3);
    o4 = fmaf(w, row[256 + lane], o4);
    if (lane < 53) o5 = fmaf(w, row[320 + lane], o5);
  }

  const float* xm = xmod + (size_t)n * D_DIM;
  float* op = out + (size_t)n * (2 * D_DIM) + goff;
  op[lane]       = fmaxf(o0 + bias[lane]       + xm[lane],       0.0f);
  op[64 + lane]  = fmaxf(o1 + bias[64 + lane]  + xm[64 + lane],  0.0f);
  op[128 + lane] = fmaxf(o2 + bias[128 + lane] + xm[128 + lane], 0.0f);
  op[192 + lane] = fmaxf(o3 + bias[192 + lane] + xm[192 + lane], 0.0f);
  op[256 + lane] = fmaxf(o4 + bias[256 + lane] + xm[256 + lane], 0.0f);
  if (lane < 53)
    op[320 + lane] = fmaxf(o5 + bias[320 + lane] + xm[320 + lane], 0.0f);
}

// ---------------------------------------------------------------------------
extern "C" void kernel_launch(void* const* d_in, const int* in_sizes, int n_in,
                              void* d_out, int out_size, void* d_ws, size_t ws_size,
                              hipStream_t stream)
{
  const float* fx     = (const float*)d_in[0];
  const float* bx     = (const float*)d_in[1];
  const int*   fei    = (const int*)d_in[2];
  const int*   bei    = (const int*)d_in[3];
  const int*   ftk    = (const int*)d_in[4];
  const int*   btk    = (const int*)d_in[5];
  const float* embed  = (const float*)d_in[6];
  const float* Wih_f  = (const float*)d_in[7];
  const float* Whh_f  = (const float*)d_in[8];
  const float* bih_f  = (const float*)d_in[9];
  const float* bhh_f  = (const float*)d_in[10];
  const float* Wih_r  = (const float*)d_in[11];
  // d_in[12] = Whh_r : unused (reverse cell consumes zero state)
  const float* bih_r  = (const float*)d_in[13];
  const float* bhh_r  = (const float*)d_in[14];
  const float* W1     = (const float*)d_in[15];
  const float* b1     = (const float*)d_in[16];
  const float* W2     = (const float*)d_in[17];
  const float* b2     = (const float*)d_in[18];

  const float* Wl_g[2]   = {(const float*)d_in[19], (const float*)d_in[25]};
  const float* bl_g[2]   = {(const float*)d_in[20], (const float*)d_in[26]};
  const float* Wr_g[2]   = {(const float*)d_in[21], (const float*)d_in[27]};
  const float* br_g[2]   = {(const float*)d_in[22], (const float*)d_in[28]};
  const float* att_g[2]  = {(const float*)d_in[23], (const float*)d_in[29]};
  const float* bias_g[2] = {(const float*)d_in[24], (const float*)d_in[30]};
  const float* x_g[2]    = {fx, bx};
  const int*   ei_g[2]   = {fei, bei};
  const int*   tk_g[2]   = {ftk, btk};

  const int E = in_sizes[2] / 2;          // 400000
  const int N = in_sizes[0] / D_DIM;      // 50000

  // ---- workspace layout (byte-based, 256B aligned chunks) ----
  char* wsb = (char*)d_ws;
  size_t off = 0;
  auto alloc = [&](size_t bytes) -> void* {
    void* p = wsb + off; off += (bytes + 255) & ~(size_t)255; return p;
  };
  unsigned short* Pg     = (unsigned short*)alloc((size_t)64 * 128 * 4 * 2);
  unsigned short* BfragW = (unsigned short*)alloc((size_t)65536 * 2);
  unsigned short* Bfrag1 = (unsigned short*)alloc((size_t)4096 * 2);
  unsigned short* Wfrag2 = (unsigned short*)alloc((size_t)2 * 294912 * 2);
  float* FB    = (float*)alloc((size_t)64 * 32 * 4);
  float* ea    = (float*)alloc((size_t)E * 4);
  float* ebuf  = (float*)alloc((size_t)E * 4);
  int*   nid   = (int*)alloc((size_t)N * 4);
  int*   csr_eid = (int*)alloc((size_t)E * 4);
  unsigned* deg  = (unsigned*)alloc((size_t)N * 4);
  unsigned* offs = (unsigned*)alloc((size_t)N * 4);
  unsigned* bsum = (unsigned*)alloc((size_t)256 * 4);
  int* win_in  = (int*)alloc((size_t)N * SID_N * 4);
  int* win_out = (int*)alloc((size_t)N * SID_N * 4);
  float* xmod  = (float*)alloc((size_t)N * D_DIM * 4);
  float* xl    = (float*)alloc((size_t)N * D_DIM * 4);
  float* xr    = (float*)alloc((size_t)N * D_DIM * 4);
  (void)ws_size; (void)n_in; (void)out_size;

  const size_t win_u32 = (size_t)((char*)win_out - (char*)win_in) / 4
                         + (size_t)N * SID_N;

  float* out = (float*)d_out;

  precompute_kernel<<<64, 512, 0, stream>>>(
      embed, Wih_f, Whh_f, bih_f, bhh_f, Wih_r, bih_r, bhh_r, W1, b1,
      Pg, BfragW, Bfrag1, FB);
  pack_w_kernel<<<(294912 + 255) / 256, 256, 0, stream>>>(
      Wl_g[0], Wr_g[0], Wfrag2);
  pack_w_kernel<<<(294912 + 255) / 256, 256, 0, stream>>>(
      Wl_g[1], Wr_g[1], Wfrag2 + 294912);

  const int nTiles  = (E + EDGES_T - 1) / EDGES_T;   // 6250
  const int gridL   = nTiles < 2048 ? nTiles : 2048;
  const int gridE   = (E + 255) / 256;
  const int gridEW  = (E + 3) / 4;
  const int nScanB  = (N + 255) / 256;
  const int gridNd  = (N * 64 + 255) / 256;
  dim3 gridG((N + 63) / 64, 12);

  for (int g = 0; g < 2; ++g) {
    const float* x  = x_g[g];
    const int*   ei = ei_g[g];

    // (1) edge scalar via MFMA LSTM
    lstm_mfma_kernel<<<gridL, 512, 0, stream>>>(tk_g[g], Pg, BfragW, Bfrag1,
                                                FB, W2, b2, ea, E, nTiles);

    // (2) x_mod = copy(x); per-node argmax; last-edge-wins scatter writes
    hipMemcpyAsync(xmod, x, (size_t)N * D_DIM * sizeof(float),
                   hipMemcpyDeviceToDevice, stream);
    node_argmax_kernel<<<gridNd, 256, 0, stream>>>(x, nid, N);
    fill_u32_kernel<<<2048, 256, 0, stream>>>((unsigned*)win_in, 0xFFFFFFFFu,
                                              win_u32);
    edge_winner_kernel<<<gridE, 256, 0, stream>>>(ei, nid, win_in, win_out, E);
    scatter_resolve_kernel<<<gridE, 256, 0, stream>>>(ei, nid, ea,
                                                      win_in, win_out, xmod, E);

    // (3) [xl||xr] = xmod @ [Wl||Wr] + bias  (bf16 MFMA)
    gemm_mfma_kernel<<<gridG, 256, 0, stream>>>(xmod, Wfrag2 + (size_t)g * 294912,
                                                bl_g[g], br_g[g], xl, xr, N);

    // (4) CSR by dst
    fill_u32_kernel<<<512, 256, 0, stream>>>(deg, 0u, (size_t)N);
    hist_kernel<<<gridE, 256, 0, stream>>>(ei, deg, E);
    scan1_kernel<<<nScanB, 256, 0, stream>>>(deg, offs, bsum, N);
    scan2_kernel<<<1, 256, 0, stream>>>(bsum, nScanB);
    scan3_kernel<<<nScanB, 256, 0, stream>>>(offs, bsum, N);
    place_kernel<<<gridE, 256, 0, stream>>>(ei, offs, csr_eid, E);

    // (5) attention logits, then fused softmax+aggregate+finalize
    edge_e_kernel<<<gridEW, 256, 0, stream>>>(xl, xr, att_g[g], ei, ebuf, E);
    node_gat_kernel<<<gridNd, 256, 0, stream>>>(ei, csr_eid, offs, deg, ebuf,
                                                xl, xmod, bias_g[g], out,
                                                N, E, g * D_DIM);
  }
}

// Round 13
// 3524.693 us; speedup vs baseline: 1.3151x; 1.0201x over previous
//
#include <hip/hip_runtime.h>
#include <cstdint>

// ---------------------------------------------------------------------------
// ForwardBackwardGNN — R13.
//   LSTM: R12 structure with N_ES=3 / EDGES_T=48 — the untested lattice cell:
//         live set ~120 <= 128-reg cap -> targets zero spill AT 4 waves/SIMD
//         (R12: spill latency-hidden but its INSTRUCTIONS ~ half of VALU work).
//   GAT:  CSR built first; edge_e is wave-per-node over CSR (xr/att cached
//         in registers per node, -525MB HBM/graph); fused node kernel.
//   N=50000, E=400000, L=16, V=64, EMB=32, H=128, D=373, SID=53.
// ---------------------------------------------------------------------------

#define D_DIM   373
#define SID_N   53
#define IN_COL  161
#define OUT_COL 320
#define HS_STRIDE 136   // u16/row
#define EDGES_T 48      // edges per tile/block
#define N_ES    3       // edge sub-tiles of 16

typedef short bf16x8 __attribute__((ext_vector_type(8)));
typedef float f32x4  __attribute__((ext_vector_type(4)));

#define LOG2E_F 1.4426950408889634f
#define TWO_LOG2E_F 2.8853900817779268f

__device__ __forceinline__ float fast_exp2(float x) {
#if __has_builtin(__builtin_amdgcn_exp2f)
  return __builtin_amdgcn_exp2f(x);
#else
  return exp2f(x);
#endif
}
__device__ __forceinline__ float fast_rcp(float x) {
#if __has_builtin(__builtin_amdgcn_rcpf)
  return __builtin_amdgcn_rcpf(x);
#else
  return 1.0f / x;
#endif
}
__device__ __forceinline__ float sig_ref(float x)  { return 1.0f / (1.0f + __expf(-x)); }
__device__ __forceinline__ float tanh_ref(float x) { return 2.0f / (1.0f + __expf(-2.0f * x)) - 1.0f; }

__device__ __forceinline__ unsigned short f2bf(float f) {
  unsigned u = __float_as_uint(f);
  unsigned r = (u + 0x7fffu + ((u >> 16) & 1u)) >> 16;
  return (unsigned short)r;
}
__device__ __forceinline__ float bflo2f(unsigned u) { return __uint_as_float(u << 16); }
__device__ __forceinline__ float bfhi2f(unsigned u) { return __uint_as_float(u & 0xffff0000u); }
__device__ __forceinline__ unsigned cvt_pk_bf16(float lo, float hi) {
  unsigned r;
  asm("v_cvt_pk_bf16_f32 %0, %1, %2" : "=v"(r) : "v"(lo), "v"(hi));
  return r;
}
// sig(a)*tanh(b) with A=2^{-a*log2e} (pre-scaled), B=2^{+2b*log2e} (pre-scaled)
__device__ __forceinline__ float pair_sig_tanh(float A, float B) {
  return (B - 1.0f) * fast_rcp((1.0f + A) * (1.0f + B));
}

// ---------------- generic fill ----------------
__global__ void fill_u32_kernel(unsigned* __restrict__ p, unsigned v, size_t n) {
  size_t i = (size_t)blockIdx.x * blockDim.x + threadIdx.x;
  size_t stride = (size_t)gridDim.x * blockDim.x;
  for (; i < n; i += stride) p[i] = v;
}

// ---------------- precompute: Pg (bf16, gate-interleaved) / FB / fragments --
__global__ void precompute_kernel(
    const float* __restrict__ embed, const float* __restrict__ Wih_f,
    const float* __restrict__ Whh_f,
    const float* __restrict__ bih_f, const float* __restrict__ bhh_f,
    const float* __restrict__ Wih_r,
    const float* __restrict__ bih_r, const float* __restrict__ bhh_r,
    const float* __restrict__ W1, const float* __restrict__ b1,
    unsigned short* __restrict__ Pg, unsigned short* __restrict__ BfragW,
    unsigned short* __restrict__ Bfrag1, float* __restrict__ FB)
{
  __shared__ float ps[512];
  __shared__ float gb[512];
  __shared__ float hb[128];
  int v = blockIdx.x;
  int j = threadIdx.x;

  float s = 0.0f;
  if (v != 0) {
    #pragma unroll
    for (int k = 0; k < 32; ++k) s += embed[v * 32 + k] * Wih_f[j * 32 + k];
  }
  ps[j] = s + bih_f[j] + bhh_f[j];

  float gr = bih_r[j] + bhh_r[j];
  if (v != 0) {
    #pragma unroll
    for (int k = 0; k < 32; ++k) gr += embed[v * 32 + k] * Wih_r[j * 32 + k];
  }
  gb[j] = gr;
  __syncthreads();
  if (j < 128) {
    float c = sig_ref(gb[j]) * tanh_ref(gb[256 + j]);
    hb[j] = sig_ref(gb[384 + j]) * tanh_ref(c);
  }
  __syncthreads();

  // Pg[v][h][g] = bf16(scale(g) * P[v][g*128+h])
  { int h = j >> 2, g = j & 3;
    float sc = (g == 2) ? TWO_LOG2E_F : -LOG2E_F;
    Pg[((size_t)v * 128 + h) * 4 + g] = f2bf(ps[g * 128 + h] * sc); }

  if (j < 32) {
    float s2 = b1[j];
    for (int m = 0; m < 128; ++m) s2 += hb[m] * W1[(128 + m) * 32 + j];
    FB[v * 32 + j] = s2;
  }

  if (v == 0) {
    // BfragW flat = ((nt*4+ks)*64 + lane)*8 + e ; val = scale * Whh_f[n][k]
    for (int f = j; f < 65536; f += 512) {
      int e = f & 7, l = (f >> 3) & 63, ks = (f >> 9) & 3, nt = f >> 11;
      int n = nt * 16 + (l & 15);
      int k = ks * 32 + (l >> 4) * 8 + e;
      float sc = ((nt >> 3) == 2) ? TWO_LOG2E_F : -LOG2E_F;
      BfragW[f] = f2bf(Whh_f[(size_t)n * 128 + k] * sc);
    }
  }
  if (v == 1) {
    // Bfrag1 flat = ((n2*4+ks)*64 + lane)*8 + e ; B[k][q] = W1[k][q] (k<128)
    for (int f = j; f < 4096; f += 512) {
      int e = f & 7, l = (f >> 3) & 63, ks = (f >> 9) & 3, n2 = f >> 11;
      int q = n2 * 16 + (l & 15);
      int k = ks * 32 + (l >> 4) * 8 + e;
      Bfrag1[f] = f2bf(W1[(size_t)k * 32 + q]);
    }
  }
}

// ---------------- MFMA LSTM: 48 edges/block (3 es), 8 waves, 1 barrier/step -
// mfma(A=W-frag, B=H-frag) -> D: col=lane&15=edge(sub), row=(lane>>4)*4+r=hcol.
// Wave wv2 owns hcols [wv2*16,+16) x 4 gates for all 3 edge sub-tiles.
__global__ __launch_bounds__(512, 4) void lstm_mfma_kernel(
    const int*   __restrict__ tokens,   // [E][16]
    const unsigned short* __restrict__ Pg,      // [64][128][4] bf16 (scaled)
    const unsigned short* __restrict__ BfragW,  // [32][4][64][8] bf16 (scaled)
    const unsigned short* __restrict__ Bfrag1,  // [2][4][64][8] bf16
    const float* __restrict__ FB,       // [64][32]
    const float* __restrict__ W2,       // [32]
    const float* __restrict__ b2,
    float* __restrict__ ea, int E, int nTiles)
{
  __shared__ unsigned short Hs[2][EDGES_T * HS_STRIDE];  // 26,112 B
  __shared__ int toks[16][EDGES_T];                      //  3,072 B

  int tid  = threadIdx.x;
  int lane = tid & 63;
  int wv2  = tid >> 6;                  // 0..7
  int l15  = lane & 15;
  int lg   = lane >> 4;                 // 0..3
  int hbase = wv2 * 16 + lg * 4;        // this lane's 4 hcols

  // persistent A-frags (W): BW[gate][ks] — 64 regs (AGPR)
  bf16x8 BW[4][4];
  #pragma unroll
  for (int gate = 0; gate < 4; ++gate)
    #pragma unroll
    for (int ks = 0; ks < 4; ++ks)
      BW[gate][ks] = *(const bf16x8*)(BfragW +
          ((size_t)((gate * 8 + wv2) * 4 + ks) * 64 + lane) * 8);

  for (int tile = blockIdx.x; tile < nTiles; tile += gridDim.x) {
    int e0 = tile * EDGES_T;
    for (int i = tid; i < 16 * EDGES_T; i += 512) {   // stage tokens [t][m]
      int m = i >> 4, t = i & 15;
      int ee = e0 + m; if (ee >= E) ee = E - 1;
      toks[t][m] = tokens[(size_t)ee * 16 + t];
    }
    __syncthreads();

    f32x4 cst[N_ES];   // statically indexed (es fully unrolled)
    // ---- step 0: gates = P only (h0=c0=0, f-term vanishes)
    #pragma unroll
    for (int es = 0; es < N_ES; ++es) {
      int eL = es * 16 + l15;
      int v0 = toks[0][eL];
      const uint4* pp = (const uint4*)(Pg + ((size_t)v0 * 128 + hbase) * 4);
      uint4 pa = pp[0], pb = pp[1];
      float pi[4] = {bflo2f(pa.x), bflo2f(pa.z), bflo2f(pb.x), bflo2f(pb.z)};
      float pg[4] = {bflo2f(pa.y), bflo2f(pa.w), bflo2f(pb.y), bflo2f(pb.w)};
      float po[4] = {bfhi2f(pa.y), bfhi2f(pa.w), bfhi2f(pb.y), bfhi2f(pb.w)};
      float h[4];
      #pragma unroll
      for (int r = 0; r < 4; ++r) {
        float A = fast_exp2(pi[r]);
        float B = fast_exp2(pg[r]);
        float O = fast_exp2(po[r]);
        float cn = pair_sig_tanh(A, B);     // i*g
        cst[es][r] = cn;
        float C = fast_exp2(TWO_LOG2E_F * cn);
        h[r] = pair_sig_tanh(O, C);         // o*tanh(c)
      }
      uint2 hp = make_uint2(cvt_pk_bf16(h[0], h[1]), cvt_pk_bf16(h[2], h[3]));
      *(uint2*)(&Hs[0][eL * HS_STRIDE + hbase]) = hp;
    }
    __syncthreads();

    int cur = 0;
    #pragma unroll 1
    for (int t = 1; t < 16; ++t) {
      #pragma unroll
      for (int es = 0; es < N_ES; ++es) {
        int eL = es * 16 + l15;
        int vt = toks[t][eL];
        const uint4* pp = (const uint4*)(Pg + ((size_t)vt * 128 + hbase) * 4);
        uint4 pa = pp[0], pb = pp[1];
        f32x4 acc[4];
        acc[0] = (f32x4){bflo2f(pa.x), bflo2f(pa.z), bflo2f(pb.x), bflo2f(pb.z)}; // i
        acc[1] = (f32x4){bfhi2f(pa.x), bfhi2f(pa.z), bfhi2f(pb.x), bfhi2f(pb.z)}; // f
        acc[2] = (f32x4){bflo2f(pa.y), bflo2f(pa.w), bflo2f(pb.y), bflo2f(pb.w)}; // g
        acc[3] = (f32x4){bfhi2f(pa.y), bfhi2f(pa.w), bfhi2f(pb.y), bfhi2f(pb.w)}; // o

        #pragma unroll
        for (int ks = 0; ks < 4; ++ks) {
          bf16x8 Hf = *(const bf16x8*)(&Hs[cur][eL * HS_STRIDE + ks * 32 + lg * 8]);
          #pragma unroll
          for (int gate = 0; gate < 4; ++gate)
            acc[gate] = __builtin_amdgcn_mfma_f32_16x16x32_bf16(
                BW[gate][ks], Hf, acc[gate], 0, 0, 0);
        }

        float h[4];
        #pragma unroll
        for (int r = 0; r < 4; ++r) {
          float A = fast_exp2(acc[0][r]);
          float F = fast_exp2(acc[1][r]);
          float B = fast_exp2(acc[2][r]);
          float O = fast_exp2(acc[3][r]);
          float ig = pair_sig_tanh(A, B);
          float f  = fast_rcp(1.0f + F);
          float cn = fmaf(f, cst[es][r], ig);
          cst[es][r] = cn;
          float C = fast_exp2(TWO_LOG2E_F * cn);
          h[r] = pair_sig_tanh(O, C);
        }
        uint2 hp = make_uint2(cvt_pk_bf16(h[0], h[1]), cvt_pk_bf16(h[2], h[3]));
        *(uint2*)(&Hs[cur ^ 1][eL * HS_STRIDE + hbase]) = hp;
      }
      cur ^= 1;
      __syncthreads();
    }

    // ---- tail: waves 0..2 each handle edge sub-tile es=wv2.
    if (wv2 < N_ES) {
      int eL = wv2 * 16 + l15;
      bf16x8 Hf[4];
      #pragma unroll
      for (int ks = 0; ks < 4; ++ks)
        Hf[ks] = *(const bf16x8*)(&Hs[cur][eL * HS_STRIDE + ks * 32 + lg * 8]);
      f32x4 a2[2];
      a2[0] = (f32x4){0.f, 0.f, 0.f, 0.f};
      a2[1] = (f32x4){0.f, 0.f, 0.f, 0.f};
      #pragma unroll
      for (int ks = 0; ks < 4; ++ks)
        #pragma unroll
        for (int n2 = 0; n2 < 2; ++n2)
          a2[n2] = __builtin_amdgcn_mfma_f32_16x16x32_bf16(
              *(const bf16x8*)(Bfrag1 + ((size_t)(n2 * 4 + ks) * 64 + lane) * 8),
              Hf[ks], a2[n2], 0, 0, 0);
      float4 w2lo = *(const float4*)(W2 + lg * 4);
      float4 w2hi = *(const float4*)(W2 + 16 + lg * 4);
      float b2v = b2[0];
      int v15 = toks[15][eL];
      float4 fb0 = *(const float4*)(FB + v15 * 32 + lg * 4);
      float4 fb1 = *(const float4*)(FB + v15 * 32 + 16 + lg * 4);
      float pr = fmaxf(a2[0][0] + fb0.x, 0.f) * w2lo.x
               + fmaxf(a2[0][1] + fb0.y, 0.f) * w2lo.y
               + fmaxf(a2[0][2] + fb0.z, 0.f) * w2lo.z
               + fmaxf(a2[0][3] + fb0.w, 0.f) * w2lo.w
               + fmaxf(a2[1][0] + fb1.x, 0.f) * w2hi.x
               + fmaxf(a2[1][1] + fb1.y, 0.f) * w2hi.y
               + fmaxf(a2[1][2] + fb1.z, 0.f) * w2hi.z
               + fmaxf(a2[1][3] + fb1.w, 0.f) * w2hi.w;
      pr += __shfl_xor(pr, 16);
      pr += __shfl_xor(pr, 32);
      int eidx = e0 + eL;
      if (lane < 16 && eidx < E) ea[eidx] = fmaxf(pr + b2v, 0.0f);
    }
    __syncthreads();   // before next tile reuses toks/Hs
  }
}

// ---------------- per-node argmax over x[:, :53] (wave per node) -----------
__global__ __launch_bounds__(256) void node_argmax_kernel(
    const float* __restrict__ x, int* __restrict__ nid, int N)
{
  int n = (blockIdx.x * 256 + threadIdx.x) >> 6;
  int lane = threadIdx.x & 63;
  if (n >= N) return;
  float v = (lane < SID_N) ? x[(size_t)n * D_DIM + lane] : -3.4e38f;
  int idx = lane;
  #pragma unroll
  for (int o = 32; o > 0; o >>= 1) {
    float ov = __shfl_down(v, o);
    int   oi = __shfl_down(idx, o);
    if (ov > v || (ov == v && oi < idx)) { v = ov; idx = oi; }
  }
  if (lane == 0) nid[n] = idx;
}

// ---------------- edge winner (last edge wins) + resolve -------------------
__global__ void edge_winner_kernel(
    const int* __restrict__ ei, const int* __restrict__ nid,
    int* __restrict__ win_in, int* __restrict__ win_out, int E)
{
  int e = blockIdx.x * 256 + threadIdx.x;
  if (e >= E) return;
  int s = ei[e];
  int t = ei[E + e];
  atomicMax(&win_in[(size_t)t * SID_N + nid[s]], e);
  atomicMax(&win_out[(size_t)s * SID_N + nid[t]], e);
}

__global__ void scatter_resolve_kernel(
    const int* __restrict__ ei, const int* __restrict__ nid,
    const float* __restrict__ ea,
    const int* __restrict__ win_in, const int* __restrict__ win_out,
    float* __restrict__ x_mod, int E)
{
  int e = blockIdx.x * 256 + threadIdx.x;
  if (e >= E) return;
  int s = ei[e];
  int t = ei[E + e];
  int sid = nid[s], tix = nid[t];
  if (win_in[(size_t)t * SID_N + sid] == e)
    x_mod[(size_t)t * D_DIM + IN_COL + sid] = ea[e];
  if (win_out[(size_t)s * SID_N + tix] == e)
    x_mod[(size_t)s * D_DIM + OUT_COL + tix] = ea[e];
}

// ---------------- pack Wl||Wr into MFMA fragment order ----------------
__global__ void pack_w_kernel(const float* __restrict__ Wl,
                              const float* __restrict__ Wr,
                              unsigned short* __restrict__ Wfrag)
{
  int f = blockIdx.x * 256 + threadIdx.x;
  if (f >= 48 * 12 * 64 * 8) return;
  int e = f & 7, l = (f >> 3) & 63;
  int rest = f >> 9;
  int ks = rest % 12, nt = rest / 12;
  int nl = nt * 16 + (l & 15);
  int k  = ks * 32 + (l >> 4) * 8 + e;
  float val = 0.0f;
  if (k < D_DIM) {
    if (nl < D_DIM)                      val = Wl[(size_t)k * D_DIM + nl];
    else if (nl >= 384 && nl < 384 + D_DIM) val = Wr[(size_t)k * D_DIM + (nl - 384)];
  }
  Wfrag[f] = f2bf(val);
}

// ---------------- fused bf16 MFMA GEMM: [xl||xr] = xmod @ [Wl||Wr] + bias ----
__global__ __launch_bounds__(256, 2) void gemm_mfma_kernel(
    const float* __restrict__ A,               // xmod [N][373] fp32
    const unsigned short* __restrict__ Wfrag,  // [48][12][64][8] bf16
    const float* __restrict__ bl, const float* __restrict__ br,
    float* __restrict__ xl, float* __restrict__ xr, int N)
{
  __shared__ unsigned short As[64][40];
  int tid  = threadIdx.x;
  int lane = tid & 63;
  int wv   = tid >> 6;
  int l15  = lane & 15, lg = lane >> 4;
  int m0   = blockIdx.x * 64;
  int nt   = blockIdx.y * 4 + wv;

  f32x4 acc[4];
  #pragma unroll
  for (int i = 0; i < 4; ++i) acc[i] = (f32x4){0.f, 0.f, 0.f, 0.f};

  int srow = tid >> 2, seg = tid & 3;
  int gr = m0 + srow; if (gr >= N) gr = N - 1;
  const float* arow = A + (size_t)gr * D_DIM;

  for (int ks = 0; ks < 12; ++ks) {
    int c0 = ks * 32 + seg * 8;
    float v[8];
    #pragma unroll
    for (int j = 0; j < 8; ++j) v[j] = (c0 + j < D_DIM) ? arow[c0 + j] : 0.0f;
    unsigned pk0 = cvt_pk_bf16(v[0], v[1]);
    unsigned pk1 = cvt_pk_bf16(v[2], v[3]);
    unsigned pk2 = cvt_pk_bf16(v[4], v[5]);
    unsigned pk3 = cvt_pk_bf16(v[6], v[7]);
    __syncthreads();
    *(uint4*)(&As[srow][seg * 8]) = make_uint4(pk0, pk1, pk2, pk3);
    __syncthreads();

    bf16x8 Bf = *(const bf16x8*)(Wfrag + ((size_t)(nt * 12 + ks) * 64 + lane) * 8);
    #pragma unroll
    for (int msub = 0; msub < 4; ++msub) {
      bf16x8 Af = *(const bf16x8*)(&As[msub * 16 + l15][lg * 8]);
      acc[msub] = __builtin_amdgcn_mfma_f32_16x16x32_bf16(Af, Bf, acc[msub], 0, 0, 0);
    }
  }

  int nl = nt * 16 + l15;
  float* dst = nullptr; int col = 0; const float* bias_ = nullptr;
  if (nl < D_DIM)                         { dst = xl; col = nl;       bias_ = bl; }
  else if (nl >= 384 && nl < 384 + D_DIM) { dst = xr; col = nl - 384; bias_ = br; }
  if (dst) {
    float bv = bias_[col];
    #pragma unroll
    for (int msub = 0; msub < 4; ++msub) {
      #pragma unroll
      for (int r = 0; r < 4; ++r) {
        int m = m0 + msub * 16 + lg * 4 + r;
        if (m < N) dst[(size_t)m * D_DIM + col] = acc[msub][r] + bv;
      }
    }
  }
}

// ---------------- CSR build: histogram / scan / placement ----------------
__global__ void hist_kernel(const int* __restrict__ ei, unsigned* __restrict__ deg,
                            int E) {
  int e = blockIdx.x * 256 + threadIdx.x;
  if (e >= E) return;
  atomicAdd(&deg[ei[E + e]], 1u);
}

__global__ void scan1_kernel(const unsigned* __restrict__ deg,
                             unsigned* __restrict__ excl,
                             unsigned* __restrict__ bsum, int n) {
  __shared__ unsigned s[256];
  int t = threadIdx.x;
  int i = blockIdx.x * 256 + t;
  unsigned v = (i < n) ? deg[i] : 0u;
  s[t] = v; __syncthreads();
  #pragma unroll
  for (int o = 1; o < 256; o <<= 1) {
    unsigned u = (t >= o) ? s[t - o] : 0u;
    __syncthreads();
    s[t] += u;
    __syncthreads();
  }
  if (i < n) excl[i] = s[t] - v;
  if (t == 255) bsum[blockIdx.x] = s[255];
}

__global__ void scan2_kernel(unsigned* __restrict__ bsum, int nb) {
  __shared__ unsigned s[256];
  int t = threadIdx.x;
  unsigned v = (t < nb) ? bsum[t] : 0u;
  s[t] = v; __syncthreads();
  #pragma unroll
  for (int o = 1; o < 256; o <<= 1) {
    unsigned u = (t >= o) ? s[t - o] : 0u;
    __syncthreads();
    s[t] += u;
    __syncthreads();
  }
  if (t < nb) bsum[t] = s[t] - v;   // exclusive
}

__global__ void scan3_kernel(unsigned* __restrict__ excl,
                             const unsigned* __restrict__ bsum, int n) {
  int i = blockIdx.x * 256 + threadIdx.x;
  if (i < n) excl[i] += bsum[i >> 8];
}

__global__ void place_kernel(const int* __restrict__ ei,
                             unsigned* __restrict__ offs,
                             int* __restrict__ csr_eid, int E) {
  int e = blockIdx.x * 256 + threadIdx.x;
  if (e >= E) return;
  unsigned j = atomicAdd(&offs[ei[E + e]], 1u);
  csr_eid[j] = e;
}

// ---------------- attention logits, wave-per-node over CSR -----------------
// xr[n] row and att are loaded once per node (registers), xl[src] gathered.
__global__ __launch_bounds__(256) void edge_e_csr_kernel(
    const float* __restrict__ xl, const float* __restrict__ xr,
    const float* __restrict__ att, const int* __restrict__ ei,
    const int* __restrict__ csr_eid, const unsigned* __restrict__ offs,
    const unsigned* __restrict__ deg, float* __restrict__ ebuf, int N, int E)
{
  int n = (blockIdx.x * 256 + threadIdx.x) >> 6;
  int lane = threadIdx.x & 63;
  if (n >= N) return;
  unsigned end = offs[n], d = deg[n], start = end - d;
  if (d == 0) return;

  const float* xrn = xr + (size_t)n * D_DIM;
  float r0 = xrn[lane],        a0 = att[lane];
  float r1 = xrn[64 + lane],   a1 = att[64 + lane];
  float r2 = xrn[128 + lane],  a2 = att[128 + lane];
  float r3 = xrn[192 + lane],  a3 = att[192 + lane];
  float r4 = xrn[256 + lane],  a4 = att[256 + lane];
  float r5 = 0.f, a5 = 0.f;
  if (lane < 53) { r5 = xrn[320 + lane]; a5 = att[320 + lane]; }

  for (unsigned j = start; j < end; ++j) {
    int eid = csr_eid[j];
    const float* row = xl + (size_t)ei[eid] * D_DIM;
    float m, acc;
    m = row[lane] + r0;        acc  = ((m > 0.f) ? m : 0.2f * m) * a0;
    m = row[64 + lane] + r1;   acc += ((m > 0.f) ? m : 0.2f * m) * a1;
    m = row[128 + lane] + r2;  acc += ((m > 0.f) ? m : 0.2f * m) * a2;
    m = row[192 + lane] + r3;  acc += ((m > 0.f) ? m : 0.2f * m) * a3;
    m = row[256 + lane] + r4;  acc += ((m > 0.f) ? m : 0.2f * m) * a4;
    if (lane < 53) { m = row[320 + lane] + r5; acc += ((m > 0.f) ? m : 0.2f * m) * a5; }
    #pragma unroll
    for (int o = 32; o > 0; o >>= 1) acc += __shfl_down(acc, o);
    if (lane == 0) ebuf[eid] = acc;
  }
}

// ---------------- fused per-node: softmax + aggregate + finalize ----------
__global__ __launch_bounds__(256) void node_gat_kernel(
    const int* __restrict__ ei, const int* __restrict__ csr_eid,
    const unsigned* __restrict__ offs, const unsigned* __restrict__ deg,
    float* __restrict__ ebuf, const float* __restrict__ xl,
    const float* __restrict__ xmod, const float* __restrict__ bias,
    float* __restrict__ out, int N, int E, int goff)
{
  int n = (blockIdx.x * 256 + threadIdx.x) >> 6;
  int lane = threadIdx.x & 63;
  if (n >= N) return;
  unsigned end = offs[n], d = deg[n], start = end - d;

  float mx = -3.4e38f;
  for (unsigned j = start; j < end; ++j)
    mx = fmaxf(mx, ebuf[csr_eid[j]]);
  float den = 0.0f;
  for (unsigned j = start; j < end; ++j) {
    int eid = csr_eid[j];
    float ex = __expf(ebuf[eid] - mx);
    ebuf[eid] = ex;               // reuse in agg pass (exclusive to this wave)
    den += ex;
  }
  float inv = 1.0f / (den + 1e-16f);

  float o0 = 0, o1 = 0, o2 = 0, o3 = 0, o4 = 0, o5 = 0;
  for (unsigned j = start; j < end; ++j) {
    int eid = csr_eid[j];
    float w = ebuf[eid] * inv;
    const float* row = xl + (size_t)ei[eid] * D_DIM;
    o0 = fmaf(w, row[lane], o0);
    o1 = fmaf(w, row[64 + lane], o1);
    o2 = fmaf(w, row[128 + lane], o2);
    o3 = fmaf(w, row[192 + lane], o3);
    o4 = fmaf(w, row[256 + lane], o4);
    if (lane < 53) o5 = fmaf(w, row[320 + lane], o5);
  }

  const float* xm = xmod + (size_t)n * D_DIM;
  float* op = out + (size_t)n * (2 * D_DIM) + goff;
  op[lane]       = fmaxf(o0 + bias[lane]       + xm[lane],       0.0f);
  op[64 + lane]  = fmaxf(o1 + bias[64 + lane]  + xm[64 + lane],  0.0f);
  op[128 + lane] = fmaxf(o2 + bias[128 + lane] + xm[128 + lane], 0.0f);
  op[192 + lane] = fmaxf(o3 + bias[192 + lane] + xm[192 + lane], 0.0f);
  op[256 + lane] = fmaxf(o4 + bias[256 + lane] + xm[256 + lane], 0.0f);
  if (lane < 53)
    op[320 + lane] = fmaxf(o5 + bias[320 + lane] + xm[320 + lane], 0.0f);
}

// ---------------------------------------------------------------------------
extern "C" void kernel_launch(void* const* d_in, const int* in_sizes, int n_in,
                              void* d_out, int out_size, void* d_ws, size_t ws_size,
                              hipStream_t stream)
{
  const float* fx     = (const float*)d_in[0];
  const float* bx     = (const float*)d_in[1];
  const int*   fei    = (const int*)d_in[2];
  const int*   bei    = (const int*)d_in[3];
  const int*   ftk    = (const int*)d_in[4];
  const int*   btk    = (const int*)d_in[5];
  const float* embed  = (const float*)d_in[6];
  const float* Wih_f  = (const float*)d_in[7];
  const float* Whh_f  = (const float*)d_in[8];
  const float* bih_f  = (const float*)d_in[9];
  const float* bhh_f  = (const float*)d_in[10];
  const float* Wih_r  = (const float*)d_in[11];
  // d_in[12] = Whh_r : unused (reverse cell consumes zero state)
  const float* bih_r  = (const float*)d_in[13];
  const float* bhh_r  = (const float*)d_in[14];
  const float* W1     = (const float*)d_in[15];
  const float* b1     = (const float*)d_in[16];
  const float* W2     = (const float*)d_in[17];
  const float* b2     = (const float*)d_in[18];

  const float* Wl_g[2]   = {(const float*)d_in[19], (const float*)d_in[25]};
  const float* bl_g[2]   = {(const float*)d_in[20], (const float*)d_in[26]};
  const float* Wr_g[2]   = {(const float*)d_in[21], (const float*)d_in[27]};
  const float* br_g[2]   = {(const float*)d_in[22], (const float*)d_in[28]};
  const float* att_g[2]  = {(const float*)d_in[23], (const float*)d_in[29]};
  const float* bias_g[2] = {(const float*)d_in[24], (const float*)d_in[30]};
  const float* x_g[2]    = {fx, bx};
  const int*   ei_g[2]   = {fei, bei};
  const int*   tk_g[2]   = {ftk, btk};

  const int E = in_sizes[2] / 2;          // 400000
  const int N = in_sizes[0] / D_DIM;      // 50000

  // ---- workspace layout (byte-based, 256B aligned chunks) ----
  char* wsb = (char*)d_ws;
  size_t off = 0;
  auto alloc = [&](size_t bytes) -> void* {
    void* p = wsb + off; off += (bytes + 255) & ~(size_t)255; return p;
  };
  unsigned short* Pg     = (unsigned short*)alloc((size_t)64 * 128 * 4 * 2);
  unsigned short* BfragW = (unsigned short*)alloc((size_t)65536 * 2);
  unsigned short* Bfrag1 = (unsigned short*)alloc((size_t)4096 * 2);
  unsigned short* Wfrag2 = (unsigned short*)alloc((size_t)2 * 294912 * 2);
  float* FB    = (float*)alloc((size_t)64 * 32 * 4);
  float* ea    = (float*)alloc((size_t)E * 4);
  float* ebuf  = (float*)alloc((size_t)E * 4);
  int*   nid   = (int*)alloc((size_t)N * 4);
  int*   csr_eid = (int*)alloc((size_t)E * 4);
  unsigned* deg  = (unsigned*)alloc((size_t)N * 4);
  unsigned* offs = (unsigned*)alloc((size_t)N * 4);
  unsigned* bsum = (unsigned*)alloc((size_t)256 * 4);
  int* win_in  = (int*)alloc((size_t)N * SID_N * 4);
  int* win_out = (int*)alloc((size_t)N * SID_N * 4);
  float* xmod  = (float*)alloc((size_t)N * D_DIM * 4);
  float* xl    = (float*)alloc((size_t)N * D_DIM * 4);
  float* xr    = (float*)alloc((size_t)N * D_DIM * 4);
  (void)ws_size; (void)n_in; (void)out_size;

  const size_t win_u32 = (size_t)((char*)win_out - (char*)win_in) / 4
                         + (size_t)N * SID_N;

  float* out = (float*)d_out;

  precompute_kernel<<<64, 512, 0, stream>>>(
      embed, Wih_f, Whh_f, bih_f, bhh_f, Wih_r, bih_r, bhh_r, W1, b1,
      Pg, BfragW, Bfrag1, FB);
  pack_w_kernel<<<(294912 + 255) / 256, 256, 0, stream>>>(
      Wl_g[0], Wr_g[0], Wfrag2);
  pack_w_kernel<<<(294912 + 255) / 256, 256, 0, stream>>>(
      Wl_g[1], Wr_g[1], Wfrag2 + 294912);

  const int nTiles  = (E + EDGES_T - 1) / EDGES_T;   // 8334
  const int gridL   = nTiles < 2048 ? nTiles : 2048;
  const int gridE   = (E + 255) / 256;
  const int nScanB  = (N + 255) / 256;
  const int gridNd  = (N * 64 + 255) / 256;
  dim3 gridG((N + 63) / 64, 12);

  for (int g = 0; g < 2; ++g) {
    const float* x  = x_g[g];
    const int*   ei = ei_g[g];

    // (1) edge scalar via MFMA LSTM
    lstm_mfma_kernel<<<gridL, 512, 0, stream>>>(tk_g[g], Pg, BfragW, Bfrag1,
                                                FB, W2, b2, ea, E, nTiles);

    // (2) x_mod = copy(x); per-node argmax; last-edge-wins scatter writes
    hipMemcpyAsync(xmod, x, (size_t)N * D_DIM * sizeof(float),
                   hipMemcpyDeviceToDevice, stream);
    node_argmax_kernel<<<gridNd, 256, 0, stream>>>(x, nid, N);
    fill_u32_kernel<<<2048, 256, 0, stream>>>((unsigned*)win_in, 0xFFFFFFFFu,
                                              win_u32);
    edge_winner_kernel<<<gridE, 256, 0, stream>>>(ei, nid, win_in, win_out, E);
    scatter_resolve_kernel<<<gridE, 256, 0, stream>>>(ei, nid, ea,
                                                      win_in, win_out, xmod, E);

    // (3) [xl||xr] = xmod @ [Wl||Wr] + bias  (bf16 MFMA)
    gemm_mfma_kernel<<<gridG, 256, 0, stream>>>(xmod, Wfrag2 + (size_t)g * 294912,
                                                bl_g[g], br_g[g], xl, xr, N);

    // (4) CSR by dst (before attention so edge_e can be node-major)
    fill_u32_kernel<<<512, 256, 0, stream>>>(deg, 0u, (size_t)N);
    hist_kernel<<<gridE, 256, 0, stream>>>(ei, deg, E);
    scan1_kernel<<<nScanB, 256, 0, stream>>>(deg, offs, bsum, N);
    scan2_kernel<<<1, 256, 0, stream>>>(bsum, nScanB);
    scan3_kernel<<<nScanB, 256, 0, stream>>>(offs, bsum, N);
    place_kernel<<<gridE, 256, 0, stream>>>(ei, offs, csr_eid, E);

    // (5) attention logits (node-major), then fused softmax+agg+finalize
    edge_e_csr_kernel<<<gridNd, 256, 0, stream>>>(xl, xr, att_g[g], ei,
                                                  csr_eid, offs, deg, ebuf, N, E);
    node_gat_kernel<<<gridNd, 256, 0, stream>>>(ei, csr_eid, offs, deg, ebuf,
                                                xl, xmod, bias_g[g], out,
                                                N, E, g * D_DIM);
  }
}

// Round 14
// 3488.574 us; speedup vs baseline: 1.3288x; 1.0104x over previous
//
#include <hip/hip_runtime.h>
#include <cstdint>

// ---------------------------------------------------------------------------
// ForwardBackwardGNN — R14: pareto consolidation.
//   LSTM: R12's measured-best config (64 edges/block, 4 es, bf16 Pg unpack,
//         cst in VGPR, launch_bounds(512,4); spill latency-hidden at 54MB).
//   GAT:  R13's measured-best tail (node-major edge_e over CSR + fused
//         softmax/aggregate/finalize node kernel).
//   N=50000, E=400000, L=16, V=64, EMB=32, H=128, D=373, SID=53.
// ---------------------------------------------------------------------------

#define D_DIM   373
#define SID_N   53
#define IN_COL  161
#define OUT_COL 320
#define HS_STRIDE 136   // u16/row
#define EDGES_T 64      // edges per tile/block
#define N_ES    4       // edge sub-tiles of 16

typedef short bf16x8 __attribute__((ext_vector_type(8)));
typedef float f32x4  __attribute__((ext_vector_type(4)));

#define LOG2E_F 1.4426950408889634f
#define TWO_LOG2E_F 2.8853900817779268f

__device__ __forceinline__ float fast_exp2(float x) {
#if __has_builtin(__builtin_amdgcn_exp2f)
  return __builtin_amdgcn_exp2f(x);
#else
  return exp2f(x);
#endif
}
__device__ __forceinline__ float fast_rcp(float x) {
#if __has_builtin(__builtin_amdgcn_rcpf)
  return __builtin_amdgcn_rcpf(x);
#else
  return 1.0f / x;
#endif
}
__device__ __forceinline__ float sig_ref(float x)  { return 1.0f / (1.0f + __expf(-x)); }
__device__ __forceinline__ float tanh_ref(float x) { return 2.0f / (1.0f + __expf(-2.0f * x)) - 1.0f; }

__device__ __forceinline__ unsigned short f2bf(float f) {
  unsigned u = __float_as_uint(f);
  unsigned r = (u + 0x7fffu + ((u >> 16) & 1u)) >> 16;
  return (unsigned short)r;
}
__device__ __forceinline__ float bflo2f(unsigned u) { return __uint_as_float(u << 16); }
__device__ __forceinline__ float bfhi2f(unsigned u) { return __uint_as_float(u & 0xffff0000u); }
__device__ __forceinline__ unsigned cvt_pk_bf16(float lo, float hi) {
  unsigned r;
  asm("v_cvt_pk_bf16_f32 %0, %1, %2" : "=v"(r) : "v"(lo), "v"(hi));
  return r;
}
// sig(a)*tanh(b) with A=2^{-a*log2e} (pre-scaled), B=2^{+2b*log2e} (pre-scaled)
__device__ __forceinline__ float pair_sig_tanh(float A, float B) {
  return (B - 1.0f) * fast_rcp((1.0f + A) * (1.0f + B));
}

// ---------------- generic fill ----------------
__global__ void fill_u32_kernel(unsigned* __restrict__ p, unsigned v, size_t n) {
  size_t i = (size_t)blockIdx.x * blockDim.x + threadIdx.x;
  size_t stride = (size_t)gridDim.x * blockDim.x;
  for (; i < n; i += stride) p[i] = v;
}

// ---------------- precompute: Pg (bf16, gate-interleaved) / FB / fragments --
__global__ void precompute_kernel(
    const float* __restrict__ embed, const float* __restrict__ Wih_f,
    const float* __restrict__ Whh_f,
    const float* __restrict__ bih_f, const float* __restrict__ bhh_f,
    const float* __restrict__ Wih_r,
    const float* __restrict__ bih_r, const float* __restrict__ bhh_r,
    const float* __restrict__ W1, const float* __restrict__ b1,
    unsigned short* __restrict__ Pg, unsigned short* __restrict__ BfragW,
    unsigned short* __restrict__ Bfrag1, float* __restrict__ FB)
{
  __shared__ float ps[512];
  __shared__ float gb[512];
  __shared__ float hb[128];
  int v = blockIdx.x;
  int j = threadIdx.x;

  float s = 0.0f;
  if (v != 0) {
    #pragma unroll
    for (int k = 0; k < 32; ++k) s += embed[v * 32 + k] * Wih_f[j * 32 + k];
  }
  ps[j] = s + bih_f[j] + bhh_f[j];

  float gr = bih_r[j] + bhh_r[j];
  if (v != 0) {
    #pragma unroll
    for (int k = 0; k < 32; ++k) gr += embed[v * 32 + k] * Wih_r[j * 32 + k];
  }
  gb[j] = gr;
  __syncthreads();
  if (j < 128) {
    float c = sig_ref(gb[j]) * tanh_ref(gb[256 + j]);
    hb[j] = sig_ref(gb[384 + j]) * tanh_ref(c);
  }
  __syncthreads();

  // Pg[v][h][g] = bf16(scale(g) * P[v][g*128+h])
  { int h = j >> 2, g = j & 3;
    float sc = (g == 2) ? TWO_LOG2E_F : -LOG2E_F;
    Pg[((size_t)v * 128 + h) * 4 + g] = f2bf(ps[g * 128 + h] * sc); }

  if (j < 32) {
    float s2 = b1[j];
    for (int m = 0; m < 128; ++m) s2 += hb[m] * W1[(128 + m) * 32 + j];
    FB[v * 32 + j] = s2;
  }

  if (v == 0) {
    // BfragW flat = ((nt*4+ks)*64 + lane)*8 + e ; val = scale * Whh_f[n][k]
    for (int f = j; f < 65536; f += 512) {
      int e = f & 7, l = (f >> 3) & 63, ks = (f >> 9) & 3, nt = f >> 11;
      int n = nt * 16 + (l & 15);
      int k = ks * 32 + (l >> 4) * 8 + e;
      float sc = ((nt >> 3) == 2) ? TWO_LOG2E_F : -LOG2E_F;
      BfragW[f] = f2bf(Whh_f[(size_t)n * 128 + k] * sc);
    }
  }
  if (v == 1) {
    // Bfrag1 flat = ((n2*4+ks)*64 + lane)*8 + e ; B[k][q] = W1[k][q] (k<128)
    for (int f = j; f < 4096; f += 512) {
      int e = f & 7, l = (f >> 3) & 63, ks = (f >> 9) & 3, n2 = f >> 11;
      int q = n2 * 16 + (l & 15);
      int k = ks * 32 + (l >> 4) * 8 + e;
      Bfrag1[f] = f2bf(W1[(size_t)k * 32 + q]);
    }
  }
}

// ---------------- MFMA LSTM: 64 edges/block, 8 waves, 1 barrier/step --------
// mfma(A=W-frag, B=H-frag) -> D: col=lane&15=edge(sub), row=(lane>>4)*4+r=hcol.
// Wave wv2 owns hcols [wv2*16,+16) x 4 gates for all 4 edge sub-tiles.
__global__ __launch_bounds__(512, 4) void lstm_mfma_kernel(
    const int*   __restrict__ tokens,   // [E][16]
    const unsigned short* __restrict__ Pg,      // [64][128][4] bf16 (scaled)
    const unsigned short* __restrict__ BfragW,  // [32][4][64][8] bf16 (scaled)
    const unsigned short* __restrict__ Bfrag1,  // [2][4][64][8] bf16
    const float* __restrict__ FB,       // [64][32]
    const float* __restrict__ W2,       // [32]
    const float* __restrict__ b2,
    float* __restrict__ ea, int E, int nTiles)
{
  __shared__ unsigned short Hs[2][EDGES_T * HS_STRIDE];  // 34,816 B
  __shared__ int toks[16][EDGES_T];                      //  4,096 B

  int tid  = threadIdx.x;
  int lane = tid & 63;
  int wv2  = tid >> 6;                  // 0..7
  int l15  = lane & 15;
  int lg   = lane >> 4;                 // 0..3
  int hbase = wv2 * 16 + lg * 4;        // this lane's 4 hcols

  // persistent A-frags (W): BW[gate][ks] — 64 regs (AGPR)
  bf16x8 BW[4][4];
  #pragma unroll
  for (int gate = 0; gate < 4; ++gate)
    #pragma unroll
    for (int ks = 0; ks < 4; ++ks)
      BW[gate][ks] = *(const bf16x8*)(BfragW +
          ((size_t)((gate * 8 + wv2) * 4 + ks) * 64 + lane) * 8);

  for (int tile = blockIdx.x; tile < nTiles; tile += gridDim.x) {
    int e0 = tile * EDGES_T;
    for (int i = tid; i < 16 * EDGES_T; i += 512) {   // stage tokens [t][m]
      int m = i >> 4, t = i & 15;
      int ee = e0 + m; if (ee >= E) ee = E - 1;
      toks[t][m] = tokens[(size_t)ee * 16 + t];
    }
    __syncthreads();

    f32x4 cst[N_ES];   // statically indexed (es fully unrolled)
    // ---- step 0: gates = P only (h0=c0=0, f-term vanishes)
    #pragma unroll
    for (int es = 0; es < N_ES; ++es) {
      int eL = es * 16 + l15;
      int v0 = toks[0][eL];
      const uint4* pp = (const uint4*)(Pg + ((size_t)v0 * 128 + hbase) * 4);
      uint4 pa = pp[0], pb = pp[1];
      float pi[4] = {bflo2f(pa.x), bflo2f(pa.z), bflo2f(pb.x), bflo2f(pb.z)};
      float pg[4] = {bflo2f(pa.y), bflo2f(pa.w), bflo2f(pb.y), bflo2f(pb.w)};
      float po[4] = {bfhi2f(pa.y), bfhi2f(pa.w), bfhi2f(pb.y), bfhi2f(pb.w)};
      float h[4];
      #pragma unroll
      for (int r = 0; r < 4; ++r) {
        float A = fast_exp2(pi[r]);
        float B = fast_exp2(pg[r]);
        float O = fast_exp2(po[r]);
        float cn = pair_sig_tanh(A, B);     // i*g
        cst[es][r] = cn;
        float C = fast_exp2(TWO_LOG2E_F * cn);
        h[r] = pair_sig_tanh(O, C);         // o*tanh(c)
      }
      uint2 hp = make_uint2(cvt_pk_bf16(h[0], h[1]), cvt_pk_bf16(h[2], h[3]));
      *(uint2*)(&Hs[0][eL * HS_STRIDE + hbase]) = hp;
    }
    __syncthreads();

    int cur = 0;
    #pragma unroll 1
    for (int t = 1; t < 16; ++t) {
      #pragma unroll
      for (int es = 0; es < N_ES; ++es) {
        int eL = es * 16 + l15;
        int vt = toks[t][eL];
        const uint4* pp = (const uint4*)(Pg + ((size_t)vt * 128 + hbase) * 4);
        uint4 pa = pp[0], pb = pp[1];
        f32x4 acc[4];
        acc[0] = (f32x4){bflo2f(pa.x), bflo2f(pa.z), bflo2f(pb.x), bflo2f(pb.z)}; // i
        acc[1] = (f32x4){bfhi2f(pa.x), bfhi2f(pa.z), bfhi2f(pb.x), bfhi2f(pb.z)}; // f
        acc[2] = (f32x4){bflo2f(pa.y), bflo2f(pa.w), bflo2f(pb.y), bflo2f(pb.w)}; // g
        acc[3] = (f32x4){bfhi2f(pa.y), bfhi2f(pa.w), bfhi2f(pb.y), bfhi2f(pb.w)}; // o

        #pragma unroll
        for (int ks = 0; ks < 4; ++ks) {
          bf16x8 Hf = *(const bf16x8*)(&Hs[cur][eL * HS_STRIDE + ks * 32 + lg * 8]);
          #pragma unroll
          for (int gate = 0; gate < 4; ++gate)
            acc[gate] = __builtin_amdgcn_mfma_f32_16x16x32_bf16(
                BW[gate][ks], Hf, acc[gate], 0, 0, 0);
        }

        float h[4];
        #pragma unroll
        for (int r = 0; r < 4; ++r) {
          float A = fast_exp2(acc[0][r]);
          float F = fast_exp2(acc[1][r]);
          float B = fast_exp2(acc[2][r]);
          float O = fast_exp2(acc[3][r]);
          float ig = pair_sig_tanh(A, B);
          float f  = fast_rcp(1.0f + F);
          float cn = fmaf(f, cst[es][r], ig);
          cst[es][r] = cn;
          float C = fast_exp2(TWO_LOG2E_F * cn);
          h[r] = pair_sig_tanh(O, C);
        }
        uint2 hp = make_uint2(cvt_pk_bf16(h[0], h[1]), cvt_pk_bf16(h[2], h[3]));
        *(uint2*)(&Hs[cur ^ 1][eL * HS_STRIDE + hbase]) = hp;
      }
      cur ^= 1;
      __syncthreads();
    }

    // ---- tail: waves 0..3 each handle edge sub-tile es=wv2.
    //      W2/b2 loaded here (not persistent) to cut live registers.
    if (wv2 < N_ES) {
      int eL = wv2 * 16 + l15;
      bf16x8 Hf[4];
      #pragma unroll
      for (int ks = 0; ks < 4; ++ks)
        Hf[ks] = *(const bf16x8*)(&Hs[cur][eL * HS_STRIDE + ks * 32 + lg * 8]);
      f32x4 a2[2];
      a2[0] = (f32x4){0.f, 0.f, 0.f, 0.f};
      a2[1] = (f32x4){0.f, 0.f, 0.f, 0.f};
      #pragma unroll
      for (int ks = 0; ks < 4; ++ks)
        #pragma unroll
        for (int n2 = 0; n2 < 2; ++n2)
          a2[n2] = __builtin_amdgcn_mfma_f32_16x16x32_bf16(
              *(const bf16x8*)(Bfrag1 + ((size_t)(n2 * 4 + ks) * 64 + lane) * 8),
              Hf[ks], a2[n2], 0, 0, 0);
      float4 w2lo = *(const float4*)(W2 + lg * 4);
      float4 w2hi = *(const float4*)(W2 + 16 + lg * 4);
      float b2v = b2[0];
      int v15 = toks[15][eL];
      float4 fb0 = *(const float4*)(FB + v15 * 32 + lg * 4);
      float4 fb1 = *(const float4*)(FB + v15 * 32 + 16 + lg * 4);
      float pr = fmaxf(a2[0][0] + fb0.x, 0.f) * w2lo.x
               + fmaxf(a2[0][1] + fb0.y, 0.f) * w2lo.y
               + fmaxf(a2[0][2] + fb0.z, 0.f) * w2lo.z
               + fmaxf(a2[0][3] + fb0.w, 0.f) * w2lo.w
               + fmaxf(a2[1][0] + fb1.x, 0.f) * w2hi.x
               + fmaxf(a2[1][1] + fb1.y, 0.f) * w2hi.y
               + fmaxf(a2[1][2] + fb1.z, 0.f) * w2hi.z
               + fmaxf(a2[1][3] + fb1.w, 0.f) * w2hi.w;
      pr += __shfl_xor(pr, 16);
      pr += __shfl_xor(pr, 32);
      int eidx = e0 + eL;
      if (lane < 16 && eidx < E) ea[eidx] = fmaxf(pr + b2v, 0.0f);
    }
    __syncthreads();   // before next tile reuses toks/Hs
  }
}

// ---------------- per-node argmax over x[:, :53] (wave per node) -----------
__global__ __launch_bounds__(256) void node_argmax_kernel(
    const float* __restrict__ x, int* __restrict__ nid, int N)
{
  int n = (blockIdx.x * 256 + threadIdx.x) >> 6;
  int lane = threadIdx.x & 63;
  if (n >= N) return;
  float v = (lane < SID_N) ? x[(size_t)n * D_DIM + lane] : -3.4e38f;
  int idx = lane;
  #pragma unroll
  for (int o = 32; o > 0; o >>= 1) {
    float ov = __shfl_down(v, o);
    int   oi = __shfl_down(idx, o);
    if (ov > v || (ov == v && oi < idx)) { v = ov; idx = oi; }
  }
  if (lane == 0) nid[n] = idx;
}

// ---------------- edge winner (last edge wins) + resolve -------------------
__global__ void edge_winner_kernel(
    const int* __restrict__ ei, const int* __restrict__ nid,
    int* __restrict__ win_in, int* __restrict__ win_out, int E)
{
  int e = blockIdx.x * 256 + threadIdx.x;
  if (e >= E) return;
  int s = ei[e];
  int t = ei[E + e];
  atomicMax(&win_in[(size_t)t * SID_N + nid[s]], e);
  atomicMax(&win_out[(size_t)s * SID_N + nid[t]], e);
}

__global__ void scatter_resolve_kernel(
    const int* __restrict__ ei, const int* __restrict__ nid,
    const float* __restrict__ ea,
    const int* __restrict__ win_in, const int* __restrict__ win_out,
    float* __restrict__ x_mod, int E)
{
  int e = blockIdx.x * 256 + threadIdx.x;
  if (e >= E) return;
  int s = ei[e];
  int t = ei[E + e];
  int sid = nid[s], tix = nid[t];
  if (win_in[(size_t)t * SID_N + sid] == e)
    x_mod[(size_t)t * D_DIM + IN_COL + sid] = ea[e];
  if (win_out[(size_t)s * SID_N + tix] == e)
    x_mod[(size_t)s * D_DIM + OUT_COL + tix] = ea[e];
}

// ---------------- pack Wl||Wr into MFMA fragment order ----------------
__global__ void pack_w_kernel(const float* __restrict__ Wl,
                              const float* __restrict__ Wr,
                              unsigned short* __restrict__ Wfrag)
{
  int f = blockIdx.x * 256 + threadIdx.x;
  if (f >= 48 * 12 * 64 * 8) return;
  int e = f & 7, l = (f >> 3) & 63;
  int rest = f >> 9;
  int ks = rest % 12, nt = rest / 12;
  int nl = nt * 16 + (l & 15);
  int k  = ks * 32 + (l >> 4) * 8 + e;
  float val = 0.0f;
  if (k < D_DIM) {
    if (nl < D_DIM)                      val = Wl[(size_t)k * D_DIM + nl];
    else if (nl >= 384 && nl < 384 + D_DIM) val = Wr[(size_t)k * D_DIM + (nl - 384)];
  }
  Wfrag[f] = f2bf(val);
}

// ---------------- fused bf16 MFMA GEMM: [xl||xr] = xmod @ [Wl||Wr] + bias ----
__global__ __launch_bounds__(256, 2) void gemm_mfma_kernel(
    const float* __restrict__ A,               // xmod [N][373] fp32
    const unsigned short* __restrict__ Wfrag,  // [48][12][64][8] bf16
    const float* __restrict__ bl, const float* __restrict__ br,
    float* __restrict__ xl, float* __restrict__ xr, int N)
{
  __shared__ unsigned short As[64][40];
  int tid  = threadIdx.x;
  int lane = tid & 63;
  int wv   = tid >> 6;
  int l15  = lane & 15, lg = lane >> 4;
  int m0   = blockIdx.x * 64;
  int nt   = blockIdx.y * 4 + wv;

  f32x4 acc[4];
  #pragma unroll
  for (int i = 0; i < 4; ++i) acc[i] = (f32x4){0.f, 0.f, 0.f, 0.f};

  int srow = tid >> 2, seg = tid & 3;
  int gr = m0 + srow; if (gr >= N) gr = N - 1;
  const float* arow = A + (size_t)gr * D_DIM;

  for (int ks = 0; ks < 12; ++ks) {
    int c0 = ks * 32 + seg * 8;
    float v[8];
    #pragma unroll
    for (int j = 0; j < 8; ++j) v[j] = (c0 + j < D_DIM) ? arow[c0 + j] : 0.0f;
    unsigned pk0 = cvt_pk_bf16(v[0], v[1]);
    unsigned pk1 = cvt_pk_bf16(v[2], v[3]);
    unsigned pk2 = cvt_pk_bf16(v[4], v[5]);
    unsigned pk3 = cvt_pk_bf16(v[6], v[7]);
    __syncthreads();
    *(uint4*)(&As[srow][seg * 8]) = make_uint4(pk0, pk1, pk2, pk3);
    __syncthreads();

    bf16x8 Bf = *(const bf16x8*)(Wfrag + ((size_t)(nt * 12 + ks) * 64 + lane) * 8);
    #pragma unroll
    for (int msub = 0; msub < 4; ++msub) {
      bf16x8 Af = *(const bf16x8*)(&As[msub * 16 + l15][lg * 8]);
      acc[msub] = __builtin_amdgcn_mfma_f32_16x16x32_bf16(Af, Bf, acc[msub], 0, 0, 0);
    }
  }

  int nl = nt * 16 + l15;
  float* dst = nullptr; int col = 0; const float* bias_ = nullptr;
  if (nl < D_DIM)                         { dst = xl; col = nl;       bias_ = bl; }
  else if (nl >= 384 && nl < 384 + D_DIM) { dst = xr; col = nl - 384; bias_ = br; }
  if (dst) {
    float bv = bias_[col];
    #pragma unroll
    for (int msub = 0; msub < 4; ++msub) {
      #pragma unroll
      for (int r = 0; r < 4; ++r) {
        int m = m0 + msub * 16 + lg * 4 + r;
        if (m < N) dst[(size_t)m * D_DIM + col] = acc[msub][r] + bv;
      }
    }
  }
}

// ---------------- CSR build: histogram / scan / placement ----------------
__global__ void hist_kernel(const int* __restrict__ ei, unsigned* __restrict__ deg,
                            int E) {
  int e = blockIdx.x * 256 + threadIdx.x;
  if (e >= E) return;
  atomicAdd(&deg[ei[E + e]], 1u);
}

__global__ void scan1_kernel(const unsigned* __restrict__ deg,
                             unsigned* __restrict__ excl,
                             unsigned* __restrict__ bsum, int n) {
  __shared__ unsigned s[256];
  int t = threadIdx.x;
  int i = blockIdx.x * 256 + t;
  unsigned v = (i < n) ? deg[i] : 0u;
  s[t] = v; __syncthreads();
  #pragma unroll
  for (int o = 1; o < 256; o <<= 1) {
    unsigned u = (t >= o) ? s[t - o] : 0u;
    __syncthreads();
    s[t] += u;
    __syncthreads();
  }
  if (i < n) excl[i] = s[t] - v;
  if (t == 255) bsum[blockIdx.x] = s[255];
}

__global__ void scan2_kernel(unsigned* __restrict__ bsum, int nb) {
  __shared__ unsigned s[256];
  int t = threadIdx.x;
  unsigned v = (t < nb) ? bsum[t] : 0u;
  s[t] = v; __syncthreads();
  #pragma unroll
  for (int o = 1; o < 256; o <<= 1) {
    unsigned u = (t >= o) ? s[t - o] : 0u;
    __syncthreads();
    s[t] += u;
    __syncthreads();
  }
  if (t < nb) bsum[t] = s[t] - v;   // exclusive
}

__global__ void scan3_kernel(unsigned* __restrict__ excl,
                             const unsigned* __restrict__ bsum, int n) {
  int i = blockIdx.x * 256 + threadIdx.x;
  if (i < n) excl[i] += bsum[i >> 8];
}

__global__ void place_kernel(const int* __restrict__ ei,
                             unsigned* __restrict__ offs,
                             int* __restrict__ csr_eid, int E) {
  int e = blockIdx.x * 256 + threadIdx.x;
  if (e >= E) return;
  unsigned j = atomicAdd(&offs[ei[E + e]], 1u);
  csr_eid[j] = e;
}

// ---------------- attention logits, wave-per-node over CSR -----------------
__global__ __launch_bounds__(256) void edge_e_csr_kernel(
    const float* __restrict__ xl, const float* __restrict__ xr,
    const float* __restrict__ att, const int* __restrict__ ei,
    const int* __restrict__ csr_eid, const unsigned* __restrict__ offs,
    const unsigned* __restrict__ deg, float* __restrict__ ebuf, int N, int E)
{
  int n = (blockIdx.x * 256 + threadIdx.x) >> 6;
  int lane = threadIdx.x & 63;
  if (n >= N) return;
  unsigned end = offs[n], d = deg[n], start = end - d;
  if (d == 0) return;

  const float* xrn = xr + (size_t)n * D_DIM;
  float r0 = xrn[lane],        a0 = att[lane];
  float r1 = xrn[64 + lane],   a1 = att[64 + lane];
  float r2 = xrn[128 + lane],  a2 = att[128 + lane];
  float r3 = xrn[192 + lane],  a3 = att[192 + lane];
  float r4 = xrn[256 + lane],  a4 = att[256 + lane];
  float r5 = 0.f, a5 = 0.f;
  if (lane < 53) { r5 = xrn[320 + lane]; a5 = att[320 + lane]; }

  for (unsigned j = start; j < end; ++j) {
    int eid = csr_eid[j];
    const float* row = xl + (size_t)ei[eid] * D_DIM;
    float m, acc;
    m = row[lane] + r0;        acc  = ((m > 0.f) ? m : 0.2f * m) * a0;
    m = row[64 + lane] + r1;   acc += ((m > 0.f) ? m : 0.2f * m) * a1;
    m = row[128 + lane] + r2;  acc += ((m > 0.f) ? m : 0.2f * m) * a2;
    m = row[192 + lane] + r3;  acc += ((m > 0.f) ? m : 0.2f * m) * a3;
    m = row[256 + lane] + r4;  acc += ((m > 0.f) ? m : 0.2f * m) * a4;
    if (lane < 53) { m = row[320 + lane] + r5; acc += ((m > 0.f) ? m : 0.2f * m) * a5; }
    #pragma unroll
    for (int o = 32; o > 0; o >>= 1) acc += __shfl_down(acc, o);
    if (lane == 0) ebuf[eid] = acc;
  }
}

// ---------------- fused per-node: softmax + aggregate + finalize ----------
__global__ __launch_bounds__(256) void node_gat_kernel(
    const int* __restrict__ ei, const int* __restrict__ csr_eid,
    const unsigned* __restrict__ offs, const unsigned* __restrict__ deg,
    float* __restrict__ ebuf, const float* __restrict__ xl,
    const float* __restrict__ xmod, const float* __restrict__ bias,
    float* __restrict__ out, int N, int E, int goff)
{
  int n = (blockIdx.x * 256 + threadIdx.x) >> 6;
  int lane = threadIdx.x & 63;
  if (n >= N) return;
  unsigned end = offs[n], d = deg[n], start = end - d;

  float mx = -3.4e38f;
  for (unsigned j = start; j < end; ++j)
    mx = fmaxf(mx, ebuf[csr_eid[j]]);
  float den = 0.0f;
  for (unsigned j = start; j < end; ++j) {
    int eid = csr_eid[j];
    float ex = __expf(ebuf[eid] - mx);
    ebuf[eid] = ex;               // reuse in agg pass (exclusive to this wave)
    den += ex;
  }
  float inv = 1.0f / (den + 1e-16f);

  float o0 = 0, o1 = 0, o2 = 0, o3 = 0, o4 = 0, o5 = 0;
  for (unsigned j = start; j < end; ++j) {
    int eid = csr_eid[j];
    float w = ebuf[eid] * inv;
    const float* row = xl + (size_t)ei[eid] * D_DIM;
    o0 = fmaf(w, row[lane], o0);
    o1 = fmaf(w, row[64 + lane], o1);
    o2 = fmaf(w, row[128 + lane], o2);
    o3 = fmaf(w, row[192 + lane], o3);
    o4 = fmaf(w, row[256 + lane], o4);
    if (lane < 53) o5 = fmaf(w, row[320 + lane], o5);
  }

  const float* xm = xmod + (size_t)n * D_DIM;
  float* op = out + (size_t)n * (2 * D_DIM) + goff;
  op[lane]       = fmaxf(o0 + bias[lane]       + xm[lane],       0.0f);
  op[64 + lane]  = fmaxf(o1 + bias[64 + lane]  + xm[64 + lane],  0.0f);
  op[128 + lane] = fmaxf(o2 + bias[128 + lane] + xm[128 + lane], 0.0f);
  op[192 + lane] = fmaxf(o3 + bias[192 + lane] + xm[192 + lane], 0.0f);
  op[256 + lane] = fmaxf(o4 + bias[256 + lane] + xm[256 + lane], 0.0f);
  if (lane < 53)
    op[320 + lane] = fmaxf(o5 + bias[320 + lane] + xm[320 + lane], 0.0f);
}

// ---------------------------------------------------------------------------
extern "C" void kernel_launch(void* const* d_in, const int* in_sizes, int n_in,
                              void* d_out, int out_size, void* d_ws, size_t ws_size,
                              hipStream_t stream)
{
  const float* fx     = (const float*)d_in[0];
  const float* bx     = (const float*)d_in[1];
  const int*   fei    = (const int*)d_in[2];
  const int*   bei    = (const int*)d_in[3];
  const int*   ftk    = (const int*)d_in[4];
  const int*   btk    = (const int*)d_in[5];
  const float* embed  = (const float*)d_in[6];
  const float* Wih_f  = (const float*)d_in[7];
  const float* Whh_f  = (const float*)d_in[8];
  const float* bih_f  = (const float*)d_in[9];
  const float* bhh_f  = (const float*)d_in[10];
  const float* Wih_r  = (const float*)d_in[11];
  // d_in[12] = Whh_r : unused (reverse cell consumes zero state)
  const float* bih_r  = (const float*)d_in[13];
  const float* bhh_r  = (const float*)d_in[14];
  const float* W1     = (const float*)d_in[15];
  const float* b1     = (const float*)d_in[16];
  const float* W2     = (const float*)d_in[17];
  const float* b2     = (const float*)d_in[18];

  const float* Wl_g[2]   = {(const float*)d_in[19], (const float*)d_in[25]};
  const float* bl_g[2]   = {(const float*)d_in[20], (const float*)d_in[26]};
  const float* Wr_g[2]   = {(const float*)d_in[21], (const float*)d_in[27]};
  const float* br_g[2]   = {(const float*)d_in[22], (const float*)d_in[28]};
  const float* att_g[2]  = {(const float*)d_in[23], (const float*)d_in[29]};
  const float* bias_g[2] = {(const float*)d_in[24], (const float*)d_in[30]};
  const float* x_g[2]    = {fx, bx};
  const int*   ei_g[2]   = {fei, bei};
  const int*   tk_g[2]   = {ftk, btk};

  const int E = in_sizes[2] / 2;          // 400000
  const int N = in_sizes[0] / D_DIM;      // 50000

  // ---- workspace layout (byte-based, 256B aligned chunks) ----
  char* wsb = (char*)d_ws;
  size_t off = 0;
  auto alloc = [&](size_t bytes) -> void* {
    void* p = wsb + off; off += (bytes + 255) & ~(size_t)255; return p;
  };
  unsigned short* Pg     = (unsigned short*)alloc((size_t)64 * 128 * 4 * 2);
  unsigned short* BfragW = (unsigned short*)alloc((size_t)65536 * 2);
  unsigned short* Bfrag1 = (unsigned short*)alloc((size_t)4096 * 2);
  unsigned short* Wfrag2 = (unsigned short*)alloc((size_t)2 * 294912 * 2);
  float* FB    = (float*)alloc((size_t)64 * 32 * 4);
  float* ea    = (float*)alloc((size_t)E * 4);
  float* ebuf  = (float*)alloc((size_t)E * 4);
  int*   nid   = (int*)alloc((size_t)N * 4);
  int*   csr_eid = (int*)alloc((size_t)E * 4);
  unsigned* deg  = (unsigned*)alloc((size_t)N * 4);
  unsigned* offs = (unsigned*)alloc((size_t)N * 4);
  unsigned* bsum = (unsigned*)alloc((size_t)256 * 4);
  int* win_in  = (int*)alloc((size_t)N * SID_N * 4);
  int* win_out = (int*)alloc((size_t)N * SID_N * 4);
  float* xmod  = (float*)alloc((size_t)N * D_DIM * 4);
  float* xl    = (float*)alloc((size_t)N * D_DIM * 4);
  float* xr    = (float*)alloc((size_t)N * D_DIM * 4);
  (void)ws_size; (void)n_in; (void)out_size;

  const size_t win_u32 = (size_t)((char*)win_out - (char*)win_in) / 4
                         + (size_t)N * SID_N;

  float* out = (float*)d_out;

  precompute_kernel<<<64, 512, 0, stream>>>(
      embed, Wih_f, Whh_f, bih_f, bhh_f, Wih_r, bih_r, bhh_r, W1, b1,
      Pg, BfragW, Bfrag1, FB);
  pack_w_kernel<<<(294912 + 255) / 256, 256, 0, stream>>>(
      Wl_g[0], Wr_g[0], Wfrag2);
  pack_w_kernel<<<(294912 + 255) / 256, 256, 0, stream>>>(
      Wl_g[1], Wr_g[1], Wfrag2 + 294912);

  const int nTiles  = (E + EDGES_T - 1) / EDGES_T;   // 6250
  const int gridL   = nTiles < 2048 ? nTiles : 2048;
  const int gridE   = (E + 255) / 256;
  const int nScanB  = (N + 255) / 256;
  const int gridNd  = (N * 64 + 255) / 256;
  dim3 gridG((N + 63) / 64, 12);

  for (int g = 0; g < 2; ++g) {
    const float* x  = x_g[g];
    const int*   ei = ei_g[g];

    // (1) edge scalar via MFMA LSTM
    lstm_mfma_kernel<<<gridL, 512, 0, stream>>>(tk_g[g], Pg, BfragW, Bfrag1,
                                                FB, W2, b2, ea, E, nTiles);

    // (2) x_mod = copy(x); per-node argmax; last-edge-wins scatter writes
    hipMemcpyAsync(xmod, x, (size_t)N * D_DIM * sizeof(float),
                   hipMemcpyDeviceToDevice, stream);
    node_argmax_kernel<<<gridNd, 256, 0, stream>>>(x, nid, N);
    fill_u32_kernel<<<2048, 256, 0, stream>>>((unsigned*)win_in, 0xFFFFFFFFu,
                                              win_u32);
    edge_winner_kernel<<<gridE, 256, 0, stream>>>(ei, nid, win_in, win_out, E);
    scatter_resolve_kernel<<<gridE, 256, 0, stream>>>(ei, nid, ea,
                                                      win_in, win_out, xmod, E);

    // (3) [xl||xr] = xmod @ [Wl||Wr] + bias  (bf16 MFMA)
    gemm_mfma_kernel<<<gridG, 256, 0, stream>>>(xmod, Wfrag2 + (size_t)g * 294912,
                                                bl_g[g], br_g[g], xl, xr, N);

    // (4) CSR by dst (before attention so edge_e can be node-major)
    fill_u32_kernel<<<512, 256, 0, stream>>>(deg, 0u, (size_t)N);
    hist_kernel<<<gridE, 256, 0, stream>>>(ei, deg, E);
    scan1_kernel<<<nScanB, 256, 0, stream>>>(deg, offs, bsum, N);
    scan2_kernel<<<1, 256, 0, stream>>>(bsum, nScanB);
    scan3_kernel<<<nScanB, 256, 0, stream>>>(offs, bsum, N);
    place_kernel<<<gridE, 256, 0, stream>>>(ei, offs, csr_eid, E);

    // (5) attention logits (node-major), then fused softmax+agg+finalize
    edge_e_csr_kernel<<<gridNd, 256, 0, stream>>>(xl, xr, att_g[g], ei,
                                                  csr_eid, offs, deg, ebuf, N, E);
    node_gat_kernel<<<gridNd, 256, 0, stream>>>(ei, csr_eid, offs, deg, ebuf,
                                                xl, xmod, bias_g[g], out,
                                                N, E, g * D_DIM);
  }
}

// Round 15
// 3434.985 us; speedup vs baseline: 1.3495x; 1.0156x over previous
//
#include <hip/hip_runtime.h>
#include <cstdint>

// ---------------------------------------------------------------------------
// ForwardBackwardGNN — R15: R14 + fused attention tail.
//   LSTM: R12/R14 measured-best config (64 edges/block, 4 es, bf16 Pg unpack,
//         cst in VGPR, launch_bounds(512,4); spill latency-hidden).
//   GAT:  single wave-per-node kernel: logits (butterfly reduce) -> softmax
//         -> weighted aggregate -> finalize. xl rows re-read L1/L2-hot.
//   N=50000, E=400000, L=16, V=64, EMB=32, H=128, D=373, SID=53.
// ---------------------------------------------------------------------------

#define D_DIM   373
#define SID_N   53
#define IN_COL  161
#define OUT_COL 320
#define HS_STRIDE 136   // u16/row
#define EDGES_T 64      // edges per tile/block
#define N_ES    4       // edge sub-tiles of 16

typedef short bf16x8 __attribute__((ext_vector_type(8)));
typedef float f32x4  __attribute__((ext_vector_type(4)));

#define LOG2E_F 1.4426950408889634f
#define TWO_LOG2E_F 2.8853900817779268f

__device__ __forceinline__ float fast_exp2(float x) {
#if __has_builtin(__builtin_amdgcn_exp2f)
  return __builtin_amdgcn_exp2f(x);
#else
  return exp2f(x);
#endif
}
__device__ __forceinline__ float fast_rcp(float x) {
#if __has_builtin(__builtin_amdgcn_rcpf)
  return __builtin_amdgcn_rcpf(x);
#else
  return 1.0f / x;
#endif
}
__device__ __forceinline__ float sig_ref(float x)  { return 1.0f / (1.0f + __expf(-x)); }
__device__ __forceinline__ float tanh_ref(float x) { return 2.0f / (1.0f + __expf(-2.0f * x)) - 1.0f; }

__device__ __forceinline__ unsigned short f2bf(float f) {
  unsigned u = __float_as_uint(f);
  unsigned r = (u + 0x7fffu + ((u >> 16) & 1u)) >> 16;
  return (unsigned short)r;
}
__device__ __forceinline__ float bflo2f(unsigned u) { return __uint_as_float(u << 16); }
__device__ __forceinline__ float bfhi2f(unsigned u) { return __uint_as_float(u & 0xffff0000u); }
__device__ __forceinline__ unsigned cvt_pk_bf16(float lo, float hi) {
  unsigned r;
  asm("v_cvt_pk_bf16_f32 %0, %1, %2" : "=v"(r) : "v"(lo), "v"(hi));
  return r;
}
// sig(a)*tanh(b) with A=2^{-a*log2e} (pre-scaled), B=2^{+2b*log2e} (pre-scaled)
__device__ __forceinline__ float pair_sig_tanh(float A, float B) {
  return (B - 1.0f) * fast_rcp((1.0f + A) * (1.0f + B));
}

// ---------------- generic fill ----------------
__global__ void fill_u32_kernel(unsigned* __restrict__ p, unsigned v, size_t n) {
  size_t i = (size_t)blockIdx.x * blockDim.x + threadIdx.x;
  size_t stride = (size_t)gridDim.x * blockDim.x;
  for (; i < n; i += stride) p[i] = v;
}

// ---------------- precompute: Pg (bf16, gate-interleaved) / FB / fragments --
__global__ void precompute_kernel(
    const float* __restrict__ embed, const float* __restrict__ Wih_f,
    const float* __restrict__ Whh_f,
    const float* __restrict__ bih_f, const float* __restrict__ bhh_f,
    const float* __restrict__ Wih_r,
    const float* __restrict__ bih_r, const float* __restrict__ bhh_r,
    const float* __restrict__ W1, const float* __restrict__ b1,
    unsigned short* __restrict__ Pg, unsigned short* __restrict__ BfragW,
    unsigned short* __restrict__ Bfrag1, float* __restrict__ FB)
{
  __shared__ float ps[512];
  __shared__ float gb[512];
  __shared__ float hb[128];
  int v = blockIdx.x;
  int j = threadIdx.x;

  float s = 0.0f;
  if (v != 0) {
    #pragma unroll
    for (int k = 0; k < 32; ++k) s += embed[v * 32 + k] * Wih_f[j * 32 + k];
  }
  ps[j] = s + bih_f[j] + bhh_f[j];

  float gr = bih_r[j] + bhh_r[j];
  if (v != 0) {
    #pragma unroll
    for (int k = 0; k < 32; ++k) gr += embed[v * 32 + k] * Wih_r[j * 32 + k];
  }
  gb[j] = gr;
  __syncthreads();
  if (j < 128) {
    float c = sig_ref(gb[j]) * tanh_ref(gb[256 + j]);
    hb[j] = sig_ref(gb[384 + j]) * tanh_ref(c);
  }
  __syncthreads();

  // Pg[v][h][g] = bf16(scale(g) * P[v][g*128+h])
  { int h = j >> 2, g = j & 3;
    float sc = (g == 2) ? TWO_LOG2E_F : -LOG2E_F;
    Pg[((size_t)v * 128 + h) * 4 + g] = f2bf(ps[g * 128 + h] * sc); }

  if (j < 32) {
    float s2 = b1[j];
    for (int m = 0; m < 128; ++m) s2 += hb[m] * W1[(128 + m) * 32 + j];
    FB[v * 32 + j] = s2;
  }

  if (v == 0) {
    // BfragW flat = ((nt*4+ks)*64 + lane)*8 + e ; val = scale * Whh_f[n][k]
    for (int f = j; f < 65536; f += 512) {
      int e = f & 7, l = (f >> 3) & 63, ks = (f >> 9) & 3, nt = f >> 11;
      int n = nt * 16 + (l & 15);
      int k = ks * 32 + (l >> 4) * 8 + e;
      float sc = ((nt >> 3) == 2) ? TWO_LOG2E_F : -LOG2E_F;
      BfragW[f] = f2bf(Whh_f[(size_t)n * 128 + k] * sc);
    }
  }
  if (v == 1) {
    // Bfrag1 flat = ((n2*4+ks)*64 + lane)*8 + e ; B[k][q] = W1[k][q] (k<128)
    for (int f = j; f < 4096; f += 512) {
      int e = f & 7, l = (f >> 3) & 63, ks = (f >> 9) & 3, n2 = f >> 11;
      int q = n2 * 16 + (l & 15);
      int k = ks * 32 + (l >> 4) * 8 + e;
      Bfrag1[f] = f2bf(W1[(size_t)k * 32 + q]);
    }
  }
}

// ---------------- MFMA LSTM: 64 edges/block, 8 waves, 1 barrier/step --------
// mfma(A=W-frag, B=H-frag) -> D: col=lane&15=edge(sub), row=(lane>>4)*4+r=hcol.
// Wave wv2 owns hcols [wv2*16,+16) x 4 gates for all 4 edge sub-tiles.
__global__ __launch_bounds__(512, 4) void lstm_mfma_kernel(
    const int*   __restrict__ tokens,   // [E][16]
    const unsigned short* __restrict__ Pg,      // [64][128][4] bf16 (scaled)
    const unsigned short* __restrict__ BfragW,  // [32][4][64][8] bf16 (scaled)
    const unsigned short* __restrict__ Bfrag1,  // [2][4][64][8] bf16
    const float* __restrict__ FB,       // [64][32]
    const float* __restrict__ W2,       // [32]
    const float* __restrict__ b2,
    float* __restrict__ ea, int E, int nTiles)
{
  __shared__ unsigned short Hs[2][EDGES_T * HS_STRIDE];  // 34,816 B
  __shared__ int toks[16][EDGES_T];                      //  4,096 B

  int tid  = threadIdx.x;
  int lane = tid & 63;
  int wv2  = tid >> 6;                  // 0..7
  int l15  = lane & 15;
  int lg   = lane >> 4;                 // 0..3
  int hbase = wv2 * 16 + lg * 4;        // this lane's 4 hcols

  // persistent A-frags (W): BW[gate][ks] — 64 regs (AGPR)
  bf16x8 BW[4][4];
  #pragma unroll
  for (int gate = 0; gate < 4; ++gate)
    #pragma unroll
    for (int ks = 0; ks < 4; ++ks)
      BW[gate][ks] = *(const bf16x8*)(BfragW +
          ((size_t)((gate * 8 + wv2) * 4 + ks) * 64 + lane) * 8);

  for (int tile = blockIdx.x; tile < nTiles; tile += gridDim.x) {
    int e0 = tile * EDGES_T;
    for (int i = tid; i < 16 * EDGES_T; i += 512) {   // stage tokens [t][m]
      int m = i >> 4, t = i & 15;
      int ee = e0 + m; if (ee >= E) ee = E - 1;
      toks[t][m] = tokens[(size_t)ee * 16 + t];
    }
    __syncthreads();

    f32x4 cst[N_ES];   // statically indexed (es fully unrolled)
    // ---- step 0: gates = P only (h0=c0=0, f-term vanishes)
    #pragma unroll
    for (int es = 0; es < N_ES; ++es) {
      int eL = es * 16 + l15;
      int v0 = toks[0][eL];
      const uint4* pp = (const uint4*)(Pg + ((size_t)v0 * 128 + hbase) * 4);
      uint4 pa = pp[0], pb = pp[1];
      float pi[4] = {bflo2f(pa.x), bflo2f(pa.z), bflo2f(pb.x), bflo2f(pb.z)};
      float pg[4] = {bflo2f(pa.y), bflo2f(pa.w), bflo2f(pb.y), bflo2f(pb.w)};
      float po[4] = {bfhi2f(pa.y), bfhi2f(pa.w), bfhi2f(pb.y), bfhi2f(pb.w)};
      float h[4];
      #pragma unroll
      for (int r = 0; r < 4; ++r) {
        float A = fast_exp2(pi[r]);
        float B = fast_exp2(pg[r]);
        float O = fast_exp2(po[r]);
        float cn = pair_sig_tanh(A, B);     // i*g
        cst[es][r] = cn;
        float C = fast_exp2(TWO_LOG2E_F * cn);
        h[r] = pair_sig_tanh(O, C);         // o*tanh(c)
      }
      uint2 hp = make_uint2(cvt_pk_bf16(h[0], h[1]), cvt_pk_bf16(h[2], h[3]));
      *(uint2*)(&Hs[0][eL * HS_STRIDE + hbase]) = hp;
    }
    __syncthreads();

    int cur = 0;
    #pragma unroll 1
    for (int t = 1; t < 16; ++t) {
      #pragma unroll
      for (int es = 0; es < N_ES; ++es) {
        int eL = es * 16 + l15;
        int vt = toks[t][eL];
        const uint4* pp = (const uint4*)(Pg + ((size_t)vt * 128 + hbase) * 4);
        uint4 pa = pp[0], pb = pp[1];
        f32x4 acc[4];
        acc[0] = (f32x4){bflo2f(pa.x), bflo2f(pa.z), bflo2f(pb.x), bflo2f(pb.z)}; // i
        acc[1] = (f32x4){bfhi2f(pa.x), bfhi2f(pa.z), bfhi2f(pb.x), bfhi2f(pb.z)}; // f
        acc[2] = (f32x4){bflo2f(pa.y), bflo2f(pa.w), bflo2f(pb.y), bflo2f(pb.w)}; // g
        acc[3] = (f32x4){bfhi2f(pa.y), bfhi2f(pa.w), bfhi2f(pb.y), bfhi2f(pb.w)}; // o

        #pragma unroll
        for (int ks = 0; ks < 4; ++ks) {
          bf16x8 Hf = *(const bf16x8*)(&Hs[cur][eL * HS_STRIDE + ks * 32 + lg * 8]);
          #pragma unroll
          for (int gate = 0; gate < 4; ++gate)
            acc[gate] = __builtin_amdgcn_mfma_f32_16x16x32_bf16(
                BW[gate][ks], Hf, acc[gate], 0, 0, 0);
        }

        float h[4];
        #pragma unroll
        for (int r = 0; r < 4; ++r) {
          float A = fast_exp2(acc[0][r]);
          float F = fast_exp2(acc[1][r]);
          float B = fast_exp2(acc[2][r]);
          float O = fast_exp2(acc[3][r]);
          float ig = pair_sig_tanh(A, B);
          float f  = fast_rcp(1.0f + F);
          float cn = fmaf(f, cst[es][r], ig);
          cst[es][r] = cn;
          float C = fast_exp2(TWO_LOG2E_F * cn);
          h[r] = pair_sig_tanh(O, C);
        }
        uint2 hp = make_uint2(cvt_pk_bf16(h[0], h[1]), cvt_pk_bf16(h[2], h[3]));
        *(uint2*)(&Hs[cur ^ 1][eL * HS_STRIDE + hbase]) = hp;
      }
      cur ^= 1;
      __syncthreads();
    }

    // ---- tail: waves 0..3 each handle edge sub-tile es=wv2.
    if (wv2 < N_ES) {
      int eL = wv2 * 16 + l15;
      bf16x8 Hf[4];
      #pragma unroll
      for (int ks = 0; ks < 4; ++ks)
        Hf[ks] = *(const bf16x8*)(&Hs[cur][eL * HS_STRIDE + ks * 32 + lg * 8]);
      f32x4 a2[2];
      a2[0] = (f32x4){0.f, 0.f, 0.f, 0.f};
      a2[1] = (f32x4){0.f, 0.f, 0.f, 0.f};
      #pragma unroll
      for (int ks = 0; ks < 4; ++ks)
        #pragma unroll
        for (int n2 = 0; n2 < 2; ++n2)
          a2[n2] = __builtin_amdgcn_mfma_f32_16x16x32_bf16(
              *(const bf16x8*)(Bfrag1 + ((size_t)(n2 * 4 + ks) * 64 + lane) * 8),
              Hf[ks], a2[n2], 0, 0, 0);
      float4 w2lo = *(const float4*)(W2 + lg * 4);
      float4 w2hi = *(const float4*)(W2 + 16 + lg * 4);
      float b2v = b2[0];
      int v15 = toks[15][eL];
      float4 fb0 = *(const float4*)(FB + v15 * 32 + lg * 4);
      float4 fb1 = *(const float4*)(FB + v15 * 32 + 16 + lg * 4);
      float pr = fmaxf(a2[0][0] + fb0.x, 0.f) * w2lo.x
               + fmaxf(a2[0][1] + fb0.y, 0.f) * w2lo.y
               + fmaxf(a2[0][2] + fb0.z, 0.f) * w2lo.z
               + fmaxf(a2[0][3] + fb0.w, 0.f) * w2lo.w
               + fmaxf(a2[1][0] + fb1.x, 0.f) * w2hi.x
               + fmaxf(a2[1][1] + fb1.y, 0.f) * w2hi.y
               + fmaxf(a2[1][2] + fb1.z, 0.f) * w2hi.z
               + fmaxf(a2[1][3] + fb1.w, 0.f) * w2hi.w;
      pr += __shfl_xor(pr, 16);
      pr += __shfl_xor(pr, 32);
      int eidx = e0 + eL;
      if (lane < 16 && eidx < E) ea[eidx] = fmaxf(pr + b2v, 0.0f);
    }
    __syncthreads();   // before next tile reuses toks/Hs
  }
}

// ---------------- per-node argmax over x[:, :53] (wave per node) -----------
__global__ __launch_bounds__(256) void node_argmax_kernel(
    const float* __restrict__ x, int* __restrict__ nid, int N)
{
  int n = (blockIdx.x * 256 + threadIdx.x) >> 6;
  int lane = threadIdx.x & 63;
  if (n >= N) return;
  float v = (lane < SID_N) ? x[(size_t)n * D_DIM + lane] : -3.4e38f;
  int idx = lane;
  #pragma unroll
  for (int o = 32; o > 0; o >>= 1) {
    float ov = __shfl_down(v, o);
    int   oi = __shfl_down(idx, o);
    if (ov > v || (ov == v && oi < idx)) { v = ov; idx = oi; }
  }
  if (lane == 0) nid[n] = idx;
}

// ---------------- edge winner (last edge wins) + resolve -------------------
__global__ void edge_winner_kernel(
    const int* __restrict__ ei, const int* __restrict__ nid,
    int* __restrict__ win_in, int* __restrict__ win_out, int E)
{
  int e = blockIdx.x * 256 + threadIdx.x;
  if (e >= E) return;
  int s = ei[e];
  int t = ei[E + e];
  atomicMax(&win_in[(size_t)t * SID_N + nid[s]], e);
  atomicMax(&win_out[(size_t)s * SID_N + nid[t]], e);
}

__global__ void scatter_resolve_kernel(
    const int* __restrict__ ei, const int* __restrict__ nid,
    const float* __restrict__ ea,
    const int* __restrict__ win_in, const int* __restrict__ win_out,
    float* __restrict__ x_mod, int E)
{
  int e = blockIdx.x * 256 + threadIdx.x;
  if (e >= E) return;
  int s = ei[e];
  int t = ei[E + e];
  int sid = nid[s], tix = nid[t];
  if (win_in[(size_t)t * SID_N + sid] == e)
    x_mod[(size_t)t * D_DIM + IN_COL + sid] = ea[e];
  if (win_out[(size_t)s * SID_N + tix] == e)
    x_mod[(size_t)s * D_DIM + OUT_COL + tix] = ea[e];
}

// ---------------- pack Wl||Wr into MFMA fragment order ----------------
__global__ void pack_w_kernel(const float* __restrict__ Wl,
                              const float* __restrict__ Wr,
                              unsigned short* __restrict__ Wfrag)
{
  int f = blockIdx.x * 256 + threadIdx.x;
  if (f >= 48 * 12 * 64 * 8) return;
  int e = f & 7, l = (f >> 3) & 63;
  int rest = f >> 9;
  int ks = rest % 12, nt = rest / 12;
  int nl = nt * 16 + (l & 15);
  int k  = ks * 32 + (l >> 4) * 8 + e;
  float val = 0.0f;
  if (k < D_DIM) {
    if (nl < D_DIM)                      val = Wl[(size_t)k * D_DIM + nl];
    else if (nl >= 384 && nl < 384 + D_DIM) val = Wr[(size_t)k * D_DIM + (nl - 384)];
  }
  Wfrag[f] = f2bf(val);
}

// ---------------- fused bf16 MFMA GEMM: [xl||xr] = xmod @ [Wl||Wr] + bias ----
__global__ __launch_bounds__(256, 2) void gemm_mfma_kernel(
    const float* __restrict__ A,               // xmod [N][373] fp32
    const unsigned short* __restrict__ Wfrag,  // [48][12][64][8] bf16
    const float* __restrict__ bl, const float* __restrict__ br,
    float* __restrict__ xl, float* __restrict__ xr, int N)
{
  __shared__ unsigned short As[64][40];
  int tid  = threadIdx.x;
  int lane = tid & 63;
  int wv   = tid >> 6;
  int l15  = lane & 15, lg = lane >> 4;
  int m0   = blockIdx.x * 64;
  int nt   = blockIdx.y * 4 + wv;

  f32x4 acc[4];
  #pragma unroll
  for (int i = 0; i < 4; ++i) acc[i] = (f32x4){0.f, 0.f, 0.f, 0.f};

  int srow = tid >> 2, seg = tid & 3;
  int gr = m0 + srow; if (gr >= N) gr = N - 1;
  const float* arow = A + (size_t)gr * D_DIM;

  for (int ks = 0; ks < 12; ++ks) {
    int c0 = ks * 32 + seg * 8;
    float v[8];
    #pragma unroll
    for (int j = 0; j < 8; ++j) v[j] = (c0 + j < D_DIM) ? arow[c0 + j] : 0.0f;
    unsigned pk0 = cvt_pk_bf16(v[0], v[1]);
    unsigned pk1 = cvt_pk_bf16(v[2], v[3]);
    unsigned pk2 = cvt_pk_bf16(v[4], v[5]);
    unsigned pk3 = cvt_pk_bf16(v[6], v[7]);
    __syncthreads();
    *(uint4*)(&As[srow][seg * 8]) = make_uint4(pk0, pk1, pk2, pk3);
    __syncthreads();

    bf16x8 Bf = *(const bf16x8*)(Wfrag + ((size_t)(nt * 12 + ks) * 64 + lane) * 8);
    #pragma unroll
    for (int msub = 0; msub < 4; ++msub) {
      bf16x8 Af = *(const bf16x8*)(&As[msub * 16 + l15][lg * 8]);
      acc[msub] = __builtin_amdgcn_mfma_f32_16x16x32_bf16(Af, Bf, acc[msub], 0, 0, 0);
    }
  }

  int nl = nt * 16 + l15;
  float* dst = nullptr; int col = 0; const float* bias_ = nullptr;
  if (nl < D_DIM)                         { dst = xl; col = nl;       bias_ = bl; }
  else if (nl >= 384 && nl < 384 + D_DIM) { dst = xr; col = nl - 384; bias_ = br; }
  if (dst) {
    float bv = bias_[col];
    #pragma unroll
    for (int msub = 0; msub < 4; ++msub) {
      #pragma unroll
      for (int r = 0; r < 4; ++r) {
        int m = m0 + msub * 16 + lg * 4 + r;
        if (m < N) dst[(size_t)m * D_DIM + col] = acc[msub][r] + bv;
      }
    }
  }
}

// ---------------- CSR build: histogram / scan / placement ----------------
__global__ void hist_kernel(const int* __restrict__ ei, unsigned* __restrict__ deg,
                            int E) {
  int e = blockIdx.x * 256 + threadIdx.x;
  if (e >= E) return;
  atomicAdd(&deg[ei[E + e]], 1u);
}

__global__ void scan1_kernel(const unsigned* __restrict__ deg,
                             unsigned* __restrict__ excl,
                             unsigned* __restrict__ bsum, int n) {
  __shared__ unsigned s[256];
  int t = threadIdx.x;
  int i = blockIdx.x * 256 + t;
  unsigned v = (i < n) ? deg[i] : 0u;
  s[t] = v; __syncthreads();
  #pragma unroll
  for (int o = 1; o < 256; o <<= 1) {
    unsigned u = (t >= o) ? s[t - o] : 0u;
    __syncthreads();
    s[t] += u;
    __syncthreads();
  }
  if (i < n) excl[i] = s[t] - v;
  if (t == 255) bsum[blockIdx.x] = s[255];
}

__global__ void scan2_kernel(unsigned* __restrict__ bsum, int nb) {
  __shared__ unsigned s[256];
  int t = threadIdx.x;
  unsigned v = (t < nb) ? bsum[t] : 0u;
  s[t] = v; __syncthreads();
  #pragma unroll
  for (int o = 1; o < 256; o <<= 1) {
    unsigned u = (t >= o) ? s[t - o] : 0u;
    __syncthreads();
    s[t] += u;
    __syncthreads();
  }
  if (t < nb) bsum[t] = s[t] - v;   // exclusive
}

__global__ void scan3_kernel(unsigned* __restrict__ excl,
                             const unsigned* __restrict__ bsum, int n) {
  int i = blockIdx.x * 256 + threadIdx.x;
  if (i < n) excl[i] += bsum[i >> 8];
}

__global__ void place_kernel(const int* __restrict__ ei,
                             unsigned* __restrict__ offs,
                             int* __restrict__ csr_eid, int E) {
  int e = blockIdx.x * 256 + threadIdx.x;
  if (e >= E) return;
  unsigned j = atomicAdd(&offs[ei[E + e]], 1u);
  csr_eid[j] = e;
}

// ---------------- fused per-node GAT: logits + softmax + agg + finalize ----
// wave per node; 3 passes over the node's edge list. xl rows touched in
// pass 1 are L1/L2-hot for pass 3 (per-node working set ~12KB).
__global__ __launch_bounds__(256) void node_gat_fused_kernel(
    const float* __restrict__ xl, const float* __restrict__ xr,
    const float* __restrict__ att, const int* __restrict__ ei,
    const int* __restrict__ csr_eid, const unsigned* __restrict__ offs,
    const unsigned* __restrict__ deg, float* __restrict__ ebuf,
    const float* __restrict__ xmod, const float* __restrict__ bias,
    float* __restrict__ out, int N, int E, int goff)
{
  int n = (blockIdx.x * 256 + threadIdx.x) >> 6;
  int lane = threadIdx.x & 63;
  if (n >= N) return;
  unsigned end = offs[n], d = deg[n], start = end - d;

  // ---- pass 1: logits (leaky(xl[s]+xr[n]).att), butterfly-reduced, + max
  const float* xrn = xr + (size_t)n * D_DIM;
  float r0 = xrn[lane],        a0 = att[lane];
  float r1 = xrn[64 + lane],   a1 = att[64 + lane];
  float r2 = xrn[128 + lane],  a2 = att[128 + lane];
  float r3 = xrn[192 + lane],  a3 = att[192 + lane];
  float r4 = xrn[256 + lane],  a4 = att[256 + lane];
  float r5 = 0.f, a5 = 0.f;
  if (lane < 53) { r5 = xrn[320 + lane]; a5 = att[320 + lane]; }

  float mx = -3.4e38f;
  for (unsigned j = start; j < end; ++j) {
    int eid = csr_eid[j];
    const float* row = xl + (size_t)ei[eid] * D_DIM;
    float m, acc;
    m = row[lane] + r0;        acc  = ((m > 0.f) ? m : 0.2f * m) * a0;
    m = row[64 + lane] + r1;   acc += ((m > 0.f) ? m : 0.2f * m) * a1;
    m = row[128 + lane] + r2;  acc += ((m > 0.f) ? m : 0.2f * m) * a2;
    m = row[192 + lane] + r3;  acc += ((m > 0.f) ? m : 0.2f * m) * a3;
    m = row[256 + lane] + r4;  acc += ((m > 0.f) ? m : 0.2f * m) * a4;
    if (lane < 53) { m = row[320 + lane] + r5; acc += ((m > 0.f) ? m : 0.2f * m) * a5; }
    // butterfly: every lane ends with the full sum
    acc += __shfl_xor(acc, 1);
    acc += __shfl_xor(acc, 2);
    acc += __shfl_xor(acc, 4);
    acc += __shfl_xor(acc, 8);
    acc += __shfl_xor(acc, 16);
    acc += __shfl_xor(acc, 32);
    if (lane == 0) ebuf[eid] = acc;
    mx = fmaxf(mx, acc);
  }

  // ---- pass 2: exp + denominator (ebuf L2-hot)
  float den = 0.0f;
  for (unsigned j = start; j < end; ++j) {
    int eid = csr_eid[j];
    float ex = __expf(ebuf[eid] - mx);
    if (lane == 0) ebuf[eid] = ex;
    den += ex;
  }
  float inv = 1.0f / (den + 1e-16f);

  // ---- pass 3: weighted aggregate (xl rows L1/L2-hot from pass 1)
  float o0 = 0, o1 = 0, o2 = 0, o3 = 0, o4 = 0, o5 = 0;
  for (unsigned j = start; j < end; ++j) {
    int eid = csr_eid[j];
    float w = ebuf[eid] * inv;
    const float* row = xl + (size_t)ei[eid] * D_DIM;
    o0 = fmaf(w, row[lane], o0);
    o1 = fmaf(w, row[64 + lane], o1);
    o2 = fmaf(w, row[128 + lane], o2);
    o3 = fmaf(w, row[192 + lane], o3);
    o4 = fmaf(w, row[256 + lane], o4);
    if (lane < 53) o5 = fmaf(w, row[320 + lane], o5);
  }

  const float* xm = xmod + (size_t)n * D_DIM;
  float* op = out + (size_t)n * (2 * D_DIM) + goff;
  op[lane]       = fmaxf(o0 + bias[lane]       + xm[lane],       0.0f);
  op[64 + lane]  = fmaxf(o1 + bias[64 + lane]  + xm[64 + lane],  0.0f);
  op[128 + lane] = fmaxf(o2 + bias[128 + lane] + xm[128 + lane], 0.0f);
  op[192 + lane] = fmaxf(o3 + bias[192 + lane] + xm[192 + lane], 0.0f);
  op[256 + lane] = fmaxf(o4 + bias[256 + lane] + xm[256 + lane], 0.0f);
  if (lane < 53)
    op[320 + lane] = fmaxf(o5 + bias[320 + lane] + xm[320 + lane], 0.0f);
}

// ---------------------------------------------------------------------------
extern "C" void kernel_launch(void* const* d_in, const int* in_sizes, int n_in,
                              void* d_out, int out_size, void* d_ws, size_t ws_size,
                              hipStream_t stream)
{
  const float* fx     = (const float*)d_in[0];
  const float* bx     = (const float*)d_in[1];
  const int*   fei    = (const int*)d_in[2];
  const int*   bei    = (const int*)d_in[3];
  const int*   ftk    = (const int*)d_in[4];
  const int*   btk    = (const int*)d_in[5];
  const float* embed  = (const float*)d_in[6];
  const float* Wih_f  = (const float*)d_in[7];
  const float* Whh_f  = (const float*)d_in[8];
  const float* bih_f  = (const float*)d_in[9];
  const float* bhh_f  = (const float*)d_in[10];
  const float* Wih_r  = (const float*)d_in[11];
  // d_in[12] = Whh_r : unused (reverse cell consumes zero state)
  const float* bih_r  = (const float*)d_in[13];
  const float* bhh_r  = (const float*)d_in[14];
  const float* W1     = (const float*)d_in[15];
  const float* b1     = (const float*)d_in[16];
  const float* W2     = (const float*)d_in[17];
  const float* b2     = (const float*)d_in[18];

  const float* Wl_g[2]   = {(const float*)d_in[19], (const float*)d_in[25]};
  const float* bl_g[2]   = {(const float*)d_in[20], (const float*)d_in[26]};
  const float* Wr_g[2]   = {(const float*)d_in[21], (const float*)d_in[27]};
  const float* br_g[2]   = {(const float*)d_in[22], (const float*)d_in[28]};
  const float* att_g[2]  = {(const float*)d_in[23], (const float*)d_in[29]};
  const float* bias_g[2] = {(const float*)d_in[24], (const float*)d_in[30]};
  const float* x_g[2]    = {fx, bx};
  const int*   ei_g[2]   = {fei, bei};
  const int*   tk_g[2]   = {ftk, btk};

  const int E = in_sizes[2] / 2;          // 400000
  const int N = in_sizes[0] / D_DIM;      // 50000

  // ---- workspace layout (byte-based, 256B aligned chunks) ----
  char* wsb = (char*)d_ws;
  size_t off = 0;
  auto alloc = [&](size_t bytes) -> void* {
    void* p = wsb + off; off += (bytes + 255) & ~(size_t)255; return p;
  };
  unsigned short* Pg     = (unsigned short*)alloc((size_t)64 * 128 * 4 * 2);
  unsigned short* BfragW = (unsigned short*)alloc((size_t)65536 * 2);
  unsigned short* Bfrag1 = (unsigned short*)alloc((size_t)4096 * 2);
  unsigned short* Wfrag2 = (unsigned short*)alloc((size_t)2 * 294912 * 2);
  float* FB    = (float*)alloc((size_t)64 * 32 * 4);
  float* ea    = (float*)alloc((size_t)E * 4);
  float* ebuf  = (float*)alloc((size_t)E * 4);
  int*   nid   = (int*)alloc((size_t)N * 4);
  int*   csr_eid = (int*)alloc((size_t)E * 4);
  unsigned* deg  = (unsigned*)alloc((size_t)N * 4);
  unsigned* offs = (unsigned*)alloc((size_t)N * 4);
  unsigned* bsum = (unsigned*)alloc((size_t)256 * 4);
  int* win_in  = (int*)alloc((size_t)N * SID_N * 4);
  int* win_out = (int*)alloc((size_t)N * SID_N * 4);
  float* xmod  = (float*)alloc((size_t)N * D_DIM * 4);
  float* xl    = (float*)alloc((size_t)N * D_DIM * 4);
  float* xr    = (float*)alloc((size_t)N * D_DIM * 4);
  (void)ws_size; (void)n_in; (void)out_size;

  const size_t win_u32 = (size_t)((char*)win_out - (char*)win_in) / 4
                         + (size_t)N * SID_N;

  float* out = (float*)d_out;

  precompute_kernel<<<64, 512, 0, stream>>>(
      embed, Wih_f, Whh_f, bih_f, bhh_f, Wih_r, bih_r, bhh_r, W1, b1,
      Pg, BfragW, Bfrag1, FB);
  pack_w_kernel<<<(294912 + 255) / 256, 256, 0, stream>>>(
      Wl_g[0], Wr_g[0], Wfrag2);
  pack_w_kernel<<<(294912 + 255) / 256, 256, 0, stream>>>(
      Wl_g[1], Wr_g[1], Wfrag2 + 294912);

  const int nTiles  = (E + EDGES_T - 1) / EDGES_T;   // 6250
  const int gridL   = nTiles < 2048 ? nTiles : 2048;
  const int gridE   = (E + 255) / 256;
  const int nScanB  = (N + 255) / 256;
  const int gridNd  = (N * 64 + 255) / 256;
  dim3 gridG((N + 63) / 64, 12);

  for (int g = 0; g < 2; ++g) {
    const float* x  = x_g[g];
    const int*   ei = ei_g[g];

    // (1) edge scalar via MFMA LSTM
    lstm_mfma_kernel<<<gridL, 512, 0, stream>>>(tk_g[g], Pg, BfragW, Bfrag1,
                                                FB, W2, b2, ea, E, nTiles);

    // (2) x_mod = copy(x); per-node argmax; last-edge-wins scatter writes
    hipMemcpyAsync(xmod, x, (size_t)N * D_DIM * sizeof(float),
                   hipMemcpyDeviceToDevice, stream);
    node_argmax_kernel<<<gridNd, 256, 0, stream>>>(x, nid, N);
    fill_u32_kernel<<<2048, 256, 0, stream>>>((unsigned*)win_in, 0xFFFFFFFFu,
                                              win_u32);
    edge_winner_kernel<<<gridE, 256, 0, stream>>>(ei, nid, win_in, win_out, E);
    scatter_resolve_kernel<<<gridE, 256, 0, stream>>>(ei, nid, ea,
                                                      win_in, win_out, xmod, E);

    // (3) [xl||xr] = xmod @ [Wl||Wr] + bias  (bf16 MFMA)
    gemm_mfma_kernel<<<gridG, 256, 0, stream>>>(xmod, Wfrag2 + (size_t)g * 294912,
                                                bl_g[g], br_g[g], xl, xr, N);

    // (4) CSR by dst
    fill_u32_kernel<<<512, 256, 0, stream>>>(deg, 0u, (size_t)N);
    hist_kernel<<<gridE, 256, 0, stream>>>(ei, deg, E);
    scan1_kernel<<<nScanB, 256, 0, stream>>>(deg, offs, bsum, N);
    scan2_kernel<<<1, 256, 0, stream>>>(bsum, nScanB);
    scan3_kernel<<<nScanB, 256, 0, stream>>>(offs, bsum, N);
    place_kernel<<<gridE, 256, 0, stream>>>(ei, offs, csr_eid, E);

    // (5) fused attention: logits + softmax + aggregate + finalize
    node_gat_fused_kernel<<<gridNd, 256, 0, stream>>>(
        xl, xr, att_g[g], ei, csr_eid, offs, deg, ebuf, xmod, bias_g[g],
        out, N, E, g * D_DIM);
  }
}

// Round 16
// 3427.916 us; speedup vs baseline: 1.3523x; 1.0021x over previous
//
#include <hip/hip_runtime.h>
#include <cstdint>

// ---------------------------------------------------------------------------
// ForwardBackwardGNN — R15: R14 + fused attention tail.
//   LSTM: R12/R14 measured-best config (64 edges/block, 4 es, bf16 Pg unpack,
//         cst in VGPR, launch_bounds(512,4); spill latency-hidden).
//   GAT:  single wave-per-node kernel: logits (butterfly reduce) -> softmax
//         -> weighted aggregate -> finalize. xl rows re-read L1/L2-hot.
//   N=50000, E=400000, L=16, V=64, EMB=32, H=128, D=373, SID=53.
// ---------------------------------------------------------------------------

#define D_DIM   373
#define SID_N   53
#define IN_COL  161
#define OUT_COL 320
#define HS_STRIDE 136   // u16/row
#define EDGES_T 64      // edges per tile/block
#define N_ES    4       // edge sub-tiles of 16

typedef short bf16x8 __attribute__((ext_vector_type(8)));
typedef float f32x4  __attribute__((ext_vector_type(4)));

#define LOG2E_F 1.4426950408889634f
#define TWO_LOG2E_F 2.8853900817779268f

__device__ __forceinline__ float fast_exp2(float x) {
#if __has_builtin(__builtin_amdgcn_exp2f)
  return __builtin_amdgcn_exp2f(x);
#else
  return exp2f(x);
#endif
}
__device__ __forceinline__ float fast_rcp(float x) {
#if __has_builtin(__builtin_amdgcn_rcpf)
  return __builtin_amdgcn_rcpf(x);
#else
  return 1.0f / x;
#endif
}
__device__ __forceinline__ float sig_ref(float x)  { return 1.0f / (1.0f + __expf(-x)); }
__device__ __forceinline__ float tanh_ref(float x) { return 2.0f / (1.0f + __expf(-2.0f * x)) - 1.0f; }

__device__ __forceinline__ unsigned short f2bf(float f) {
  unsigned u = __float_as_uint(f);
  unsigned r = (u + 0x7fffu + ((u >> 16) & 1u)) >> 16;
  return (unsigned short)r;
}
__device__ __forceinline__ float bflo2f(unsigned u) { return __uint_as_float(u << 16); }
__device__ __forceinline__ float bfhi2f(unsigned u) { return __uint_as_float(u & 0xffff0000u); }
__device__ __forceinline__ unsigned cvt_pk_bf16(float lo, float hi) {
  unsigned r;
  asm("v_cvt_pk_bf16_f32 %0, %1, %2" : "=v"(r) : "v"(lo), "v"(hi));
  return r;
}
// sig(a)*tanh(b) with A=2^{-a*log2e} (pre-scaled), B=2^{+2b*log2e} (pre-scaled)
__device__ __forceinline__ float pair_sig_tanh(float A, float B) {
  return (B - 1.0f) * fast_rcp((1.0f + A) * (1.0f + B));
}

// ---------------- generic fill ----------------
__global__ void fill_u32_kernel(unsigned* __restrict__ p, unsigned v, size_t n) {
  size_t i = (size_t)blockIdx.x * blockDim.x + threadIdx.x;
  size_t stride = (size_t)gridDim.x * blockDim.x;
  for (; i < n; i += stride) p[i] = v;
}

// ---------------- precompute: Pg (bf16, gate-interleaved) / FB / fragments --
__global__ void precompute_kernel(
    const float* __restrict__ embed, const float* __restrict__ Wih_f,
    const float* __restrict__ Whh_f,
    const float* __restrict__ bih_f, const float* __restrict__ bhh_f,
    const float* __restrict__ Wih_r,
    const float* __restrict__ bih_r, const float* __restrict__ bhh_r,
    const float* __restrict__ W1, const float* __restrict__ b1,
    unsigned short* __restrict__ Pg, unsigned short* __restrict__ BfragW,
    unsigned short* __restrict__ Bfrag1, float* __restrict__ FB)
{
  __shared__ float ps[512];
  __shared__ float gb[512];
  __shared__ float hb[128];
  int v = blockIdx.x;
  int j = threadIdx.x;

  float s = 0.0f;
  if (v != 0) {
    #pragma unroll
    for (int k = 0; k < 32; ++k) s += embed[v * 32 + k] * Wih_f[j * 32 + k];
  }
  ps[j] = s + bih_f[j] + bhh_f[j];

  float gr = bih_r[j] + bhh_r[j];
  if (v != 0) {
    #pragma unroll
    for (int k = 0; k < 32; ++k) gr += embed[v * 32 + k] * Wih_r[j * 32 + k];
  }
  gb[j] = gr;
  __syncthreads();
  if (j < 128) {
    float c = sig_ref(gb[j]) * tanh_ref(gb[256 + j]);
    hb[j] = sig_ref(gb[384 + j]) * tanh_ref(c);
  }
  __syncthreads();

  // Pg[v][h][g] = bf16(scale(g) * P[v][g*128+h])
  { int h = j >> 2, g = j & 3;
    float sc = (g == 2) ? TWO_LOG2E_F : -LOG2E_F;
    Pg[((size_t)v * 128 + h) * 4 + g] = f2bf(ps[g * 128 + h] * sc); }

  if (j < 32) {
    float s2 = b1[j];
    for (int m = 0; m < 128; ++m) s2 += hb[m] * W1[(128 + m) * 32 + j];
    FB[v * 32 + j] = s2;
  }

  if (v == 0) {
    // BfragW flat = ((nt*4+ks)*64 + lane)*8 + e ; val = scale * Whh_f[n][k]
    for (int f = j; f < 65536; f += 512) {
      int e = f & 7, l = (f >> 3) & 63, ks = (f >> 9) & 3, nt = f >> 11;
      int n = nt * 16 + (l & 15);
      int k = ks * 32 + (l >> 4) * 8 + e;
      float sc = ((nt >> 3) == 2) ? TWO_LOG2E_F : -LOG2E_F;
      BfragW[f] = f2bf(Whh_f[(size_t)n * 128 + k] * sc);
    }
  }
  if (v == 1) {
    // Bfrag1 flat = ((n2*4+ks)*64 + lane)*8 + e ; B[k][q] = W1[k][q] (k<128)
    for (int f = j; f < 4096; f += 512) {
      int e = f & 7, l = (f >> 3) & 63, ks = (f >> 9) & 3, n2 = f >> 11;
      int q = n2 * 16 + (l & 15);
      int k = ks * 32 + (l >> 4) * 8 + e;
      Bfrag1[f] = f2bf(W1[(size_t)k * 32 + q]);
    }
  }
}

// ---------------- MFMA LSTM: 64 edges/block, 8 waves, 1 barrier/step --------
// mfma(A=W-frag, B=H-frag) -> D: col=lane&15=edge(sub), row=(lane>>4)*4+r=hcol.
// Wave wv2 owns hcols [wv2*16,+16) x 4 gates for all 4 edge sub-tiles.
__global__ __launch_bounds__(512, 4) void lstm_mfma_kernel(
    const int*   __restrict__ tokens,   // [E][16]
    const unsigned short* __restrict__ Pg,      // [64][128][4] bf16 (scaled)
    const unsigned short* __restrict__ BfragW,  // [32][4][64][8] bf16 (scaled)
    const unsigned short* __restrict__ Bfrag1,  // [2][4][64][8] bf16
    const float* __restrict__ FB,       // [64][32]
    const float* __restrict__ W2,       // [32]
    const float* __restrict__ b2,
    float* __restrict__ ea, int E, int nTiles)
{
  __shared__ unsigned short Hs[2][EDGES_T * HS_STRIDE];  // 34,816 B
  __shared__ int toks[16][EDGES_T];                      //  4,096 B

  int tid  = threadIdx.x;
  int lane = tid & 63;
  int wv2  = tid >> 6;                  // 0..7
  int l15  = lane & 15;
  int lg   = lane >> 4;                 // 0..3
  int hbase = wv2 * 16 + lg * 4;        // this lane's 4 hcols

  // persistent A-frags (W): BW[gate][ks] — 64 regs (AGPR)
  bf16x8 BW[4][4];
  #pragma unroll
  for (int gate = 0; gate < 4; ++gate)
    #pragma unroll
    for (int ks = 0; ks < 4; ++ks)
      BW[gate][ks] = *(const bf16x8*)(BfragW +
          ((size_t)((gate * 8 + wv2) * 4 + ks) * 64 + lane) * 8);

  for (int tile = blockIdx.x; tile < nTiles; tile += gridDim.x) {
    int e0 = tile * EDGES_T;
    for (int i = tid; i < 16 * EDGES_T; i += 512) {   // stage tokens [t][m]
      int m = i >> 4, t = i & 15;
      int ee = e0 + m; if (ee >= E) ee = E - 1;
      toks[t][m] = tokens[(size_t)ee * 16 + t];
    }
    __syncthreads();

    f32x4 cst[N_ES];   // statically indexed (es fully unrolled)
    // ---- step 0: gates = P only (h0=c0=0, f-term vanishes)
    #pragma unroll
    for (int es = 0; es < N_ES; ++es) {
      int eL = es * 16 + l15;
      int v0 = toks[0][eL];
      const uint4* pp = (const uint4*)(Pg + ((size_t)v0 * 128 + hbase) * 4);
      uint4 pa = pp[0], pb = pp[1];
      float pi[4] = {bflo2f(pa.x), bflo2f(pa.z), bflo2f(pb.x), bflo2f(pb.z)};
      float pg[4] = {bflo2f(pa.y), bflo2f(pa.w), bflo2f(pb.y), bflo2f(pb.w)};
      float po[4] = {bfhi2f(pa.y), bfhi2f(pa.w), bfhi2f(pb.y), bfhi2f(pb.w)};
      float h[4];
      #pragma unroll
      for (int r = 0; r < 4; ++r) {
        float A = fast_exp2(pi[r]);
        float B = fast_exp2(pg[r]);
        float O = fast_exp2(po[r]);
        float cn = pair_sig_tanh(A, B);     // i*g
        cst[es][r] = cn;
        float C = fast_exp2(TWO_LOG2E_F * cn);
        h[r] = pair_sig_tanh(O, C);         // o*tanh(c)
      }
      uint2 hp = make_uint2(cvt_pk_bf16(h[0], h[1]), cvt_pk_bf16(h[2], h[3]));
      *(uint2*)(&Hs[0][eL * HS_STRIDE + hbase]) = hp;
    }
    __syncthreads();

    int cur = 0;
    #pragma unroll 1
    for (int t = 1; t < 16; ++t) {
      #pragma unroll
      for (int es = 0; es < N_ES; ++es) {
        int eL = es * 16 + l15;
        int vt = toks[t][eL];
        const uint4* pp = (const uint4*)(Pg + ((size_t)vt * 128 + hbase) * 4);
        uint4 pa = pp[0], pb = pp[1];
        f32x4 acc[4];
        acc[0] = (f32x4){bflo2f(pa.x), bflo2f(pa.z), bflo2f(pb.x), bflo2f(pb.z)}; // i
        acc[1] = (f32x4){bfhi2f(pa.x), bfhi2f(pa.z), bfhi2f(pb.x), bfhi2f(pb.z)}; // f
        acc[2] = (f32x4){bflo2f(pa.y), bflo2f(pa.w), bflo2f(pb.y), bflo2f(pb.w)}; // g
        acc[3] = (f32x4){bfhi2f(pa.y), bfhi2f(pa.w), bfhi2f(pb.y), bfhi2f(pb.w)}; // o

        #pragma unroll
        for (int ks = 0; ks < 4; ++ks) {
          bf16x8 Hf = *(const bf16x8*)(&Hs[cur][eL * HS_STRIDE + ks * 32 + lg * 8]);
          #pragma unroll
          for (int gate = 0; gate < 4; ++gate)
            acc[gate] = __builtin_amdgcn_mfma_f32_16x16x32_bf16(
                BW[gate][ks], Hf, acc[gate], 0, 0, 0);
        }

        float h[4];
        #pragma unroll
        for (int r = 0; r < 4; ++r) {
          float A = fast_exp2(acc[0][r]);
          float F = fast_exp2(acc[1][r]);
          float B = fast_exp2(acc[2][r]);
          float O = fast_exp2(acc[3][r]);
          float ig = pair_sig_tanh(A, B);
          float f  = fast_rcp(1.0f + F);
          float cn = fmaf(f, cst[es][r], ig);
          cst[es][r] = cn;
          float C = fast_exp2(TWO_LOG2E_F * cn);
          h[r] = pair_sig_tanh(O, C);
        }
        uint2 hp = make_uint2(cvt_pk_bf16(h[0], h[1]), cvt_pk_bf16(h[2], h[3]));
        *(uint2*)(&Hs[cur ^ 1][eL * HS_STRIDE + hbase]) = hp;
      }
      cur ^= 1;
      __syncthreads();
    }

    // ---- tail: waves 0..3 each handle edge sub-tile es=wv2.
    if (wv2 < N_ES) {
      int eL = wv2 * 16 + l15;
      bf16x8 Hf[4];
      #pragma unroll
      for (int ks = 0; ks < 4; ++ks)
        Hf[ks] = *(const bf16x8*)(&Hs[cur][eL * HS_STRIDE + ks * 32 + lg * 8]);
      f32x4 a2[2];
      a2[0] = (f32x4){0.f, 0.f, 0.f, 0.f};
      a2[1] = (f32x4){0.f, 0.f, 0.f, 0.f};
      #pragma unroll
      for (int ks = 0; ks < 4; ++ks)
        #pragma unroll
        for (int n2 = 0; n2 < 2; ++n2)
          a2[n2] = __builtin_amdgcn_mfma_f32_16x16x32_bf16(
              *(const bf16x8*)(Bfrag1 + ((size_t)(n2 * 4 + ks) * 64 + lane) * 8),
              Hf[ks], a2[n2], 0, 0, 0);
      float4 w2lo = *(const float4*)(W2 + lg * 4);
      float4 w2hi = *(const float4*)(W2 + 16 + lg * 4);
      float b2v = b2[0];
      int v15 = toks[15][eL];
      float4 fb0 = *(const float4*)(FB + v15 * 32 + lg * 4);
      float4 fb1 = *(const float4*)(FB + v15 * 32 + 16 + lg * 4);
      float pr = fmaxf(a2[0][0] + fb0.x, 0.f) * w2lo.x
               + fmaxf(a2[0][1] + fb0.y, 0.f) * w2lo.y
               + fmaxf(a2[0][2] + fb0.z, 0.f) * w2lo.z
               + fmaxf(a2[0][3] + fb0.w, 0.f) * w2lo.w
               + fmaxf(a2[1][0] + fb1.x, 0.f) * w2hi.x
               + fmaxf(a2[1][1] + fb1.y, 0.f) * w2hi.y
               + fmaxf(a2[1][2] + fb1.z, 0.f) * w2hi.z
               + fmaxf(a2[1][3] + fb1.w, 0.f) * w2hi.w;
      pr += __shfl_xor(pr, 16);
      pr += __shfl_xor(pr, 32);
      int eidx = e0 + eL;
      if (lane < 16 && eidx < E) ea[eidx] = fmaxf(pr + b2v, 0.0f);
    }
    __syncthreads();   // before next tile reuses toks/Hs
  }
}

// ---------------- per-node argmax over x[:, :53] (wave per node) -----------
__global__ __launch_bounds__(256) void node_argmax_kernel(
    const float* __restrict__ x, int* __restrict__ nid, int N)
{
  int n = (blockIdx.x * 256 + threadIdx.x) >> 6;
  int lane = threadIdx.x & 63;
  if (n >= N) return;
  float v = (lane < SID_N) ? x[(size_t)n * D_DIM + lane] : -3.4e38f;
  int idx = lane;
  #pragma unroll
  for (int o = 32; o > 0; o >>= 1) {
    float ov = __shfl_down(v, o);
    int   oi = __shfl_down(idx, o);
    if (ov > v || (ov == v && oi < idx)) { v = ov; idx = oi; }
  }
  if (lane == 0) nid[n] = idx;
}

// ---------------- edge winner (last edge wins) + resolve -------------------
__global__ void edge_winner_kernel(
    const int* __restrict__ ei, const int* __restrict__ nid,
    int* __restrict__ win_in, int* __restrict__ win_out, int E)
{
  int e = blockIdx.x * 256 + threadIdx.x;
  if (e >= E) return;
  int s = ei[e];
  int t = ei[E + e];
  atomicMax(&win_in[(size_t)t * SID_N + nid[s]], e);
  atomicMax(&win_out[(size_t)s * SID_N + nid[t]], e);
}

__global__ void scatter_resolve_kernel(
    const int* __restrict__ ei, const int* __restrict__ nid,
    const float* __restrict__ ea,
    const int* __restrict__ win_in, const int* __restrict__ win_out,
    float* __restrict__ x_mod, int E)
{
  int e = blockIdx.x * 256 + threadIdx.x;
  if (e >= E) return;
  int s = ei[e];
  int t = ei[E + e];
  int sid = nid[s], tix = nid[t];
  if (win_in[(size_t)t * SID_N + sid] == e)
    x_mod[(size_t)t * D_DIM + IN_COL + sid] = ea[e];
  if (win_out[(size_t)s * SID_N + tix] == e)
    x_mod[(size_t)s * D_DIM + OUT_COL + tix] = ea[e];
}

// ---------------- pack Wl||Wr into MFMA fragment order ----------------
__global__ void pack_w_kernel(const float* __restrict__ Wl,
                              const float* __restrict__ Wr,
                              unsigned short* __restrict__ Wfrag)
{
  int f = blockIdx.x * 256 + threadIdx.x;
  if (f >= 48 * 12 * 64 * 8) return;
  int e = f & 7, l = (f >> 3) & 63;
  int rest = f >> 9;
  int ks = rest % 12, nt = rest / 12;
  int nl = nt * 16 + (l & 15);
  int k  = ks * 32 + (l >> 4) * 8 + e;
  float val = 0.0f;
  if (k < D_DIM) {
    if (nl < D_DIM)                      val = Wl[(size_t)k * D_DIM + nl];
    else if (nl >= 384 && nl < 384 + D_DIM) val = Wr[(size_t)k * D_DIM + (nl - 384)];
  }
  Wfrag[f] = f2bf(val);
}

// ---------------- fused bf16 MFMA GEMM: [xl||xr] = xmod @ [Wl||Wr] + bias ----
__global__ __launch_bounds__(256, 2) void gemm_mfma_kernel(
    const float* __restrict__ A,               // xmod [N][373] fp32
    const unsigned short* __restrict__ Wfrag,  // [48][12][64][8] bf16
    const float* __restrict__ bl, const float* __restrict__ br,
    float* __restrict__ xl, float* __restrict__ xr, int N)
{
  __shared__ unsigned short As[64][40];
  int tid  = threadIdx.x;
  int lane = tid & 63;
  int wv   = tid >> 6;
  int l15  = lane & 15, lg = lane >> 4;
  int m0   = blockIdx.x * 64;
  int nt   = blockIdx.y * 4 + wv;

  f32x4 acc[4];
  #pragma unroll
  for (int i = 0; i < 4; ++i) acc[i] = (f32x4){0.f, 0.f, 0.f, 0.f};

  int srow = tid >> 2, seg = tid & 3;
  int gr = m0 + srow; if (gr >= N) gr = N - 1;
  const float* arow = A + (size_t)gr * D_DIM;

  for (int ks = 0; ks < 12; ++ks) {
    int c0 = ks * 32 + seg * 8;
    float v[8];
    #pragma unroll
    for (int j = 0; j < 8; ++j) v[j] = (c0 + j < D_DIM) ? arow[c0 + j] : 0.0f;
    unsigned pk0 = cvt_pk_bf16(v[0], v[1]);
    unsigned pk1 = cvt_pk_bf16(v[2], v[3]);
    unsigned pk2 = cvt_pk_bf16(v[4], v[5]);
    unsigned pk3 = cvt_pk_bf16(v[6], v[7]);
    __syncthreads();
    *(uint4*)(&As[srow][seg * 8]) = make_uint4(pk0, pk1, pk2, pk3);
    __syncthreads();

    bf16x8 Bf = *(const bf16x8*)(Wfrag + ((size_t)(nt * 12 + ks) * 64 + lane) * 8);
    #pragma unroll
    for (int msub = 0; msub < 4; ++msub) {
      bf16x8 Af = *(const bf16x8*)(&As[msub * 16 + l15][lg * 8]);
      acc[msub] = __builtin_amdgcn_mfma_f32_16x16x32_bf16(Af, Bf, acc[msub], 0, 0, 0);
    }
  }

  int nl = nt * 16 + l15;
  float* dst = nullptr; int col = 0; const float* bias_ = nullptr;
  if (nl < D_DIM)                         { dst = xl; col = nl;       bias_ = bl; }
  else if (nl >= 384 && nl < 384 + D_DIM) { dst = xr; col = nl - 384; bias_ = br; }
  if (dst) {
    float bv = bias_[col];
    #pragma unroll
    for (int msub = 0; msub < 4; ++msub) {
      #pragma unroll
      for (int r = 0; r < 4; ++r) {
        int m = m0 + msub * 16 + lg * 4 + r;
        if (m < N) dst[(size_t)m * D_DIM + col] = acc[msub][r] + bv;
      }
    }
  }
}

// ---------------- CSR build: histogram / scan / placement ----------------
__global__ void hist_kernel(const int* __restrict__ ei, unsigned* __restrict__ deg,
                            int E) {
  int e = blockIdx.x * 256 + threadIdx.x;
  if (e >= E) return;
  atomicAdd(&deg[ei[E + e]], 1u);
}

__global__ void scan1_kernel(const unsigned* __restrict__ deg,
                             unsigned* __restrict__ excl,
                             unsigned* __restrict__ bsum, int n) {
  __shared__ unsigned s[256];
  int t = threadIdx.x;
  int i = blockIdx.x * 256 + t;
  unsigned v = (i < n) ? deg[i] : 0u;
  s[t] = v; __syncthreads();
  #pragma unroll
  for (int o = 1; o < 256; o <<= 1) {
    unsigned u = (t >= o) ? s[t - o] : 0u;
    __syncthreads();
    s[t] += u;
    __syncthreads();
  }
  if (i < n) excl[i] = s[t] - v;
  if (t == 255) bsum[blockIdx.x] = s[255];
}

__global__ void scan2_kernel(unsigned* __restrict__ bsum, int nb) {
  __shared__ unsigned s[256];
  int t = threadIdx.x;
  unsigned v = (t < nb) ? bsum[t] : 0u;
  s[t] = v; __syncthreads();
  #pragma unroll
  for (int o = 1; o < 256; o <<= 1) {
    unsigned u = (t >= o) ? s[t - o] : 0u;
    __syncthreads();
    s[t] += u;
    __syncthreads();
  }
  if (t < nb) bsum[t] = s[t] - v;   // exclusive
}

__global__ void scan3_kernel(unsigned* __restrict__ excl,
                             const unsigned* __restrict__ bsum, int n) {
  int i = blockIdx.x * 256 + threadIdx.x;
  if (i < n) excl[i] += bsum[i >> 8];
}

__global__ void place_kernel(const int* __restrict__ ei,
                             unsigned* __restrict__ offs,
                             int* __restrict__ csr_eid, int E) {
  int e = blockIdx.x * 256 + threadIdx.x;
  if (e >= E) return;
  unsigned j = atomicAdd(&offs[ei[E + e]], 1u);
  csr_eid[j] = e;
}

// ---------------- fused per-node GAT: logits + softmax + agg + finalize ----
// wave per node; 3 passes over the node's edge list. xl rows touched in
// pass 1 are L1/L2-hot for pass 3 (per-node working set ~12KB).
__global__ __launch_bounds__(256) void node_gat_fused_kernel(
    const float* __restrict__ xl, const float* __restrict__ xr,
    const float* __restrict__ att, const int* __restrict__ ei,
    const int* __restrict__ csr_eid, const unsigned* __restrict__ offs,
    const unsigned* __restrict__ deg, float* __restrict__ ebuf,
    const float* __restrict__ xmod, const float* __restrict__ bias,
    float* __restrict__ out, int N, int E, int goff)
{
  int n = (blockIdx.x * 256 + threadIdx.x) >> 6;
  int lane = threadIdx.x & 63;
  if (n >= N) return;
  unsigned end = offs[n], d = deg[n], start = end - d;

  // ---- pass 1: logits (leaky(xl[s]+xr[n]).att), butterfly-reduced, + max
  const float* xrn = xr + (size_t)n * D_DIM;
  float r0 = xrn[lane],        a0 = att[lane];
  float r1 = xrn[64 + lane],   a1 = att[64 + lane];
  float r2 = xrn[128 + lane],  a2 = att[128 + lane];
  float r3 = xrn[192 + lane],  a3 = att[192 + lane];
  float r4 = xrn[256 + lane],  a4 = att[256 + lane];
  float r5 = 0.f, a5 = 0.f;
  if (lane < 53) { r5 = xrn[320 + lane]; a5 = att[320 + lane]; }

  float mx = -3.4e38f;
  for (unsigned j = start; j < end; ++j) {
    int eid = csr_eid[j];
    const float* row = xl + (size_t)ei[eid] * D_DIM;
    float m, acc;
    m = row[lane] + r0;        acc  = ((m > 0.f) ? m : 0.2f * m) * a0;
    m = row[64 + lane] + r1;   acc += ((m > 0.f) ? m : 0.2f * m) * a1;
    m = row[128 + lane] + r2;  acc += ((m > 0.f) ? m : 0.2f * m) * a2;
    m = row[192 + lane] + r3;  acc += ((m > 0.f) ? m : 0.2f * m) * a3;
    m = row[256 + lane] + r4;  acc += ((m > 0.f) ? m : 0.2f * m) * a4;
    if (lane < 53) { m = row[320 + lane] + r5; acc += ((m > 0.f) ? m : 0.2f * m) * a5; }
    // butterfly: every lane ends with the full sum
    acc += __shfl_xor(acc, 1);
    acc += __shfl_xor(acc, 2);
    acc += __shfl_xor(acc, 4);
    acc += __shfl_xor(acc, 8);
    acc += __shfl_xor(acc, 16);
    acc += __shfl_xor(acc, 32);
    if (lane == 0) ebuf[eid] = acc;
    mx = fmaxf(mx, acc);
  }

  // ---- pass 2: exp + denominator (ebuf L2-hot)
  float den = 0.0f;
  for (unsigned j = start; j < end; ++j) {
    int eid = csr_eid[j];
    float ex = __expf(ebuf[eid] - mx);
    if (lane == 0) ebuf[eid] = ex;
    den += ex;
  }
  float inv = 1.0f / (den + 1e-16f);

  // ---- pass 3: weighted aggregate (xl rows L1/L2-hot from pass 1)
  float o0 = 0, o1 = 0, o2 = 0, o3 = 0, o4 = 0, o5 = 0;
  for (unsigned j = start; j < end; ++j) {
    int eid = csr_eid[j];
    float w = ebuf[eid] * inv;
    const float* row = xl + (size_t)ei[eid] * D_DIM;
    o0 = fmaf(w, row[lane], o0);
    o1 = fmaf(w, row[64 + lane], o1);
    o2 = fmaf(w, row[128 + lane], o2);
    o3 = fmaf(w, row[192 + lane], o3);
    o4 = fmaf(w, row[256 + lane], o4);
    if (lane < 53) o5 = fmaf(w, row[320 + lane], o5);
  }

  const float* xm = xmod + (size_t)n * D_DIM;
  float* op = out + (size_t)n * (2 * D_DIM) + goff;
  op[lane]       = fmaxf(o0 + bias[lane]       + xm[lane],       0.0f);
  op[64 + lane]  = fmaxf(o1 + bias[64 + lane]  + xm[64 + lane],  0.0f);
  op[128 + lane] = fmaxf(o2 + bias[128 + lane] + xm[128 + lane], 0.0f);
  op[192 + lane] = fmaxf(o3 + bias[192 + lane] + xm[192 + lane], 0.0f);
  op[256 + lane] = fmaxf(o4 + bias[256 + lane] + xm[256 + lane], 0.0f);
  if (lane < 53)
    op[320 + lane] = fmaxf(o5 + bias[320 + lane] + xm[320 + lane], 0.0f);
}

// ---------------------------------------------------------------------------
extern "C" void kernel_launch(void* const* d_in, const int* in_sizes, int n_in,
                              void* d_out, int out_size, void* d_ws, size_t ws_size,
                              hipStream_t stream)
{
  const float* fx     = (const float*)d_in[0];
  const float* bx     = (const float*)d_in[1];
  const int*   fei    = (const int*)d_in[2];
  const int*   bei    = (const int*)d_in[3];
  const int*   ftk    = (const int*)d_in[4];
  const int*   btk    = (const int*)d_in[5];
  const float* embed  = (const float*)d_in[6];
  const float* Wih_f  = (const float*)d_in[7];
  const float* Whh_f  = (const float*)d_in[8];
  const float* bih_f  = (const float*)d_in[9];
  const float* bhh_f  = (const float*)d_in[10];
  const float* Wih_r  = (const float*)d_in[11];
  // d_in[12] = Whh_r : unused (reverse cell consumes zero state)
  const float* bih_r  = (const float*)d_in[13];
  const float* bhh_r  = (const float*)d_in[14];
  const float* W1     = (const float*)d_in[15];
  const float* b1     = (const float*)d_in[16];
  const float* W2     = (const float*)d_in[17];
  const float* b2     = (const float*)d_in[18];

  const float* Wl_g[2]   = {(const float*)d_in[19], (const float*)d_in[25]};
  const float* bl_g[2]   = {(const float*)d_in[20], (const float*)d_in[26]};
  const float* Wr_g[2]   = {(const float*)d_in[21], (const float*)d_in[27]};
  const float* br_g[2]   = {(const float*)d_in[22], (const float*)d_in[28]};
  const float* att_g[2]  = {(const float*)d_in[23], (const float*)d_in[29]};
  const float* bias_g[2] = {(const float*)d_in[24], (const float*)d_in[30]};
  const float* x_g[2]    = {fx, bx};
  const int*   ei_g[2]   = {fei, bei};
  const int*   tk_g[2]   = {ftk, btk};

  const int E = in_sizes[2] / 2;          // 400000
  const int N = in_sizes[0] / D_DIM;      // 50000

  // ---- workspace layout (byte-based, 256B aligned chunks) ----
  char* wsb = (char*)d_ws;
  size_t off = 0;
  auto alloc = [&](size_t bytes) -> void* {
    void* p = wsb + off; off += (bytes + 255) & ~(size_t)255; return p;
  };
  unsigned short* Pg     = (unsigned short*)alloc((size_t)64 * 128 * 4 * 2);
  unsigned short* BfragW = (unsigned short*)alloc((size_t)65536 * 2);
  unsigned short* Bfrag1 = (unsigned short*)alloc((size_t)4096 * 2);
  unsigned short* Wfrag2 = (unsigned short*)alloc((size_t)2 * 294912 * 2);
  float* FB    = (float*)alloc((size_t)64 * 32 * 4);
  float* ea    = (float*)alloc((size_t)E * 4);
  float* ebuf  = (float*)alloc((size_t)E * 4);
  int*   nid   = (int*)alloc((size_t)N * 4);
  int*   csr_eid = (int*)alloc((size_t)E * 4);
  unsigned* deg  = (unsigned*)alloc((size_t)N * 4);
  unsigned* offs = (unsigned*)alloc((size_t)N * 4);
  unsigned* bsum = (unsigned*)alloc((size_t)256 * 4);
  int* win_in  = (int*)alloc((size_t)N * SID_N * 4);
  int* win_out = (int*)alloc((size_t)N * SID_N * 4);
  float* xmod  = (float*)alloc((size_t)N * D_DIM * 4);
  float* xl    = (float*)alloc((size_t)N * D_DIM * 4);
  float* xr    = (float*)alloc((size_t)N * D_DIM * 4);
  (void)ws_size; (void)n_in; (void)out_size;

  const size_t win_u32 = (size_t)((char*)win_out - (char*)win_in) / 4
                         + (size_t)N * SID_N;

  float* out = (float*)d_out;

  precompute_kernel<<<64, 512, 0, stream>>>(
      embed, Wih_f, Whh_f, bih_f, bhh_f, Wih_r, bih_r, bhh_r, W1, b1,
      Pg, BfragW, Bfrag1, FB);
  pack_w_kernel<<<(294912 + 255) / 256, 256, 0, stream>>>(
      Wl_g[0], Wr_g[0], Wfrag2);
  pack_w_kernel<<<(294912 + 255) / 256, 256, 0, stream>>>(
      Wl_g[1], Wr_g[1], Wfrag2 + 294912);

  const int nTiles  = (E + EDGES_T - 1) / EDGES_T;   // 6250
  const int gridL   = nTiles < 2048 ? nTiles : 2048;
  const int gridE   = (E + 255) / 256;
  const int nScanB  = (N + 255) / 256;
  const int gridNd  = (N * 64 + 255) / 256;
  dim3 gridG((N + 63) / 64, 12);

  for (int g = 0; g < 2; ++g) {
    const float* x  = x_g[g];
    const int*   ei = ei_g[g];

    // (1) edge scalar via MFMA LSTM
    lstm_mfma_kernel<<<gridL, 512, 0, stream>>>(tk_g[g], Pg, BfragW, Bfrag1,
                                                FB, W2, b2, ea, E, nTiles);

    // (2) x_mod = copy(x); per-node argmax; last-edge-wins scatter writes
    hipMemcpyAsync(xmod, x, (size_t)N * D_DIM * sizeof(float),
                   hipMemcpyDeviceToDevice, stream);
    node_argmax_kernel<<<gridNd, 256, 0, stream>>>(x, nid, N);
    fill_u32_kernel<<<2048, 256, 0, stream>>>((unsigned*)win_in, 0xFFFFFFFFu,
                                              win_u32);
    edge_winner_kernel<<<gridE, 256, 0, stream>>>(ei, nid, win_in, win_out, E);
    scatter_resolve_kernel<<<gridE, 256, 0, stream>>>(ei, nid, ea,
                                                      win_in, win_out, xmod, E);

    // (3) [xl||xr] = xmod @ [Wl||Wr] + bias  (bf16 MFMA)
    gemm_mfma_kernel<<<gridG, 256, 0, stream>>>(xmod, Wfrag2 + (size_t)g * 294912,
                                                bl_g[g], br_g[g], xl, xr, N);

    // (4) CSR by dst
    fill_u32_kernel<<<512, 256, 0, stream>>>(deg, 0u, (size_t)N);
    hist_kernel<<<gridE, 256, 0, stream>>>(ei, deg, E);
    scan1_kernel<<<nScanB, 256, 0, stream>>>(deg, offs, bsum, N);
    scan2_kernel<<<1, 256, 0, stream>>>(bsum, nScanB);
    scan3_kernel<<<nScanB, 256, 0, stream>>>(offs, bsum, N);
    place_kernel<<<gridE, 256, 0, stream>>>(ei, offs, csr_eid, E);

    // (5) fused attention: logits + softmax + aggregate + finalize
    node_gat_fused_kernel<<<gridNd, 256, 0, stream>>>(
        xl, xr, att_g[g], ei, csr_eid, offs, deg, ebuf, xmod, bias_g[g],
        out, N, E, g * D_DIM);
  }
}